// Round 1
// baseline (2640.011 us; speedup 1.0000x reference)
//
#include <hip/hip_runtime.h>
#include <hip/hip_bf16.h>
#include <math.h>

// ---------------------------------------------------------------------------
// EncoderBlock: pre-norm attention (NO softmax) + pre-norm FFN. All fp32.
// x:[4,1024,1024], mask:[4,1,1,1024] int32, D=1024, H=16, Dk=64, FF=4096.
// Round 0: correct fp32 baseline. GEMMs: 64x64x16 tiles, 4x4/thread.
// ---------------------------------------------------------------------------

#define EPS 1e-5f
#define NEG (-1e9f)

// ---- LayerNorm: one block per row of 1024. torch semantics:
// mean over last dim, UNBIASED std (ddof=1), y = a*(x-mean)/(std+eps)+b.
__global__ __launch_bounds__(256) void ln_kernel(
    const float* __restrict__ x, float* __restrict__ y,
    const float* __restrict__ alpha, const float* __restrict__ beta) {
  const int row = blockIdx.x;
  const float4 v = ((const float4*)(x + (size_t)row * 1024))[threadIdx.x];
  float s  = v.x + v.y + v.z + v.w;
  float ss = v.x * v.x + v.y * v.y + v.z * v.z + v.w * v.w;
#pragma unroll
  for (int off = 32; off > 0; off >>= 1) {
    s  += __shfl_down(s, off, 64);
    ss += __shfl_down(ss, off, 64);
  }
  __shared__ float red[8];
  const int lane = threadIdx.x & 63, wv = threadIdx.x >> 6;
  if (lane == 0) { red[wv] = s; red[4 + wv] = ss; }
  __syncthreads();
  const float S  = red[0] + red[1] + red[2] + red[3];
  const float SS = red[4] + red[5] + red[6] + red[7];
  const float mean = S * (1.0f / 1024.0f);
  float var = (SS - 1024.0f * mean * mean) * (1.0f / 1023.0f);
  var = fmaxf(var, 0.0f);
  const float scl = alpha[0] / (sqrtf(var) + EPS);
  const float b = beta[0];
  float4 o;
  o.x = (v.x - mean) * scl + b;
  o.y = (v.y - mean) * scl + b;
  o.z = (v.z - mean) * scl + b;
  o.w = (v.w - mean) * scl + b;
  ((float4*)(y + (size_t)row * 1024))[threadIdx.x] = o;
}

// ---- fp32 tiled GEMM: C[M,N] = op(A[M,K] @ W[K,N] + bias[N] (+ res[M,N]))
// 64x64 tile, BK=16, 256 threads, 4x4 micro-tile.
template <bool RELU, bool RES>
__global__ __launch_bounds__(256) void gemm_kernel(
    const float* __restrict__ A, const float* __restrict__ W,
    const float* __restrict__ bias, const float* __restrict__ res,
    float* __restrict__ C, int M, int N, int K) {
  __shared__ float As[16][65];  // [k][m], pad breaks write conflicts
  __shared__ float Ws[16][64];  // [k][n]
  const int tx = threadIdx.x & 15, ty = threadIdx.x >> 4;
  const int m0 = blockIdx.y * 64, n0 = blockIdx.x * 64;
  const int lr = threadIdx.x >> 2;          // A-stage row 0..63
  const int lk = (threadIdx.x & 3) * 4;     // A-stage k   {0,4,8,12}
  const int wr = threadIdx.x >> 4;          // W-stage row 0..15
  const int wc = (threadIdx.x & 15) * 4;    // W-stage col

  float c[4][4] = {};
  for (int k0 = 0; k0 < K; k0 += 16) {
    const float4 a4 = *(const float4*)(A + (size_t)(m0 + lr) * K + k0 + lk);
    As[lk + 0][lr] = a4.x;
    As[lk + 1][lr] = a4.y;
    As[lk + 2][lr] = a4.z;
    As[lk + 3][lr] = a4.w;
    *(float4*)&Ws[wr][wc] = *(const float4*)(W + (size_t)(k0 + wr) * N + n0 + wc);
    __syncthreads();
#pragma unroll
    for (int k = 0; k < 16; ++k) {
      const float a0 = As[k][4 * ty + 0];   // broadcast reads (free)
      const float a1 = As[k][4 * ty + 1];
      const float a2 = As[k][4 * ty + 2];
      const float a3 = As[k][4 * ty + 3];
      const float4 b4 = *(const float4*)&Ws[k][4 * tx];  // 2-way (free)
      c[0][0] += a0 * b4.x; c[0][1] += a0 * b4.y; c[0][2] += a0 * b4.z; c[0][3] += a0 * b4.w;
      c[1][0] += a1 * b4.x; c[1][1] += a1 * b4.y; c[1][2] += a1 * b4.z; c[1][3] += a1 * b4.w;
      c[2][0] += a2 * b4.x; c[2][1] += a2 * b4.y; c[2][2] += a2 * b4.z; c[2][3] += a2 * b4.w;
      c[3][0] += a3 * b4.x; c[3][1] += a3 * b4.y; c[3][2] += a3 * b4.z; c[3][3] += a3 * b4.w;
    }
    __syncthreads();
  }
#pragma unroll
  for (int i = 0; i < 4; ++i) {
    const int m = m0 + 4 * ty + i;
    const int n = n0 + 4 * tx;
    float4 o;
    o.x = c[i][0] + bias[n + 0];
    o.y = c[i][1] + bias[n + 1];
    o.z = c[i][2] + bias[n + 2];
    o.w = c[i][3] + bias[n + 3];
    if (RES) {
      const float4 r4 = *(const float4*)(res + (size_t)m * N + n);
      o.x += r4.x; o.y += r4.y; o.z += r4.z; o.w += r4.w;
    }
    if (RELU) {
      o.x = fmaxf(o.x, 0.0f); o.y = fmaxf(o.y, 0.0f);
      o.z = fmaxf(o.z, 0.0f); o.w = fmaxf(o.w, 0.0f);
    }
    *(float4*)(C + (size_t)m * N + n) = o;
  }
}

// ---- fused no-softmax attention: ctx = (mask? QK^T/8 : -1e9) @ V
// One block per (q_tile=64, head, batch). K/V processed in 32-key tiles.
// q/k/v layout: [b*1024+s, h*64+d] (projection output). ctx same layout.
__global__ __launch_bounds__(256) void attn_kernel(
    const float* __restrict__ qb, const float* __restrict__ kb,
    const float* __restrict__ vb, const int* __restrict__ mask,
    float* __restrict__ ctx) {
  __shared__ float Qs[64][65];  // 64 q rows x 64 d
  __shared__ float Ks[32][65];  // 32 keys  x 64 d
  __shared__ float Vs[32][68];  // 32 keys  x 64 d (pad 68: aligned float4)
  __shared__ float Ss[64][33];  // 64 q x 32 k scores
  const int b = blockIdx.z, h = blockIdx.y, q0 = blockIdx.x * 64;
  const int tx = threadIdx.x & 15, ty = threadIdx.x >> 4;
  const size_t hb_off = ((size_t)b * 1024) * 1024 + (size_t)h * 64;
  const int* mrow = mask + b * 1024;

  // stage Q tile (64x64)
  for (int idx = threadIdx.x; idx < 64 * 64; idx += 256) {
    const int r = idx >> 6, cc = idx & 63;
    Qs[r][cc] = qb[hb_off + (size_t)(q0 + r) * 1024 + cc];
  }

  float acc[4][4] = {};
  for (int kt = 0; kt < 32; ++kt) {
    const int kbase = kt * 32;
    __syncthreads();  // iter0: Q staged; else: prev PV done, safe to overwrite
    for (int idx = threadIdx.x; idx < 32 * 64; idx += 256) {
      const int r = idx >> 6, cc = idx & 63;
      Ks[r][cc] = kb[hb_off + (size_t)(kbase + r) * 1024 + cc];
      Vs[r][cc] = vb[hb_off + (size_t)(kbase + r) * 1024 + cc];
    }
    __syncthreads();

    // S tile: each thread 4 q-rows x 2 k-cols
    float s[4][2] = {};
#pragma unroll 8
    for (int d = 0; d < 64; ++d) {
      const float a0 = Qs[4 * ty + 0][d];
      const float a1 = Qs[4 * ty + 1][d];
      const float a2 = Qs[4 * ty + 2][d];
      const float a3 = Qs[4 * ty + 3][d];
      const float k0 = Ks[2 * tx + 0][d];
      const float k1 = Ks[2 * tx + 1][d];
      s[0][0] += a0 * k0; s[0][1] += a0 * k1;
      s[1][0] += a1 * k0; s[1][1] += a1 * k1;
      s[2][0] += a2 * k0; s[2][1] += a2 * k1;
      s[3][0] += a3 * k0; s[3][1] += a3 * k1;
    }
    const int2 mv = *(const int2*)(mrow + kbase + 2 * tx);
#pragma unroll
    for (int i = 0; i < 4; ++i) {
      Ss[4 * ty + i][2 * tx + 0] = mv.x ? s[i][0] * 0.125f : NEG;
      Ss[4 * ty + i][2 * tx + 1] = mv.y ? s[i][1] * 0.125f : NEG;
    }
    __syncthreads();

    // acc += Ss @ Vs (each thread: 4 q-rows x 4 d-cols)
#pragma unroll 8
    for (int kk = 0; kk < 32; ++kk) {
      const float p0 = Ss[4 * ty + 0][kk];  // broadcast (free)
      const float p1 = Ss[4 * ty + 1][kk];
      const float p2 = Ss[4 * ty + 2][kk];
      const float p3 = Ss[4 * ty + 3][kk];
      const float4 v4 = *(const float4*)&Vs[kk][4 * tx];  // 2-way (free)
      acc[0][0] += p0 * v4.x; acc[0][1] += p0 * v4.y; acc[0][2] += p0 * v4.z; acc[0][3] += p0 * v4.w;
      acc[1][0] += p1 * v4.x; acc[1][1] += p1 * v4.y; acc[1][2] += p1 * v4.z; acc[1][3] += p1 * v4.w;
      acc[2][0] += p2 * v4.x; acc[2][1] += p2 * v4.y; acc[2][2] += p2 * v4.z; acc[2][3] += p2 * v4.w;
      acc[3][0] += p3 * v4.x; acc[3][1] += p3 * v4.y; acc[3][2] += p3 * v4.z; acc[3][3] += p3 * v4.w;
    }
  }
#pragma unroll
  for (int i = 0; i < 4; ++i) {
    float4 o;
    o.x = acc[i][0]; o.y = acc[i][1]; o.z = acc[i][2]; o.w = acc[i][3];
    *(float4*)(ctx + hb_off + (size_t)(q0 + 4 * ty + i) * 1024 + 4 * tx) = o;
  }
}

extern "C" void kernel_launch(void* const* d_in, const int* in_sizes, int n_in,
                              void* d_out, int out_size, void* d_ws, size_t ws_size,
                              hipStream_t stream) {
  const float* x    = (const float*)d_in[0];
  const int*   mask = (const int*)d_in[1];
  const float* wq = (const float*)d_in[2];
  const float* bq = (const float*)d_in[3];
  const float* wk = (const float*)d_in[4];
  const float* bk = (const float*)d_in[5];
  const float* wv = (const float*)d_in[6];
  const float* bv = (const float*)d_in[7];
  const float* wo = (const float*)d_in[8];
  const float* bo = (const float*)d_in[9];
  const float* w1 = (const float*)d_in[10];
  const float* b1 = (const float*)d_in[11];
  const float* w2 = (const float*)d_in[12];
  const float* b2 = (const float*)d_in[13];
  const float* ln1a = (const float*)d_in[14];
  const float* ln1b = (const float*)d_in[15];
  const float* ln2a = (const float*)d_in[16];
  const float* ln2b = (const float*)d_in[17];
  float* out = (float*)d_out;
  float* ws  = (float*)d_ws;

  const size_t SZ = (size_t)4096 * 1024;  // one [4096,1024] fp32 buffer
  float* xn  = ws;           // buf0
  float* q   = ws + SZ;      // buf1
  float* k   = ws + 2 * SZ;  // buf2
  float* v   = ws + 3 * SZ;  // buf3
  float* hb  = ws + 4 * SZ;  // buf4: FFN hidden chunk [1024,4096]
  float* ctx = xn;           // reuse buf0 (xn dead after QKV proj)
  float* x1  = q;            // reuse buf1 (q dead after attention)
  float* xn2 = k;            // reuse buf2 (k dead after attention)

  // 1. xn = LN1(x)
  ln_kernel<<<4096, 256, 0, stream>>>(x, xn, ln1a, ln1b);
  // 2. Q/K/V projections
  const dim3 gproj(1024 / 64, 4096 / 64);
  gemm_kernel<false, false><<<gproj, 256, 0, stream>>>(xn, wq, bq, nullptr, q, 4096, 1024, 1024);
  gemm_kernel<false, false><<<gproj, 256, 0, stream>>>(xn, wk, bk, nullptr, k, 4096, 1024, 1024);
  gemm_kernel<false, false><<<gproj, 256, 0, stream>>>(xn, wv, bv, nullptr, v, 4096, 1024, 1024);
  // 3. fused masked-score attention (no softmax)
  attn_kernel<<<dim3(16, 16, 4), 256, 0, stream>>>(q, k, v, mask, ctx);
  // 4. x1 = x + ctx @ wo + bo
  gemm_kernel<false, true><<<gproj, 256, 0, stream>>>(ctx, wo, bo, x, x1, 4096, 1024, 1024);
  // 5. xn2 = LN2(x1)
  ln_kernel<<<4096, 256, 0, stream>>>(x1, xn2, ln2a, ln2b);
  // 6. FFN, chunked over 4x1024 tokens to bound workspace:
  for (int c = 0; c < 4; ++c) {
    const size_t ro = (size_t)c * 1024 * 1024;
    gemm_kernel<true, false><<<dim3(4096 / 64, 1024 / 64), 256, 0, stream>>>(
        xn2 + ro, w1, b1, nullptr, hb, 1024, 4096, 1024);
    gemm_kernel<false, true><<<dim3(1024 / 64, 1024 / 64), 256, 0, stream>>>(
        hb, w2, b2, x1 + ro, out + ro, 1024, 1024, 4096);
  }
}

// Round 2
// 527.970 us; speedup vs baseline: 5.0003x; 5.0003x over previous
//
#include <hip/hip_runtime.h>
#include <hip/hip_bf16.h>
#include <math.h>

// ---------------------------------------------------------------------------
// EncoderBlock, bf16-MFMA version.
// All GEMMs: C[m][n] = sum_k A[m][k]*Bt[n][k]  (Bt = [N][K] row-major bf16),
// m97 structure: 128x128 tile, BK=32, global_load_lds(16B), mfma 16x16x32.
// Attention: S = Q K^T (no softmax); masked entries handled as rank-1
// correction in fp32:  out = (mask? S/8 : 0)@V  + (-1e9)*sum_{masked k} V[k,:]
// ---------------------------------------------------------------------------

#define EPS 1e-5f

typedef __attribute__((ext_vector_type(8))) short bf16x8;
typedef __attribute__((ext_vector_type(4))) float f32x4;

typedef const __attribute__((address_space(1))) unsigned char glob_byte;
typedef __attribute__((address_space(3))) unsigned char lds_byte;

__device__ __forceinline__ void g2l16(const void* g, void* l) {
  // 16B direct global->LDS. LDS dest = wave-uniform base + lane*16; our slot
  // maps are lane-contiguous per wave so passing the per-lane pointer is safe.
  __builtin_amdgcn_global_load_lds((glob_byte*)g, (lds_byte*)l, 16, 0, 0);
}

__device__ __forceinline__ unsigned short f2bf(float f) {
  union { float f; unsigned int u; } v; v.f = f;
  return (unsigned short)((v.u + 0x7FFFu + ((v.u >> 16) & 1u)) >> 16);
}
__device__ __forceinline__ float bf2f(unsigned short b) {
  union { unsigned int u; float f; } v; v.u = (unsigned int)b << 16;
  return v.f;
}

// ---- weight fp32 [K][N] -> bf16 transposed [N][K], 64x64 tiles, one launch.
__global__ __launch_bounds__(256) void wconv_kernel(
    const float* __restrict__ wq, const float* __restrict__ wk,
    const float* __restrict__ wv, const float* __restrict__ wo,
    const float* __restrict__ w1, const float* __restrict__ w2,
    unsigned short* __restrict__ wqT, unsigned short* __restrict__ wkT,
    unsigned short* __restrict__ wvT, unsigned short* __restrict__ woT,
    unsigned short* __restrict__ w1T, unsigned short* __restrict__ w2T) {
  __shared__ float tile[64][65];
  const int bid = blockIdx.x;
  const float* src; unsigned short* dst; int K, N, tk, tn;
  if (bid < 1024) {
    const int m = bid >> 8, loc = bid & 255;
    src = m == 0 ? wq : m == 1 ? wk : m == 2 ? wv : wo;
    dst = m == 0 ? wqT : m == 1 ? wkT : m == 2 ? wvT : woT;
    K = 1024; N = 1024; tk = loc >> 4; tn = loc & 15;
  } else if (bid < 2048) {
    const int loc = bid - 1024; src = w1; dst = w1T;
    K = 1024; N = 4096; tk = loc >> 6; tn = loc & 63;
  } else {
    const int loc = bid - 2048; src = w2; dst = w2T;
    K = 4096; N = 1024; tk = loc >> 4; tn = loc & 15;
  }
  const int t = threadIdx.x;
  const int lr = t >> 4, lc = (t & 15) * 4;
#pragma unroll
  for (int i = 0; i < 4; ++i) {
    const float4 v = *(const float4*)(src + (size_t)(tk * 64 + lr + 16 * i) * N + tn * 64 + lc);
    tile[lr + 16 * i][lc + 0] = v.x;
    tile[lr + 16 * i][lc + 1] = v.y;
    tile[lr + 16 * i][lc + 2] = v.z;
    tile[lr + 16 * i][lc + 3] = v.w;
  }
  __syncthreads();
  const int on = t >> 2, ok = (t & 3) * 16;
#pragma unroll
  for (int jj = 0; jj < 4; ++jj) {
    ushort4 o4;
    o4.x = f2bf(tile[ok + 4 * jj + 0][on]);
    o4.y = f2bf(tile[ok + 4 * jj + 1][on]);
    o4.z = f2bf(tile[ok + 4 * jj + 2][on]);
    o4.w = f2bf(tile[ok + 4 * jj + 3][on]);
    *(ushort4*)(dst + (size_t)(tn * 64 + on) * K + tk * 64 + ok + 4 * jj) = o4;
  }
}

// ---- LayerNorm (torch semantics: ddof=1, /(std+eps)), fp32 in -> bf16 out.
__global__ __launch_bounds__(256) void ln_kernel(
    const float* __restrict__ x, unsigned short* __restrict__ y,
    const float* __restrict__ alpha, const float* __restrict__ beta) {
  const int row = blockIdx.x;
  const float4 v = ((const float4*)(x + (size_t)row * 1024))[threadIdx.x];
  float s  = v.x + v.y + v.z + v.w;
  float ss = v.x * v.x + v.y * v.y + v.z * v.z + v.w * v.w;
#pragma unroll
  for (int off = 32; off > 0; off >>= 1) {
    s  += __shfl_down(s, off, 64);
    ss += __shfl_down(ss, off, 64);
  }
  __shared__ float red[8];
  const int lane = threadIdx.x & 63, wv_ = threadIdx.x >> 6;
  if (lane == 0) { red[wv_] = s; red[4 + wv_] = ss; }
  __syncthreads();
  const float S  = red[0] + red[1] + red[2] + red[3];
  const float SS = red[4] + red[5] + red[6] + red[7];
  const float mean = S * (1.0f / 1024.0f);
  float var = (SS - 1024.0f * mean * mean) * (1.0f / 1023.0f);
  var = fmaxf(var, 0.0f);
  const float scl = alpha[0] / (sqrtf(var) + EPS);
  const float b = beta[0];
  ushort4 o;
  o.x = f2bf((v.x - mean) * scl + b);
  o.y = f2bf((v.y - mean) * scl + b);
  o.z = f2bf((v.z - mean) * scl + b);
  o.w = f2bf((v.w - mean) * scl + b);
  ((ushort4*)(y + (size_t)row * 1024))[threadIdx.x] = o;
}

// ---- bf16 MFMA GEMM (m97 structure). A:[M][K], Bt:[N][K], both bf16 row-major.
template <bool OUT_BF16, bool BIAS_M, bool RELU, bool RES>
__global__ __launch_bounds__(256, 2) void mfma_gemm(
    const unsigned short* __restrict__ A, const unsigned short* __restrict__ Bt,
    const float* __restrict__ bias, const float* __restrict__ res,
    void* __restrict__ Cout, int M, int N, int K) {
  __shared__ __align__(16) unsigned short As[128 * 32];  // [m][k] 64B rows
  __shared__ __align__(16) unsigned short Bs[128 * 32];  // [n][k]
  const int tid = threadIdx.x, lane = tid & 63, w = tid >> 6;
  const int quad = lane >> 4, col = lane & 15;
  const int wm = w & 1, wn = w >> 1;
  const int m0 = blockIdx.y * 128, n0 = blockIdx.x * 128;

  f32x4 acc[4][4];
  const f32x4 z4 = {0.f, 0.f, 0.f, 0.f};
#pragma unroll
  for (int i = 0; i < 4; ++i)
#pragma unroll
    for (int j = 0; j < 4; ++j) acc[i][j] = z4;

  for (int k0 = 0; k0 < K; k0 += 32) {
    __syncthreads();
#pragma unroll
    for (int t = 0; t < 2; ++t) {
      const int s = t * 256 + w * 64 + lane;       // 16B chunk id
      const int r = s >> 2, c = s & 3;
      g2l16(A  + (size_t)(m0 + r) * K + k0 + c * 8, (void*)(As + s * 8));
      g2l16(Bt + (size_t)(n0 + r) * K + k0 + c * 8, (void*)(Bs + s * 8));
    }
    __syncthreads();
    bf16x8 af[4], bfr[4];
#pragma unroll
    for (int i = 0; i < 4; ++i) {
      af[i]  = *(const bf16x8*)(As + (wm * 64 + i * 16 + col) * 32 + quad * 8);
      bfr[i] = *(const bf16x8*)(Bs + (wn * 64 + i * 16 + col) * 32 + quad * 8);
    }
#pragma unroll
    for (int i = 0; i < 4; ++i)
#pragma unroll
      for (int j = 0; j < 4; ++j)
        acc[i][j] = __builtin_amdgcn_mfma_f32_16x16x32_bf16(af[i], bfr[j], acc[i][j], 0, 0, 0);
  }
  // epilogue: C-layout col=lane&15, row=quad*4+r (m89-verified)
#pragma unroll
  for (int i = 0; i < 4; ++i) {
    const int mrow = m0 + wm * 64 + i * 16 + quad * 4;
#pragma unroll
    for (int j = 0; j < 4; ++j) {
      const int n = n0 + wn * 64 + j * 16 + col;
      const float bn = BIAS_M ? 0.f : bias[n];
#pragma unroll
      for (int r = 0; r < 4; ++r) {
        const int m = mrow + r;
        float v = acc[i][j][r] + (BIAS_M ? bias[m] : bn);
        if (RES)  v += res[(size_t)m * N + n];
        if (RELU) v = fmaxf(v, 0.f);
        if (OUT_BF16) ((unsigned short*)Cout)[(size_t)m * N + n] = f2bf(v);
        else          ((float*)Cout)[(size_t)m * N + n] = v;
      }
    }
  }
}

// ---- corr[b][hd] = -1e9 * sum_{s: mask[b][s]==0} V[s][hd]  (from vT bf16)
__global__ __launch_bounds__(256) void masksum_kernel(
    const unsigned short* __restrict__ vT, const int* __restrict__ mask,
    float* __restrict__ corr) {
  const int hg = blockIdx.x, b = blockIdx.y, t = threadIdx.x;
  const int hd = hg * 64 + (t & 63), sg = t >> 6;
  const int* mrow = mask + b * 1024;
  const unsigned short* vrow = vT + (size_t)hd * 4096 + b * 1024 + sg * 256;
  float s = 0.f;
  for (int i = 0; i < 256; ++i)
    if (mrow[sg * 256 + i] == 0) s += bf2f(vrow[i]);
  __shared__ float red[4][64];
  red[sg][t & 63] = s;
  __syncthreads();
  if (sg == 0)
    corr[b * 1024 + hd] = -1e9f * (red[0][t] + red[1][t] + red[2][t] + red[3][t]);
}

// ---- fused attention: ctx[token][hd] = (mask? QK^T/8 : 0)@V + corr
// block = (q-tile 128, head, batch); 4 waves, each owns 32 q-rows.
__global__ __launch_bounds__(256, 2) void attn_kernel(
    const unsigned short* __restrict__ q, const unsigned short* __restrict__ k,
    const unsigned short* __restrict__ vT, const int* __restrict__ mask,
    const float* __restrict__ corr, unsigned short* __restrict__ ctx) {
  __shared__ __align__(16) unsigned short Qs[128 * 64];  // 128B rows, XOR-swz
  __shared__ __align__(16) unsigned short Ks[32 * 64];   // 128B rows, XOR-swz
  __shared__ __align__(16) unsigned short Vs[64 * 32];   // Vt[d][key], 64B rows
  __shared__ __align__(16) unsigned short Ps[128 * 32];  // P[q][key], XOR-swz
  const int tid = threadIdx.x, lane = tid & 63, w = tid >> 6;
  const int quad = lane >> 4, col = lane & 15;
  const int b = blockIdx.z, h = blockIdx.y, q0 = blockIdx.x * 128;
  const size_t qbase = ((size_t)(b * 1024 + q0)) * 1024 + h * 64;

  // stage Q 128x64 (8 chunks/row, chunk c stored at slot m*8 + (c^(m&7)))
#pragma unroll
  for (int t = 0; t < 4; ++t) {
    const int s = t * 256 + w * 64 + lane;
    const int m = s >> 3, c = (s & 7) ^ (m & 7);
    g2l16(q + qbase + (size_t)m * 1024 + c * 8, (void*)(Qs + s * 8));
  }
  __syncthreads();
  bf16x8 qf[2][2];
#pragma unroll
  for (int qt = 0; qt < 2; ++qt)
#pragma unroll
    for (int kf = 0; kf < 2; ++kf) {
      const int m = (w * 2 + qt) * 16 + col;
      const int c = (kf * 4 + quad) ^ (m & 7);
      qf[qt][kf] = *(const bf16x8*)(Qs + m * 64 + c * 8);
    }

  const f32x4 z4 = {0.f, 0.f, 0.f, 0.f};
  f32x4 oacc[2][4];
#pragma unroll
  for (int qt = 0; qt < 2; ++qt)
#pragma unroll
    for (int nt = 0; nt < 4; ++nt) oacc[qt][nt] = z4;

  const int* mrow = mask + b * 1024;
  for (int kb = 0; kb < 1024; kb += 32) {
    __syncthreads();
    {  // stage K 32x64 (swizzled) + Vt 64x32 (natural), 1 instr each per wave
      const int s = w * 64 + lane;
      const int key = s >> 3, ck = (s & 7) ^ (key & 7);
      g2l16(k + ((size_t)(b * 1024 + kb + key)) * 1024 + h * 64 + ck * 8,
            (void*)(Ks + s * 8));
      const int d = s >> 2, cv = s & 3;
      g2l16(vT + ((size_t)(h * 64 + d)) * 4096 + b * 1024 + kb + cv * 8,
            (void*)(Vs + s * 8));
    }
    __syncthreads();

    // S = Q K^T  (2 q-tiles x 2 key-tiles, K=64 via 2 chained mfma)
    f32x4 sacc[2][2];
#pragma unroll
    for (int qt = 0; qt < 2; ++qt)
#pragma unroll
      for (int kt = 0; kt < 2; ++kt) sacc[qt][kt] = z4;
#pragma unroll
    for (int kt = 0; kt < 2; ++kt)
#pragma unroll
      for (int kf = 0; kf < 2; ++kf) {
        const int key = kt * 16 + col;
        const int c = (kf * 4 + quad) ^ (key & 7);
        const bf16x8 kfrag = *(const bf16x8*)(Ks + key * 64 + c * 8);
#pragma unroll
        for (int qt = 0; qt < 2; ++qt)
          sacc[qt][kt] = __builtin_amdgcn_mfma_f32_16x16x32_bf16(
              qf[qt][kf], kfrag, sacc[qt][kt], 0, 0, 0);
      }

    // mask+scale -> Ps (bf16), chunk kc stored at slot q*4 + (kc ^ swz(q))
#pragma unroll
    for (int kt = 0; kt < 2; ++kt) {
      const bool keep = mrow[kb + kt * 16 + col] != 0;
#pragma unroll
      for (int qt = 0; qt < 2; ++qt)
#pragma unroll
        for (int r = 0; r < 4; ++r) {
          const int qq = (w * 2 + qt) * 16 + quad * 4 + r;
          const int kc = (kt * 16 + col) >> 3;
          const int sw = (qq & 3) ^ ((qq >> 2) & 3);
          Ps[(qq * 4 + (kc ^ sw)) * 8 + (col & 7)] =
              f2bf(keep ? sacc[qt][kt][r] * 0.125f : 0.f);
        }
    }
    // no barrier needed: each wave reads only the P rows it wrote

    // oacc += P @ V   (A=P rows q, B=Vt rows d: bt-pattern)
#pragma unroll
    for (int qt = 0; qt < 2; ++qt) {
      const int m = (w * 2 + qt) * 16 + col;
      const int sw = (m & 3) ^ ((m >> 2) & 3);
      const bf16x8 pf = *(const bf16x8*)(Ps + m * 32 + (quad ^ sw) * 8);
#pragma unroll
      for (int nt = 0; nt < 4; ++nt) {
        const bf16x8 vf = *(const bf16x8*)(Vs + (nt * 16 + col) * 32 + quad * 8);
        oacc[qt][nt] = __builtin_amdgcn_mfma_f32_16x16x32_bf16(pf, vf, oacc[qt][nt], 0, 0, 0);
      }
    }
  }

  const float* crow = corr + b * 1024 + h * 64;
#pragma unroll
  for (int qt = 0; qt < 2; ++qt)
#pragma unroll
    for (int nt = 0; nt < 4; ++nt) {
      const int d = nt * 16 + col;
      const float cv = crow[d];
#pragma unroll
      for (int r = 0; r < 4; ++r) {
        const int qq = q0 + (w * 2 + qt) * 16 + quad * 4 + r;
        ctx[((size_t)(b * 1024) + qq) * 1024 + h * 64 + d] = f2bf(oacc[qt][nt][r] + cv);
      }
    }
}

extern "C" void kernel_launch(void* const* d_in, const int* in_sizes, int n_in,
                              void* d_out, int out_size, void* d_ws, size_t ws_size,
                              hipStream_t stream) {
  const float* x    = (const float*)d_in[0];
  const int*   mask = (const int*)d_in[1];
  const float* wq = (const float*)d_in[2];
  const float* bq = (const float*)d_in[3];
  const float* wk = (const float*)d_in[4];
  const float* bk = (const float*)d_in[5];
  const float* wv = (const float*)d_in[6];
  const float* bv = (const float*)d_in[7];
  const float* wo = (const float*)d_in[8];
  const float* bo = (const float*)d_in[9];
  const float* w1 = (const float*)d_in[10];
  const float* b1 = (const float*)d_in[11];
  const float* w2 = (const float*)d_in[12];
  const float* b2 = (const float*)d_in[13];
  const float* ln1a = (const float*)d_in[14];
  const float* ln1b = (const float*)d_in[15];
  const float* ln2a = (const float*)d_in[16];
  const float* ln2b = (const float*)d_in[17];
  float* out = (float*)d_out;
  char* W = (char*)d_ws;
  const size_t MB = 1u << 20;

  unsigned short* wqT = (unsigned short*)(W + 0 * MB);   // 2 MB each
  unsigned short* wkT = (unsigned short*)(W + 2 * MB);
  unsigned short* wvT = (unsigned short*)(W + 4 * MB);
  unsigned short* woT = (unsigned short*)(W + 6 * MB);
  unsigned short* w1T = (unsigned short*)(W + 8 * MB);   // 8 MB
  unsigned short* w2T = (unsigned short*)(W + 16 * MB);  // 8 MB
  unsigned short* xn  = (unsigned short*)(W + 24 * MB);  // 8 MB
  unsigned short* qb  = (unsigned short*)(W + 32 * MB);  // 8 MB
  unsigned short* kb  = (unsigned short*)(W + 40 * MB);  // 8 MB
  unsigned short* vT  = (unsigned short*)(W + 48 * MB);  // 8 MB [1024][4096]
  unsigned short* ctx = (unsigned short*)(W + 56 * MB);  // 8 MB
  float*          x1  = (float*)(W + 32 * MB);           // 16 MB, reuses qb+kb
  unsigned short* xn2 = (unsigned short*)(W + 48 * MB);  // reuses vT
  unsigned short* hb  = (unsigned short*)(W + 64 * MB);  // 16 MB [2048][4096]
  float*          corr = (float*)(W + 80 * MB);          // 16 KB

  wconv_kernel<<<3072, 256, 0, stream>>>(wq, wk, wv, wo, w1, w2,
                                         wqT, wkT, wvT, woT, w1T, w2T);
  ln_kernel<<<4096, 256, 0, stream>>>(x, xn, ln1a, ln1b);
  // q/k: [4096]x[1024], K=1024
  mfma_gemm<true, false, false, false><<<dim3(8, 32), 256, 0, stream>>>(
      xn, wqT, bq, nullptr, qb, 4096, 1024, 1024);
  mfma_gemm<true, false, false, false><<<dim3(8, 32), 256, 0, stream>>>(
      xn, wkT, bk, nullptr, kb, 4096, 1024, 1024);
  // vT = (xn@wv)^T : A=wvT [1024][1024], Bt=xn [4096][1024], bias per-m
  mfma_gemm<true, true, false, false><<<dim3(32, 8), 256, 0, stream>>>(
      wvT, xn, bv, nullptr, vT, 1024, 4096, 1024);
  masksum_kernel<<<dim3(16, 4), 256, 0, stream>>>(vT, mask, corr);
  attn_kernel<<<dim3(8, 16, 4), 256, 0, stream>>>(qb, kb, vT, mask, corr, ctx);
  // x1 = x + ctx@wo + bo   (fp32 out)
  mfma_gemm<false, false, false, true><<<dim3(8, 32), 256, 0, stream>>>(
      ctx, woT, bo, x, x1, 4096, 1024, 1024);
  ln_kernel<<<4096, 256, 0, stream>>>(x1, xn2, ln2a, ln2b);
  // FFN in 2 token-chunks of 2048 (bounds hb at 16 MB)
  for (int c = 0; c < 2; ++c) {
    const size_t ro = (size_t)c * 2048 * 1024;
    mfma_gemm<true, false, true, false><<<dim3(32, 16), 256, 0, stream>>>(
        xn2 + ro, w1T, b1, nullptr, hb, 2048, 4096, 1024);
    mfma_gemm<false, false, false, true><<<dim3(8, 16), 256, 0, stream>>>(
        hb, w2T, b2, x1 + ro, out + ro, 2048, 1024, 4096);
  }
}

// Round 3
// 418.530 us; speedup vs baseline: 6.3078x; 1.2615x over previous
//
#include <hip/hip_runtime.h>
#include <hip/hip_bf16.h>
#include <math.h>

// ---------------------------------------------------------------------------
// EncoderBlock, bf16-MFMA, round 3: grid-size fixes.
//  - fused Q+K projection (wqkT [2048][1024], fused bias)
//  - un-chunked FFN (hb [4096][4096] bf16 = 32 MB, overlaps dead buffers)
//  - templated tiles TMxTN: 128x128 / 128x64 / 64x128 so every GEMM >= 512 blocks
// ---------------------------------------------------------------------------

#define EPS 1e-5f

typedef __attribute__((ext_vector_type(8))) short bf16x8;
typedef __attribute__((ext_vector_type(4))) float f32x4;

typedef const __attribute__((address_space(1))) unsigned char glob_byte;
typedef __attribute__((address_space(3))) unsigned char lds_byte;

__device__ __forceinline__ void g2l16(const void* g, void* l) {
  __builtin_amdgcn_global_load_lds((glob_byte*)g, (lds_byte*)l, 16, 0, 0);
}

__device__ __forceinline__ unsigned short f2bf(float f) {
  union { float f; unsigned int u; } v; v.f = f;
  return (unsigned short)((v.u + 0x7FFFu + ((v.u >> 16) & 1u)) >> 16);
}
__device__ __forceinline__ float bf2f(unsigned short b) {
  union { unsigned int u; float f; } v; v.u = (unsigned int)b << 16;
  return v.f;
}

// ---- weight fp32 [K][N] -> bf16 transposed [N][K]; also fused qk bias.
__global__ __launch_bounds__(256) void wconv_kernel(
    const float* __restrict__ wq, const float* __restrict__ wk,
    const float* __restrict__ wv, const float* __restrict__ wo,
    const float* __restrict__ w1, const float* __restrict__ w2,
    const float* __restrict__ bq, const float* __restrict__ bk,
    unsigned short* __restrict__ wqkT, unsigned short* __restrict__ wvT,
    unsigned short* __restrict__ woT, unsigned short* __restrict__ w1T,
    unsigned short* __restrict__ w2T, float* __restrict__ bqk) {
  const int bid = blockIdx.x;
  const int t = threadIdx.x;
  if (bid == 3072) {  // fused bias: bqk[0:1024]=bq, [1024:2048]=bk
#pragma unroll
    for (int i = 0; i < 8; ++i) {
      const int n = i * 256 + t;
      bqk[n] = n < 1024 ? bq[n] : bk[n - 1024];
    }
    return;
  }
  __shared__ float tile[64][65];
  const float* src; unsigned short* dst; int K, N, tk, tn;
  if (bid < 1024) {
    const int m = bid >> 8, loc = bid & 255;
    src = m == 0 ? wq : m == 1 ? wk : m == 2 ? wv : wo;
    dst = m == 0 ? wqkT : m == 1 ? (wqkT + (size_t)1024 * 1024)
                        : m == 2 ? wvT : woT;
    K = 1024; N = 1024; tk = loc >> 4; tn = loc & 15;
  } else if (bid < 2048) {
    const int loc = bid - 1024; src = w1; dst = w1T;
    K = 1024; N = 4096; tk = loc >> 6; tn = loc & 63;
  } else {
    const int loc = bid - 2048; src = w2; dst = w2T;
    K = 4096; N = 1024; tk = loc >> 4; tn = loc & 15;
  }
  const int lr = t >> 4, lc = (t & 15) * 4;
#pragma unroll
  for (int i = 0; i < 4; ++i) {
    const float4 v = *(const float4*)(src + (size_t)(tk * 64 + lr + 16 * i) * N + tn * 64 + lc);
    tile[lr + 16 * i][lc + 0] = v.x;
    tile[lr + 16 * i][lc + 1] = v.y;
    tile[lr + 16 * i][lc + 2] = v.z;
    tile[lr + 16 * i][lc + 3] = v.w;
  }
  __syncthreads();
  const int on = t >> 2, ok = (t & 3) * 16;
#pragma unroll
  for (int jj = 0; jj < 4; ++jj) {
    ushort4 o4;
    o4.x = f2bf(tile[ok + 4 * jj + 0][on]);
    o4.y = f2bf(tile[ok + 4 * jj + 1][on]);
    o4.z = f2bf(tile[ok + 4 * jj + 2][on]);
    o4.w = f2bf(tile[ok + 4 * jj + 3][on]);
    *(ushort4*)(dst + (size_t)(tn * 64 + on) * K + tk * 64 + ok + 4 * jj) = o4;
  }
}

// ---- LayerNorm (torch: ddof=1, /(std+eps)), fp32 in -> bf16 out.
__global__ __launch_bounds__(256) void ln_kernel(
    const float* __restrict__ x, unsigned short* __restrict__ y,
    const float* __restrict__ alpha, const float* __restrict__ beta) {
  const int row = blockIdx.x;
  const float4 v = ((const float4*)(x + (size_t)row * 1024))[threadIdx.x];
  float s  = v.x + v.y + v.z + v.w;
  float ss = v.x * v.x + v.y * v.y + v.z * v.z + v.w * v.w;
#pragma unroll
  for (int off = 32; off > 0; off >>= 1) {
    s  += __shfl_down(s, off, 64);
    ss += __shfl_down(ss, off, 64);
  }
  __shared__ float red[8];
  const int lane = threadIdx.x & 63, wv_ = threadIdx.x >> 6;
  if (lane == 0) { red[wv_] = s; red[4 + wv_] = ss; }
  __syncthreads();
  const float S  = red[0] + red[1] + red[2] + red[3];
  const float SS = red[4] + red[5] + red[6] + red[7];
  const float mean = S * (1.0f / 1024.0f);
  float var = (SS - 1024.0f * mean * mean) * (1.0f / 1023.0f);
  var = fmaxf(var, 0.0f);
  const float scl = alpha[0] / (sqrtf(var) + EPS);
  const float b = beta[0];
  ushort4 o;
  o.x = f2bf((v.x - mean) * scl + b);
  o.y = f2bf((v.y - mean) * scl + b);
  o.z = f2bf((v.z - mean) * scl + b);
  o.w = f2bf((v.w - mean) * scl + b);
  ((ushort4*)(y + (size_t)row * 1024))[threadIdx.x] = o;
}

// ---- bf16 MFMA GEMM. A:[M][K], Bt:[N][K] bf16 row-major. Tile TM x TN.
// Wave layout: 128x128 -> 2x2 waves (64x64 each); 128x64 -> 4x1 (32x64);
// 64x128 -> 1x4 (64x32).
template <int TM, int TN, bool OUT_BF16, bool BIAS_M, bool RELU, bool RES>
__global__ __launch_bounds__(256, 2) void mfma_gemm(
    const unsigned short* __restrict__ A, const unsigned short* __restrict__ Bt,
    const float* __restrict__ bias, const float* __restrict__ res,
    void* __restrict__ Cout, int M, int N, int K) {
  constexpr int WM = (TM == 128) ? ((TN == 128) ? 2 : 4) : 1;
  constexpr int WN = 4 / WM;
  constexpr int MSPAN = TM / WM, NSPAN = TN / WN;
  constexpr int MI = MSPAN / 16, NJ = NSPAN / 16;
  __shared__ __align__(16) unsigned short As[TM * 32];
  __shared__ __align__(16) unsigned short Bs[TN * 32];
  const int tid = threadIdx.x, lane = tid & 63, w = tid >> 6;
  const int quad = lane >> 4, col = lane & 15;
  const int wm = w % WM, wn = w / WM;
  const int m0 = blockIdx.y * TM, n0 = blockIdx.x * TN;

  f32x4 acc[MI][NJ];
  const f32x4 z4 = {0.f, 0.f, 0.f, 0.f};
#pragma unroll
  for (int i = 0; i < MI; ++i)
#pragma unroll
    for (int j = 0; j < NJ; ++j) acc[i][j] = z4;

  for (int k0 = 0; k0 < K; k0 += 32) {
    __syncthreads();
#pragma unroll
    for (int t = 0; t < TM / 64; ++t) {
      const int s = t * 256 + tid;
      const int r = s >> 2, c = s & 3;
      g2l16(A + (size_t)(m0 + r) * K + k0 + c * 8, (void*)(As + s * 8));
    }
#pragma unroll
    for (int t = 0; t < TN / 64; ++t) {
      const int s = t * 256 + tid;
      const int r = s >> 2, c = s & 3;
      g2l16(Bt + (size_t)(n0 + r) * K + k0 + c * 8, (void*)(Bs + s * 8));
    }
    __syncthreads();
    bf16x8 af[MI], bfr[NJ];
#pragma unroll
    for (int i = 0; i < MI; ++i)
      af[i] = *(const bf16x8*)(As + (wm * MSPAN + i * 16 + col) * 32 + quad * 8);
#pragma unroll
    for (int j = 0; j < NJ; ++j)
      bfr[j] = *(const bf16x8*)(Bs + (wn * NSPAN + j * 16 + col) * 32 + quad * 8);
#pragma unroll
    for (int i = 0; i < MI; ++i)
#pragma unroll
      for (int j = 0; j < NJ; ++j)
        acc[i][j] = __builtin_amdgcn_mfma_f32_16x16x32_bf16(af[i], bfr[j], acc[i][j], 0, 0, 0);
  }
#pragma unroll
  for (int i = 0; i < MI; ++i) {
    const int mrow = m0 + wm * MSPAN + i * 16 + quad * 4;
#pragma unroll
    for (int j = 0; j < NJ; ++j) {
      const int n = n0 + wn * NSPAN + j * 16 + col;
      const float bn = BIAS_M ? 0.f : bias[n];
#pragma unroll
      for (int r = 0; r < 4; ++r) {
        const int m = mrow + r;
        float v = acc[i][j][r] + (BIAS_M ? bias[m] : bn);
        if (RES)  v += res[(size_t)m * N + n];
        if (RELU) v = fmaxf(v, 0.f);
        if (OUT_BF16) ((unsigned short*)Cout)[(size_t)m * N + n] = f2bf(v);
        else          ((float*)Cout)[(size_t)m * N + n] = v;
      }
    }
  }
}

// ---- corr[b][hd] = -1e9 * sum_{s: mask[b][s]==0} V[s][hd]  (from vT bf16)
__global__ __launch_bounds__(256) void masksum_kernel(
    const unsigned short* __restrict__ vT, const int* __restrict__ mask,
    float* __restrict__ corr) {
  const int hg = blockIdx.x, b = blockIdx.y, t = threadIdx.x;
  const int hd = hg * 64 + (t & 63), sg = t >> 6;
  const int* mrow = mask + b * 1024;
  const unsigned short* vrow = vT + (size_t)hd * 4096 + b * 1024 + sg * 256;
  float s = 0.f;
  for (int i = 0; i < 256; ++i)
    if (mrow[sg * 256 + i] == 0) s += bf2f(vrow[i]);
  __shared__ float red[4][64];
  red[sg][t & 63] = s;
  __syncthreads();
  if (sg == 0)
    corr[b * 1024 + hd] = -1e9f * (red[0][t] + red[1][t] + red[2][t] + red[3][t]);
}

// ---- fused attention: ctx[token][hd] = (mask? QK^T/8 : 0)@V + corr
// q/k from fused qkb [4096][2048] (cols 0-1023 q, 1024-2047 k).
__global__ __launch_bounds__(256, 2) void attn_kernel(
    const unsigned short* __restrict__ qkb, const unsigned short* __restrict__ vT,
    const int* __restrict__ mask, const float* __restrict__ corr,
    unsigned short* __restrict__ ctx) {
  __shared__ __align__(16) unsigned short Qs[128 * 64];
  __shared__ __align__(16) unsigned short Ks[32 * 64];
  __shared__ __align__(16) unsigned short Vs[64 * 32];
  __shared__ __align__(16) unsigned short Ps[128 * 32];
  const int tid = threadIdx.x, lane = tid & 63, w = tid >> 6;
  const int quad = lane >> 4, col = lane & 15;
  const int b = blockIdx.z, h = blockIdx.y, q0 = blockIdx.x * 128;
  const size_t qbase = ((size_t)(b * 1024 + q0)) * 2048 + h * 64;

#pragma unroll
  for (int t = 0; t < 4; ++t) {
    const int s = t * 256 + w * 64 + lane;
    const int m = s >> 3, c = (s & 7) ^ (m & 7);
    g2l16(qkb + qbase + (size_t)m * 2048 + c * 8, (void*)(Qs + s * 8));
  }
  __syncthreads();
  bf16x8 qf[2][2];
#pragma unroll
  for (int qt = 0; qt < 2; ++qt)
#pragma unroll
    for (int kf = 0; kf < 2; ++kf) {
      const int m = (w * 2 + qt) * 16 + col;
      const int c = (kf * 4 + quad) ^ (m & 7);
      qf[qt][kf] = *(const bf16x8*)(Qs + m * 64 + c * 8);
    }

  const f32x4 z4 = {0.f, 0.f, 0.f, 0.f};
  f32x4 oacc[2][4];
#pragma unroll
  for (int qt = 0; qt < 2; ++qt)
#pragma unroll
    for (int nt = 0; nt < 4; ++nt) oacc[qt][nt] = z4;

  const int* mrow = mask + b * 1024;
  for (int kb = 0; kb < 1024; kb += 32) {
    __syncthreads();
    {
      const int s = w * 64 + lane;
      const int key = s >> 3, ck = (s & 7) ^ (key & 7);
      g2l16(qkb + ((size_t)(b * 1024 + kb + key)) * 2048 + 1024 + h * 64 + ck * 8,
            (void*)(Ks + s * 8));
      const int d = s >> 2, cv = s & 3;
      g2l16(vT + ((size_t)(h * 64 + d)) * 4096 + b * 1024 + kb + cv * 8,
            (void*)(Vs + s * 8));
    }
    __syncthreads();

    f32x4 sacc[2][2];
#pragma unroll
    for (int qt = 0; qt < 2; ++qt)
#pragma unroll
      for (int kt = 0; kt < 2; ++kt) sacc[qt][kt] = z4;
#pragma unroll
    for (int kt = 0; kt < 2; ++kt)
#pragma unroll
      for (int kf = 0; kf < 2; ++kf) {
        const int key = kt * 16 + col;
        const int c = (kf * 4 + quad) ^ (key & 7);
        const bf16x8 kfrag = *(const bf16x8*)(Ks + key * 64 + c * 8);
#pragma unroll
        for (int qt = 0; qt < 2; ++qt)
          sacc[qt][kt] = __builtin_amdgcn_mfma_f32_16x16x32_bf16(
              qf[qt][kf], kfrag, sacc[qt][kt], 0, 0, 0);
      }

#pragma unroll
    for (int kt = 0; kt < 2; ++kt) {
      const bool keep = mrow[kb + kt * 16 + col] != 0;
#pragma unroll
      for (int qt = 0; qt < 2; ++qt)
#pragma unroll
        for (int r = 0; r < 4; ++r) {
          const int qq = (w * 2 + qt) * 16 + quad * 4 + r;
          const int kc = (kt * 16 + col) >> 3;
          const int sw = (qq & 3) ^ ((qq >> 2) & 3);
          Ps[(qq * 4 + (kc ^ sw)) * 8 + (col & 7)] =
              f2bf(keep ? sacc[qt][kt][r] * 0.125f : 0.f);
        }
    }
    // no barrier: each wave reads only the P rows it wrote

#pragma unroll
    for (int qt = 0; qt < 2; ++qt) {
      const int m = (w * 2 + qt) * 16 + col;
      const int sw = (m & 3) ^ ((m >> 2) & 3);
      const bf16x8 pf = *(const bf16x8*)(Ps + m * 32 + (quad ^ sw) * 8);
#pragma unroll
      for (int nt = 0; nt < 4; ++nt) {
        const bf16x8 vf = *(const bf16x8*)(Vs + (nt * 16 + col) * 32 + quad * 8);
        oacc[qt][nt] = __builtin_amdgcn_mfma_f32_16x16x32_bf16(pf, vf, oacc[qt][nt], 0, 0, 0);
      }
    }
  }

  const float* crow = corr + b * 1024 + h * 64;
#pragma unroll
  for (int qt = 0; qt < 2; ++qt)
#pragma unroll
    for (int nt = 0; nt < 4; ++nt) {
      const int d = nt * 16 + col;
      const float cv = crow[d];
#pragma unroll
      for (int r = 0; r < 4; ++r) {
        const int qq = q0 + (w * 2 + qt) * 16 + quad * 4 + r;
        ctx[((size_t)(b * 1024) + qq) * 1024 + h * 64 + d] = f2bf(oacc[qt][nt][r] + cv);
      }
    }
}

extern "C" void kernel_launch(void* const* d_in, const int* in_sizes, int n_in,
                              void* d_out, int out_size, void* d_ws, size_t ws_size,
                              hipStream_t stream) {
  const float* x    = (const float*)d_in[0];
  const int*   mask = (const int*)d_in[1];
  const float* wq = (const float*)d_in[2];
  const float* bq = (const float*)d_in[3];
  const float* wk = (const float*)d_in[4];
  const float* bk = (const float*)d_in[5];
  const float* wv = (const float*)d_in[6];
  const float* bv = (const float*)d_in[7];
  const float* wo = (const float*)d_in[8];
  const float* bo = (const float*)d_in[9];
  const float* w1 = (const float*)d_in[10];
  const float* b1 = (const float*)d_in[11];
  const float* w2 = (const float*)d_in[12];
  const float* b2 = (const float*)d_in[13];
  const float* ln1a = (const float*)d_in[14];
  const float* ln1b = (const float*)d_in[15];
  const float* ln2a = (const float*)d_in[16];
  const float* ln2b = (const float*)d_in[17];
  float* out = (float*)d_out;
  char* W = (char*)d_ws;
  const size_t MB = 1u << 20;

  // layout (82 MB total):
  unsigned short* wqkT = (unsigned short*)(W + 0 * MB);   // 4 MB [2048][1024]
  unsigned short* wvT  = (unsigned short*)(W + 4 * MB);   // 2 MB
  unsigned short* woT  = (unsigned short*)(W + 6 * MB);   // 2 MB
  unsigned short* w1T  = (unsigned short*)(W + 8 * MB);   // 8 MB
  unsigned short* w2T  = (unsigned short*)(W + 16 * MB);  // 8 MB
  float*          bqk  = (float*)(W + 24 * MB);           // 8 KB
  unsigned short* xn   = (unsigned short*)(W + 25 * MB);  // 8 MB
  unsigned short* qkb  = (unsigned short*)(W + 33 * MB);  // 16 MB [4096][2048]
  unsigned short* vT   = (unsigned short*)(W + 49 * MB);  // 8 MB [1024][4096]
  unsigned short* ctx  = (unsigned short*)(W + 57 * MB);  // 8 MB
  float*          corr = (float*)(W + 65 * MB);           // 16 KB
  float*          x1   = (float*)(W + 66 * MB);           // 16 MB (66-82)
  unsigned short* xn2  = xn;                              // reuse (xn dead)
  unsigned short* hb   = qkb;  // 32 MB @33-65: qkb/vT/ctx dead after wo-proj

  wconv_kernel<<<3073, 256, 0, stream>>>(wq, wk, wv, wo, w1, w2, bq, bk,
                                         wqkT, wvT, woT, w1T, w2T, bqk);
  ln_kernel<<<4096, 256, 0, stream>>>(x, xn, ln1a, ln1b);
  // fused q|k: [4096][2048] = xn @ [wq|wk], 512 blocks
  mfma_gemm<128, 128, true, false, false, false><<<dim3(16, 32), 256, 0, stream>>>(
      xn, wqkT, bqk, nullptr, qkb, 4096, 2048, 1024);
  // vT[hd][token] = wvT @ xn^T, 64x128 tiles -> 512 blocks, bias per-m
  mfma_gemm<64, 128, true, true, false, false><<<dim3(32, 16), 256, 0, stream>>>(
      wvT, xn, bv, nullptr, vT, 1024, 4096, 1024);
  masksum_kernel<<<dim3(16, 4), 256, 0, stream>>>(vT, mask, corr);
  attn_kernel<<<dim3(8, 16, 4), 256, 0, stream>>>(qkb, vT, mask, corr, ctx);
  // x1 = x + ctx@wo + bo, 128x64 tiles -> 512 blocks, fp32 out
  mfma_gemm<128, 64, false, false, false, true><<<dim3(16, 32), 256, 0, stream>>>(
      ctx, woT, bo, x, x1, 4096, 1024, 1024);
  ln_kernel<<<4096, 256, 0, stream>>>(x1, xn2, ln2a, ln2b);
  // FFN, full 4096 rows: ffn1 1024 blocks, ffn2 512 blocks
  mfma_gemm<128, 128, true, false, true, false><<<dim3(32, 32), 256, 0, stream>>>(
      xn2, w1T, b1, nullptr, hb, 4096, 4096, 1024);
  mfma_gemm<128, 64, false, false, false, true><<<dim3(16, 32), 256, 0, stream>>>(
      hb, w2T, b2, x1, out, 4096, 1024, 4096);
}

// Round 4
// 406.284 us; speedup vs baseline: 6.4979x; 1.0301x over previous
//
#include <hip/hip_runtime.h>
#include <hip/hip_bf16.h>
#include <math.h>

// ---------------------------------------------------------------------------
// EncoderBlock, bf16-MFMA, round 4:
//  - split-K (gridDim.z=2) 128x128 GEMMs for wo-proj and ffn2 (keeps 16-MFMA
//    per-wave density AND >=512 blocks)
//  - combine+LN2 fused kernel (wo partials + bias + residual -> x1, xn2)
//  - ffn2 combine kernel (p0 + out + b2 + x1)
//  - attention: S^T via swapped MFMA operands -> P packed as ds_write_b64
//    (4 writes/thread/iter instead of 16 scalar b16 writes)
// ---------------------------------------------------------------------------

#define EPS 1e-5f

typedef __attribute__((ext_vector_type(8))) short bf16x8;
typedef __attribute__((ext_vector_type(4))) float f32x4;

typedef const __attribute__((address_space(1))) unsigned char glob_byte;
typedef __attribute__((address_space(3))) unsigned char lds_byte;

__device__ __forceinline__ void g2l16(const void* g, void* l) {
  __builtin_amdgcn_global_load_lds((glob_byte*)g, (lds_byte*)l, 16, 0, 0);
}

__device__ __forceinline__ unsigned short f2bf(float f) {
  union { float f; unsigned int u; } v; v.f = f;
  return (unsigned short)((v.u + 0x7FFFu + ((v.u >> 16) & 1u)) >> 16);
}
__device__ __forceinline__ float bf2f(unsigned short b) {
  union { unsigned int u; float f; } v; v.u = (unsigned int)b << 16;
  return v.f;
}

// ---- weight fp32 [K][N] -> bf16 transposed [N][K]; also fused qk bias.
__global__ __launch_bounds__(256) void wconv_kernel(
    const float* __restrict__ wq, const float* __restrict__ wk,
    const float* __restrict__ wv, const float* __restrict__ wo,
    const float* __restrict__ w1, const float* __restrict__ w2,
    const float* __restrict__ bq, const float* __restrict__ bk,
    unsigned short* __restrict__ wqkT, unsigned short* __restrict__ wvT,
    unsigned short* __restrict__ woT, unsigned short* __restrict__ w1T,
    unsigned short* __restrict__ w2T, float* __restrict__ bqk) {
  const int bid = blockIdx.x;
  const int t = threadIdx.x;
  if (bid == 3072) {
#pragma unroll
    for (int i = 0; i < 8; ++i) {
      const int n = i * 256 + t;
      bqk[n] = n < 1024 ? bq[n] : bk[n - 1024];
    }
    return;
  }
  __shared__ float tile[64][65];
  const float* src; unsigned short* dst; int K, N, tk, tn;
  if (bid < 1024) {
    const int m = bid >> 8, loc = bid & 255;
    src = m == 0 ? wq : m == 1 ? wk : m == 2 ? wv : wo;
    dst = m == 0 ? wqkT : m == 1 ? (wqkT + (size_t)1024 * 1024)
                        : m == 2 ? wvT : woT;
    K = 1024; N = 1024; tk = loc >> 4; tn = loc & 15;
  } else if (bid < 2048) {
    const int loc = bid - 1024; src = w1; dst = w1T;
    K = 1024; N = 4096; tk = loc >> 6; tn = loc & 63;
  } else {
    const int loc = bid - 2048; src = w2; dst = w2T;
    K = 4096; N = 1024; tk = loc >> 4; tn = loc & 15;
  }
  const int lr = t >> 4, lc = (t & 15) * 4;
#pragma unroll
  for (int i = 0; i < 4; ++i) {
    const float4 v = *(const float4*)(src + (size_t)(tk * 64 + lr + 16 * i) * N + tn * 64 + lc);
    tile[lr + 16 * i][lc + 0] = v.x;
    tile[lr + 16 * i][lc + 1] = v.y;
    tile[lr + 16 * i][lc + 2] = v.z;
    tile[lr + 16 * i][lc + 3] = v.w;
  }
  __syncthreads();
  const int on = t >> 2, ok = (t & 3) * 16;
#pragma unroll
  for (int jj = 0; jj < 4; ++jj) {
    ushort4 o4;
    o4.x = f2bf(tile[ok + 4 * jj + 0][on]);
    o4.y = f2bf(tile[ok + 4 * jj + 1][on]);
    o4.z = f2bf(tile[ok + 4 * jj + 2][on]);
    o4.w = f2bf(tile[ok + 4 * jj + 3][on]);
    *(ushort4*)(dst + (size_t)(tn * 64 + on) * K + tk * 64 + ok + 4 * jj) = o4;
  }
}

// ---- LayerNorm (torch: ddof=1, /(std+eps)), fp32 in -> bf16 out.
__global__ __launch_bounds__(256) void ln_kernel(
    const float* __restrict__ x, unsigned short* __restrict__ y,
    const float* __restrict__ alpha, const float* __restrict__ beta) {
  const int row = blockIdx.x;
  const float4 v = ((const float4*)(x + (size_t)row * 1024))[threadIdx.x];
  float s  = v.x + v.y + v.z + v.w;
  float ss = v.x * v.x + v.y * v.y + v.z * v.z + v.w * v.w;
#pragma unroll
  for (int off = 32; off > 0; off >>= 1) {
    s  += __shfl_down(s, off, 64);
    ss += __shfl_down(ss, off, 64);
  }
  __shared__ float red[8];
  const int lane = threadIdx.x & 63, wv_ = threadIdx.x >> 6;
  if (lane == 0) { red[wv_] = s; red[4 + wv_] = ss; }
  __syncthreads();
  const float S  = red[0] + red[1] + red[2] + red[3];
  const float SS = red[4] + red[5] + red[6] + red[7];
  const float mean = S * (1.0f / 1024.0f);
  float var = (SS - 1024.0f * mean * mean) * (1.0f / 1023.0f);
  var = fmaxf(var, 0.0f);
  const float scl = alpha[0] / (sqrtf(var) + EPS);
  const float b = beta[0];
  ushort4 o;
  o.x = f2bf((v.x - mean) * scl + b);
  o.y = f2bf((v.y - mean) * scl + b);
  o.z = f2bf((v.z - mean) * scl + b);
  o.w = f2bf((v.w - mean) * scl + b);
  ((ushort4*)(y + (size_t)row * 1024))[threadIdx.x] = o;
}

// ---- bf16 MFMA GEMM. A:[M][K-lda], Bt:[N][K-ldb] bf16 row-major. Tile TMxTN.
// SPLITK: gridDim.z=2, z*KH K-offset; z=0 -> C0 (fp32 raw), z=1 -> C1.
template <int TM, int TN, bool OUT_BF16, bool BIAS_M, bool RELU, bool RES, bool SPLITK>
__global__ __launch_bounds__(256, 2) void mfma_gemm(
    const unsigned short* __restrict__ A, const unsigned short* __restrict__ Bt,
    const float* __restrict__ bias, const float* __restrict__ res,
    void* __restrict__ C0, void* __restrict__ C1,
    int N, int lda, int ldb, int KH) {
  constexpr int WM = (TM == 128) ? ((TN == 128) ? 2 : 4) : 1;
  constexpr int WN = 4 / WM;
  constexpr int MSPAN = TM / WM, NSPAN = TN / WN;
  constexpr int MI = MSPAN / 16, NJ = NSPAN / 16;
  __shared__ __align__(16) unsigned short As[TM * 32];
  __shared__ __align__(16) unsigned short Bs[TN * 32];
  const int tid = threadIdx.x, lane = tid & 63;
  const int w = tid >> 6;
  const int quad = lane >> 4, col = lane & 15;
  const int wm = w % WM, wn = w / WM;
  const int m0 = blockIdx.y * TM, n0 = blockIdx.x * TN;
  const int koff = SPLITK ? blockIdx.z * KH : 0;

  f32x4 acc[MI][NJ];
  const f32x4 z4 = {0.f, 0.f, 0.f, 0.f};
#pragma unroll
  for (int i = 0; i < MI; ++i)
#pragma unroll
    for (int j = 0; j < NJ; ++j) acc[i][j] = z4;

  for (int k0 = 0; k0 < KH; k0 += 32) {
    __syncthreads();
#pragma unroll
    for (int t = 0; t < TM / 64; ++t) {
      const int s = t * 256 + tid;
      const int r = s >> 2, c = s & 3;
      g2l16(A + (size_t)(m0 + r) * lda + koff + k0 + c * 8, (void*)(As + s * 8));
    }
#pragma unroll
    for (int t = 0; t < TN / 64; ++t) {
      const int s = t * 256 + tid;
      const int r = s >> 2, c = s & 3;
      g2l16(Bt + (size_t)(n0 + r) * ldb + koff + k0 + c * 8, (void*)(Bs + s * 8));
    }
    __syncthreads();
    bf16x8 af[MI], bfr[NJ];
#pragma unroll
    for (int i = 0; i < MI; ++i)
      af[i] = *(const bf16x8*)(As + (wm * MSPAN + i * 16 + col) * 32 + quad * 8);
#pragma unroll
    for (int j = 0; j < NJ; ++j)
      bfr[j] = *(const bf16x8*)(Bs + (wn * NSPAN + j * 16 + col) * 32 + quad * 8);
#pragma unroll
    for (int i = 0; i < MI; ++i)
#pragma unroll
      for (int j = 0; j < NJ; ++j)
        acc[i][j] = __builtin_amdgcn_mfma_f32_16x16x32_bf16(af[i], bfr[j], acc[i][j], 0, 0, 0);
  }
#pragma unroll
  for (int i = 0; i < MI; ++i) {
    const int mrow = m0 + wm * MSPAN + i * 16 + quad * 4;
#pragma unroll
    for (int j = 0; j < NJ; ++j) {
      const int n = n0 + wn * NSPAN + j * 16 + col;
      const float bn = (SPLITK || BIAS_M) ? 0.f : bias[n];
#pragma unroll
      for (int r = 0; r < 4; ++r) {
        const int m = mrow + r;
        if (SPLITK) {
          float* P = blockIdx.z ? (float*)C1 : (float*)C0;
          P[(size_t)m * N + n] = acc[i][j][r];
        } else {
          float v = acc[i][j][r] + (BIAS_M ? bias[m] : bn);
          if (RES)  v += res[(size_t)m * N + n];
          if (RELU) v = fmaxf(v, 0.f);
          if (OUT_BF16) ((unsigned short*)C0)[(size_t)m * N + n] = f2bf(v);
          else          ((float*)C0)[(size_t)m * N + n] = v;
        }
      }
    }
  }
}

// ---- combine wo-proj partials + bias + residual, then LayerNorm2.
// x1 = p0 + p1 + bo + x ; xn2 = LN(x1). p1 may alias x1 (same-thread RMW).
__global__ __launch_bounds__(256) void combine_ln_kernel(
    const float* __restrict__ p0, const float* p1, const float* __restrict__ x,
    const float* __restrict__ bo, const float* __restrict__ alpha,
    const float* __restrict__ beta, float* x1, unsigned short* __restrict__ xn2) {
  const int row = blockIdx.x, t = threadIdx.x;
  const size_t i = (size_t)row * 256 + t;
  const float4 a = ((const float4*)p0)[i];
  const float4 b4 = ((const float4*)p1)[i];
  const float4 c4 = ((const float4*)x)[i];
  const float4 d4 = ((const float4*)bo)[t];
  float4 v;
  v.x = a.x + b4.x + c4.x + d4.x;
  v.y = a.y + b4.y + c4.y + d4.y;
  v.z = a.z + b4.z + c4.z + d4.z;
  v.w = a.w + b4.w + c4.w + d4.w;
  ((float4*)x1)[i] = v;
  float s  = v.x + v.y + v.z + v.w;
  float ss = v.x * v.x + v.y * v.y + v.z * v.z + v.w * v.w;
#pragma unroll
  for (int off = 32; off > 0; off >>= 1) {
    s  += __shfl_down(s, off, 64);
    ss += __shfl_down(ss, off, 64);
  }
  __shared__ float red[8];
  const int lane = t & 63, wv_ = t >> 6;
  if (lane == 0) { red[wv_] = s; red[4 + wv_] = ss; }
  __syncthreads();
  const float S  = red[0] + red[1] + red[2] + red[3];
  const float SS = red[4] + red[5] + red[6] + red[7];
  const float mean = S * (1.0f / 1024.0f);
  float var = (SS - 1024.0f * mean * mean) * (1.0f / 1023.0f);
  var = fmaxf(var, 0.0f);
  const float scl = alpha[0] / (sqrtf(var) + EPS);
  const float bb = beta[0];
  ushort4 o;
  o.x = f2bf((v.x - mean) * scl + bb);
  o.y = f2bf((v.y - mean) * scl + bb);
  o.z = f2bf((v.z - mean) * scl + bb);
  o.w = f2bf((v.w - mean) * scl + bb);
  ((ushort4*)xn2)[i] = o;
}

// ---- combine ffn2 partials: out = p0 + out + b2 + x1  (all fp32)
__global__ __launch_bounds__(256) void combine_out_kernel(
    const float* __restrict__ p0, const float* __restrict__ b2,
    const float* __restrict__ x1, float* out) {
  const size_t stride = (size_t)gridDim.x * 256;
  for (size_t i = (size_t)blockIdx.x * 256 + threadIdx.x; i < 4096u * 256u; i += stride) {
    const float4 a = ((const float4*)p0)[i];
    const float4 b4 = ((const float4*)out)[i];
    const float4 c4 = ((const float4*)x1)[i];
    const float4 d4 = ((const float4*)b2)[i & 255];
    float4 v;
    v.x = a.x + b4.x + c4.x + d4.x;
    v.y = a.y + b4.y + c4.y + d4.y;
    v.z = a.z + b4.z + c4.z + d4.z;
    v.w = a.w + b4.w + c4.w + d4.w;
    ((float4*)out)[i] = v;
  }
}

// ---- corr[b][hd] = -1e9 * sum_{s: mask[b][s]==0} V[s][hd]  (from vT bf16)
__global__ __launch_bounds__(256) void masksum_kernel(
    const unsigned short* __restrict__ vT, const int* __restrict__ mask,
    float* __restrict__ corr) {
  const int hg = blockIdx.x, b = blockIdx.y, t = threadIdx.x;
  const int hd = hg * 64 + (t & 63), sg = t >> 6;
  const int* mrow = mask + b * 1024;
  const unsigned short* vrow = vT + (size_t)hd * 4096 + b * 1024 + sg * 256;
  float s = 0.f;
  for (int i = 0; i < 256; ++i)
    if (mrow[sg * 256 + i] == 0) s += bf2f(vrow[i]);
  __shared__ float red[4][64];
  red[sg][t & 63] = s;
  __syncthreads();
  if (sg == 0)
    corr[b * 1024 + hd] = -1e9f * (red[0][t] + red[1][t] + red[2][t] + red[3][t]);
}

// ---- fused attention: ctx[token][hd] = (mask? QK^T/8 : 0)@V + corr
// S^T computed via swapped MFMA operands so each lane's 4 acc values are
// consecutive KEYS -> packed ds_write_b64 into Ps (16B-pair XOR swizzle).
__global__ __launch_bounds__(256, 2) void attn_kernel(
    const unsigned short* __restrict__ qkb, const unsigned short* __restrict__ vT,
    const int* __restrict__ mask, const float* __restrict__ corr,
    unsigned short* __restrict__ ctx) {
  __shared__ __align__(16) unsigned short Qs[128 * 64];
  __shared__ __align__(16) unsigned short Ks[32 * 64];
  __shared__ __align__(16) unsigned short Vs[64 * 32];
  __shared__ __align__(16) unsigned short Ps[128 * 32];
  const int tid = threadIdx.x, lane = tid & 63, w = tid >> 6;
  const int quad = lane >> 4, col = lane & 15;
  const int b = blockIdx.z, h = blockIdx.y, q0 = blockIdx.x * 128;
  const size_t qbase = ((size_t)(b * 1024 + q0)) * 2048 + h * 64;

#pragma unroll
  for (int t = 0; t < 4; ++t) {
    const int s = t * 256 + w * 64 + lane;
    const int m = s >> 3, c = (s & 7) ^ (m & 7);
    g2l16(qkb + qbase + (size_t)m * 2048 + c * 8, (void*)(Qs + s * 8));
  }
  __syncthreads();
  bf16x8 qf[2][2];
#pragma unroll
  for (int qt = 0; qt < 2; ++qt)
#pragma unroll
    for (int kf = 0; kf < 2; ++kf) {
      const int m = (w * 2 + qt) * 16 + col;
      const int c = (kf * 4 + quad) ^ (m & 7);
      qf[qt][kf] = *(const bf16x8*)(Qs + m * 64 + c * 8);
    }

  const f32x4 z4 = {0.f, 0.f, 0.f, 0.f};
  f32x4 oacc[2][4];
#pragma unroll
  for (int qt = 0; qt < 2; ++qt)
#pragma unroll
    for (int nt = 0; nt < 4; ++nt) oacc[qt][nt] = z4;

  const int* mrow = mask + b * 1024;
  for (int kb = 0; kb < 1024; kb += 32) {
    __syncthreads();
    {
      const int s = w * 64 + lane;
      const int key = s >> 3, ck = (s & 7) ^ (key & 7);
      g2l16(qkb + ((size_t)(b * 1024 + kb + key)) * 2048 + 1024 + h * 64 + ck * 8,
            (void*)(Ks + s * 8));
      const int d = s >> 2, cv = s & 3;
      g2l16(vT + ((size_t)(h * 64 + d)) * 4096 + b * 1024 + kb + cv * 8,
            (void*)(Vs + s * 8));
    }
    __syncthreads();

    // S^T = K Q^T : C rows = key (kt*16 + quad*4 + r), cols = q (tile col)
    f32x4 st[2][2];  // [qt][kt]
#pragma unroll
    for (int qt = 0; qt < 2; ++qt)
#pragma unroll
      for (int kt = 0; kt < 2; ++kt) st[qt][kt] = z4;
#pragma unroll
    for (int kt = 0; kt < 2; ++kt)
#pragma unroll
      for (int kf = 0; kf < 2; ++kf) {
        const int key = kt * 16 + col;
        const int c = (kf * 4 + quad) ^ (key & 7);
        const bf16x8 kfrag = *(const bf16x8*)(Ks + key * 64 + c * 8);
#pragma unroll
        for (int qt = 0; qt < 2; ++qt)
          st[qt][kt] = __builtin_amdgcn_mfma_f32_16x16x32_bf16(
              kfrag, qf[qt][kf], st[qt][kt], 0, 0, 0);
      }

    // mask + scale + pack 4 keys -> one b64 write per (qt,kt)
    const int4 mv0 = *(const int4*)(mrow + kb + quad * 4);
    const int4 mv1 = *(const int4*)(mrow + kb + 16 + quad * 4);
#pragma unroll
    for (int qt = 0; qt < 2; ++qt) {
      const int qrow = (w * 2 + qt) * 16 + col;
#pragma unroll
      for (int kt = 0; kt < 2; ++kt) {
        const int4 mv = kt ? mv1 : mv0;
        const f32x4 sv = st[qt][kt];
        const unsigned int u0 = mv.x ? f2bf(sv[0] * 0.125f) : 0u;
        const unsigned int u1 = mv.y ? f2bf(sv[1] * 0.125f) : 0u;
        const unsigned int u2 = mv.z ? f2bf(sv[2] * 0.125f) : 0u;
        const unsigned int u3 = mv.w ? f2bf(sv[3] * 0.125f) : 0u;
        uint2 pk;
        pk.x = u0 | (u1 << 16);
        pk.y = u2 | (u3 << 16);
        const int pp = kt * 2 + (quad >> 1);
        *(uint2*)(Ps + qrow * 32 + ((pp ^ (qrow & 3)) * 8 + (quad & 1) * 4)) = pk;
      }
    }
    // no barrier: wave w only touches its own q-rows [w*32, w*32+32)

    // oacc += P @ V
#pragma unroll
    for (int qt = 0; qt < 2; ++qt) {
      const int qrow = (w * 2 + qt) * 16 + col;
      const bf16x8 pf = *(const bf16x8*)(Ps + qrow * 32 + (quad ^ (qrow & 3)) * 8);
#pragma unroll
      for (int nt = 0; nt < 4; ++nt) {
        const bf16x8 vf = *(const bf16x8*)(Vs + (nt * 16 + col) * 32 + quad * 8);
        oacc[qt][nt] = __builtin_amdgcn_mfma_f32_16x16x32_bf16(pf, vf, oacc[qt][nt], 0, 0, 0);
      }
    }
  }

  const float* crow = corr + b * 1024 + h * 64;
#pragma unroll
  for (int qt = 0; qt < 2; ++qt)
#pragma unroll
    for (int nt = 0; nt < 4; ++nt) {
      const int d = nt * 16 + col;
      const float cv = crow[d];
#pragma unroll
      for (int r = 0; r < 4; ++r) {
        const int qq = q0 + (w * 2 + qt) * 16 + quad * 4 + r;
        ctx[((size_t)(b * 1024) + qq) * 1024 + h * 64 + d] = f2bf(oacc[qt][nt][r] + cv);
      }
    }
}

extern "C" void kernel_launch(void* const* d_in, const int* in_sizes, int n_in,
                              void* d_out, int out_size, void* d_ws, size_t ws_size,
                              hipStream_t stream) {
  const float* x    = (const float*)d_in[0];
  const int*   mask = (const int*)d_in[1];
  const float* wq = (const float*)d_in[2];
  const float* bq = (const float*)d_in[3];
  const float* wk = (const float*)d_in[4];
  const float* bk = (const float*)d_in[5];
  const float* wv = (const float*)d_in[6];
  const float* bv = (const float*)d_in[7];
  const float* wo = (const float*)d_in[8];
  const float* bo = (const float*)d_in[9];
  const float* w1 = (const float*)d_in[10];
  const float* b1 = (const float*)d_in[11];
  const float* w2 = (const float*)d_in[12];
  const float* b2 = (const float*)d_in[13];
  const float* ln1a = (const float*)d_in[14];
  const float* ln1b = (const float*)d_in[15];
  const float* ln2a = (const float*)d_in[16];
  const float* ln2b = (const float*)d_in[17];
  float* out = (float*)d_out;
  char* W = (char*)d_ws;
  const size_t MB = 1u << 20;

  // layout (82 MB):
  unsigned short* wqkT = (unsigned short*)(W + 0 * MB);   // 4 MB [2048][1024]
  unsigned short* wvT  = (unsigned short*)(W + 4 * MB);   // 2 MB
  unsigned short* woT  = (unsigned short*)(W + 6 * MB);   // 2 MB
  unsigned short* w1T  = (unsigned short*)(W + 8 * MB);   // 8 MB
  unsigned short* w2T  = (unsigned short*)(W + 16 * MB);  // 8 MB
  float*          bqk  = (float*)(W + 24 * MB);           // 8 KB
  float*          corr = (float*)(W + 24 * MB + 65536);   // 16 KB
  unsigned short* xn   = (unsigned short*)(W + 25 * MB);  // 8 MB (xn / xn2)
  unsigned short* qkb  = (unsigned short*)(W + 33 * MB);  // 16 MB [4096][2048]
  unsigned short* vT   = (unsigned short*)(W + 49 * MB);  // 8 MB [1024][4096]
  unsigned short* ctx  = (unsigned short*)(W + 57 * MB);  // 8 MB
  float*          x1   = (float*)(W + 66 * MB);           // 16 MB (66-82)
  unsigned short* xn2  = xn;                              // reuse
  float*          p0wo = (float*)(W + 33 * MB);           // 16 MB (qkb dead)
  float*          p0f2 = (float*)(W + 0 * MB);            // 16 MB (weights dead)
  unsigned short* hb   = qkb;                             // 32 MB @33-65

  wconv_kernel<<<3073, 256, 0, stream>>>(wq, wk, wv, wo, w1, w2, bq, bk,
                                         wqkT, wvT, woT, w1T, w2T, bqk);
  ln_kernel<<<4096, 256, 0, stream>>>(x, xn, ln1a, ln1b);
  // fused q|k: [4096][2048] = xn @ [wq|wk]^T, 512 blocks
  mfma_gemm<128, 128, true, false, false, false, false><<<dim3(16, 32), 256, 0, stream>>>(
      xn, wqkT, bqk, nullptr, qkb, nullptr, 2048, 1024, 1024, 1024);
  // vT[hd][token] = wvT @ xn^T, 64x128 tiles -> 512 blocks, bias per-m
  mfma_gemm<64, 128, true, true, false, false, false><<<dim3(32, 16), 256, 0, stream>>>(
      wvT, xn, bv, nullptr, vT, nullptr, 4096, 1024, 1024, 1024);
  masksum_kernel<<<dim3(16, 4), 256, 0, stream>>>(vT, mask, corr);
  attn_kernel<<<dim3(8, 16, 4), 256, 0, stream>>>(qkb, vT, mask, corr, ctx);
  // wo-proj split-K: 2x(8x32)=512 blocks of 128x128, KH=512 -> p0wo / x1(raw)
  mfma_gemm<128, 128, false, false, false, false, true><<<dim3(8, 32, 2), 256, 0, stream>>>(
      ctx, woT, nullptr, nullptr, p0wo, x1, 1024, 1024, 1024, 512);
  // x1 = p0 + p1 + bo + x ; xn2 = LN2(x1)
  combine_ln_kernel<<<4096, 256, 0, stream>>>(p0wo, x1, x, bo, ln2a, ln2b, x1, xn2);
  // FFN1: 1024 blocks
  mfma_gemm<128, 128, true, false, true, false, false><<<dim3(32, 32), 256, 0, stream>>>(
      xn2, w1T, b1, nullptr, hb, nullptr, 4096, 1024, 1024, 1024);
  // FFN2 split-K: 2x(8x32)=512 blocks of 128x128, KH=2048 -> p0f2 / out(raw)
  mfma_gemm<128, 128, false, false, false, false, true><<<dim3(8, 32, 2), 256, 0, stream>>>(
      hb, w2T, nullptr, nullptr, p0f2, out, 1024, 4096, 4096, 2048);
  // out = p0 + out + b2 + x1
  combine_out_kernel<<<4096, 256, 0, stream>>>(p0f2, b2, x1, out);
}

// Round 5
// 393.394 us; speedup vs baseline: 6.7109x; 1.0328x over previous
//
#include <hip/hip_runtime.h>
#include <hip/hip_bf16.h>
#include <math.h>

// ---------------------------------------------------------------------------
// EncoderBlock, bf16-MFMA, round 5: XCD-locality block swizzle.
// Blocks sharing an A-tile (GEMM) / a (b,h) KV-stream (attn) are remapped to
// the same linear_id%8 residue -> same XCD -> A fetched once per XCD L2
// instead of 8x. (Round-4 counters: ffn2 FETCH=135MB ~= 8x its 16MB K-half.)
// ---------------------------------------------------------------------------

#define EPS 1e-5f

typedef __attribute__((ext_vector_type(8))) short bf16x8;
typedef __attribute__((ext_vector_type(4))) float f32x4;

typedef const __attribute__((address_space(1))) unsigned char glob_byte;
typedef __attribute__((address_space(3))) unsigned char lds_byte;

__device__ __forceinline__ void g2l16(const void* g, void* l) {
  __builtin_amdgcn_global_load_lds((glob_byte*)g, (lds_byte*)l, 16, 0, 0);
}

__device__ __forceinline__ unsigned short f2bf(float f) {
  union { float f; unsigned int u; } v; v.f = f;
  return (unsigned short)((v.u + 0x7FFFu + ((v.u >> 16) & 1u)) >> 16);
}
__device__ __forceinline__ float bf2f(unsigned short b) {
  union { unsigned int u; float f; } v; v.u = (unsigned int)b << 16;
  return v.f;
}

// ---- weight fp32 [K][N] -> bf16 transposed [N][K]; also fused qk bias.
__global__ __launch_bounds__(256) void wconv_kernel(
    const float* __restrict__ wq, const float* __restrict__ wk,
    const float* __restrict__ wv, const float* __restrict__ wo,
    const float* __restrict__ w1, const float* __restrict__ w2,
    const float* __restrict__ bq, const float* __restrict__ bk,
    unsigned short* __restrict__ wqkT, unsigned short* __restrict__ wvT,
    unsigned short* __restrict__ woT, unsigned short* __restrict__ w1T,
    unsigned short* __restrict__ w2T, float* __restrict__ bqk) {
  const int bid = blockIdx.x;
  const int t = threadIdx.x;
  if (bid == 3072) {
#pragma unroll
    for (int i = 0; i < 8; ++i) {
      const int n = i * 256 + t;
      bqk[n] = n < 1024 ? bq[n] : bk[n - 1024];
    }
    return;
  }
  __shared__ float tile[64][65];
  const float* src; unsigned short* dst; int K, N, tk, tn;
  if (bid < 1024) {
    const int m = bid >> 8, loc = bid & 255;
    src = m == 0 ? wq : m == 1 ? wk : m == 2 ? wv : wo;
    dst = m == 0 ? wqkT : m == 1 ? (wqkT + (size_t)1024 * 1024)
                        : m == 2 ? wvT : woT;
    K = 1024; N = 1024; tk = loc >> 4; tn = loc & 15;
  } else if (bid < 2048) {
    const int loc = bid - 1024; src = w1; dst = w1T;
    K = 1024; N = 4096; tk = loc >> 6; tn = loc & 63;
  } else {
    const int loc = bid - 2048; src = w2; dst = w2T;
    K = 4096; N = 1024; tk = loc >> 4; tn = loc & 15;
  }
  const int lr = t >> 4, lc = (t & 15) * 4;
#pragma unroll
  for (int i = 0; i < 4; ++i) {
    const float4 v = *(const float4*)(src + (size_t)(tk * 64 + lr + 16 * i) * N + tn * 64 + lc);
    tile[lr + 16 * i][lc + 0] = v.x;
    tile[lr + 16 * i][lc + 1] = v.y;
    tile[lr + 16 * i][lc + 2] = v.z;
    tile[lr + 16 * i][lc + 3] = v.w;
  }
  __syncthreads();
  const int on = t >> 2, ok = (t & 3) * 16;
#pragma unroll
  for (int jj = 0; jj < 4; ++jj) {
    ushort4 o4;
    o4.x = f2bf(tile[ok + 4 * jj + 0][on]);
    o4.y = f2bf(tile[ok + 4 * jj + 1][on]);
    o4.z = f2bf(tile[ok + 4 * jj + 2][on]);
    o4.w = f2bf(tile[ok + 4 * jj + 3][on]);
    *(ushort4*)(dst + (size_t)(tn * 64 + on) * K + tk * 64 + ok + 4 * jj) = o4;
  }
}

// ---- LayerNorm (torch: ddof=1, /(std+eps)), fp32 in -> bf16 out.
__global__ __launch_bounds__(256) void ln_kernel(
    const float* __restrict__ x, unsigned short* __restrict__ y,
    const float* __restrict__ alpha, const float* __restrict__ beta) {
  const int row = blockIdx.x;
  const float4 v = ((const float4*)(x + (size_t)row * 1024))[threadIdx.x];
  float s  = v.x + v.y + v.z + v.w;
  float ss = v.x * v.x + v.y * v.y + v.z * v.z + v.w * v.w;
#pragma unroll
  for (int off = 32; off > 0; off >>= 1) {
    s  += __shfl_down(s, off, 64);
    ss += __shfl_down(ss, off, 64);
  }
  __shared__ float red[8];
  const int lane = threadIdx.x & 63, wv_ = threadIdx.x >> 6;
  if (lane == 0) { red[wv_] = s; red[4 + wv_] = ss; }
  __syncthreads();
  const float S  = red[0] + red[1] + red[2] + red[3];
  const float SS = red[4] + red[5] + red[6] + red[7];
  const float mean = S * (1.0f / 1024.0f);
  float var = (SS - 1024.0f * mean * mean) * (1.0f / 1023.0f);
  var = fmaxf(var, 0.0f);
  const float scl = alpha[0] / (sqrtf(var) + EPS);
  const float b = beta[0];
  ushort4 o;
  o.x = f2bf((v.x - mean) * scl + b);
  o.y = f2bf((v.y - mean) * scl + b);
  o.z = f2bf((v.z - mean) * scl + b);
  o.w = f2bf((v.w - mean) * scl + b);
  ((ushort4*)(y + (size_t)row * 1024))[threadIdx.x] = o;
}

// ---- bf16 MFMA GEMM. A:[M][lda], Bt:[N][ldb] bf16 row-major. Tile TMxTN.
// SPLITK: gridDim.z=2, z*KH K-offset; z=0 -> C0 (fp32 raw), z=1 -> C1.
// SWZ: remap blocks so all n-columns of one (m,z) tile share an XCD
// (requires gridDim.y*gridDim.z % 8 == 0; bijective remap, order-free).
template <int TM, int TN, bool OUT_BF16, bool BIAS_M, bool RELU, bool RES,
          bool SPLITK, bool SWZ>
__global__ __launch_bounds__(256, 2) void mfma_gemm(
    const unsigned short* __restrict__ A, const unsigned short* __restrict__ Bt,
    const float* __restrict__ bias, const float* __restrict__ res,
    void* __restrict__ C0, void* __restrict__ C1,
    int N, int lda, int ldb, int KH) {
  constexpr int WM = (TM == 128) ? ((TN == 128) ? 2 : 4) : 1;
  constexpr int WN = 4 / WM;
  constexpr int MSPAN = TM / WM, NSPAN = TN / WN;
  constexpr int MI = MSPAN / 16, NJ = NSPAN / 16;
  __shared__ __align__(16) unsigned short As[TM * 32];
  __shared__ __align__(16) unsigned short Bs[TN * 32];
  const int tid = threadIdx.x, lane = tid & 63;
  const int w = tid >> 6;
  const int quad = lane >> 4, col = lane & 15;
  const int wm = w % WM, wn = w / WM;

  int bx = blockIdx.x, by = blockIdx.y, bz = blockIdx.z;
  if (SWZ) {
    const int gx = gridDim.x, gy = gridDim.y;
    const int L = bx + gx * (by + gy * bz);
    const int G = (gy * gridDim.z) >> 3;   // myz-groups per XCD
    const int r = L & 7, s = L >> 3;
    bx = s % gx;
    const int myz = r * G + s / gx;
    by = myz % gy;
    bz = myz / gy;
  }
  const int m0 = by * TM, n0 = bx * TN;
  const int koff = SPLITK ? bz * KH : 0;

  f32x4 acc[MI][NJ];
  const f32x4 z4 = {0.f, 0.f, 0.f, 0.f};
#pragma unroll
  for (int i = 0; i < MI; ++i)
#pragma unroll
    for (int j = 0; j < NJ; ++j) acc[i][j] = z4;

  for (int k0 = 0; k0 < KH; k0 += 32) {
    __syncthreads();
#pragma unroll
    for (int t = 0; t < TM / 64; ++t) {
      const int s = t * 256 + tid;
      const int r = s >> 2, c = s & 3;
      g2l16(A + (size_t)(m0 + r) * lda + koff + k0 + c * 8, (void*)(As + s * 8));
    }
#pragma unroll
    for (int t = 0; t < TN / 64; ++t) {
      const int s = t * 256 + tid;
      const int r = s >> 2, c = s & 3;
      g2l16(Bt + (size_t)(n0 + r) * ldb + koff + k0 + c * 8, (void*)(Bs + s * 8));
    }
    __syncthreads();
    bf16x8 af[MI], bfr[NJ];
#pragma unroll
    for (int i = 0; i < MI; ++i)
      af[i] = *(const bf16x8*)(As + (wm * MSPAN + i * 16 + col) * 32 + quad * 8);
#pragma unroll
    for (int j = 0; j < NJ; ++j)
      bfr[j] = *(const bf16x8*)(Bs + (wn * NSPAN + j * 16 + col) * 32 + quad * 8);
#pragma unroll
    for (int i = 0; i < MI; ++i)
#pragma unroll
      for (int j = 0; j < NJ; ++j)
        acc[i][j] = __builtin_amdgcn_mfma_f32_16x16x32_bf16(af[i], bfr[j], acc[i][j], 0, 0, 0);
  }
#pragma unroll
  for (int i = 0; i < MI; ++i) {
    const int mrow = m0 + wm * MSPAN + i * 16 + quad * 4;
#pragma unroll
    for (int j = 0; j < NJ; ++j) {
      const int n = n0 + wn * NSPAN + j * 16 + col;
      const float bn = (SPLITK || BIAS_M) ? 0.f : bias[n];
#pragma unroll
      for (int r = 0; r < 4; ++r) {
        const int m = mrow + r;
        if (SPLITK) {
          float* P = bz ? (float*)C1 : (float*)C0;
          P[(size_t)m * N + n] = acc[i][j][r];
        } else {
          float v = acc[i][j][r] + (BIAS_M ? bias[m] : bn);
          if (RES)  v += res[(size_t)m * N + n];
          if (RELU) v = fmaxf(v, 0.f);
          if (OUT_BF16) ((unsigned short*)C0)[(size_t)m * N + n] = f2bf(v);
          else          ((float*)C0)[(size_t)m * N + n] = v;
        }
      }
    }
  }
}

// ---- combine wo-proj partials + bias + residual, then LayerNorm2.
__global__ __launch_bounds__(256) void combine_ln_kernel(
    const float* __restrict__ p0, const float* p1, const float* __restrict__ x,
    const float* __restrict__ bo, const float* __restrict__ alpha,
    const float* __restrict__ beta, float* x1, unsigned short* __restrict__ xn2) {
  const int row = blockIdx.x, t = threadIdx.x;
  const size_t i = (size_t)row * 256 + t;
  const float4 a = ((const float4*)p0)[i];
  const float4 b4 = ((const float4*)p1)[i];
  const float4 c4 = ((const float4*)x)[i];
  const float4 d4 = ((const float4*)bo)[t];
  float4 v;
  v.x = a.x + b4.x + c4.x + d4.x;
  v.y = a.y + b4.y + c4.y + d4.y;
  v.z = a.z + b4.z + c4.z + d4.z;
  v.w = a.w + b4.w + c4.w + d4.w;
  ((float4*)x1)[i] = v;
  float s  = v.x + v.y + v.z + v.w;
  float ss = v.x * v.x + v.y * v.y + v.z * v.z + v.w * v.w;
#pragma unroll
  for (int off = 32; off > 0; off >>= 1) {
    s  += __shfl_down(s, off, 64);
    ss += __shfl_down(ss, off, 64);
  }
  __shared__ float red[8];
  const int lane = t & 63, wv_ = t >> 6;
  if (lane == 0) { red[wv_] = s; red[4 + wv_] = ss; }
  __syncthreads();
  const float S  = red[0] + red[1] + red[2] + red[3];
  const float SS = red[4] + red[5] + red[6] + red[7];
  const float mean = S * (1.0f / 1024.0f);
  float var = (SS - 1024.0f * mean * mean) * (1.0f / 1023.0f);
  var = fmaxf(var, 0.0f);
  const float scl = alpha[0] / (sqrtf(var) + EPS);
  const float bb = beta[0];
  ushort4 o;
  o.x = f2bf((v.x - mean) * scl + bb);
  o.y = f2bf((v.y - mean) * scl + bb);
  o.z = f2bf((v.z - mean) * scl + bb);
  o.w = f2bf((v.w - mean) * scl + bb);
  ((ushort4*)xn2)[i] = o;
}

// ---- combine ffn2 partials: out = p0 + out + b2 + x1  (all fp32)
__global__ __launch_bounds__(256) void combine_out_kernel(
    const float* __restrict__ p0, const float* __restrict__ b2,
    const float* __restrict__ x1, float* out) {
  const size_t stride = (size_t)gridDim.x * 256;
  for (size_t i = (size_t)blockIdx.x * 256 + threadIdx.x; i < 4096u * 256u; i += stride) {
    const float4 a = ((const float4*)p0)[i];
    const float4 b4 = ((const float4*)out)[i];
    const float4 c4 = ((const float4*)x1)[i];
    const float4 d4 = ((const float4*)b2)[i & 255];
    float4 v;
    v.x = a.x + b4.x + c4.x + d4.x;
    v.y = a.y + b4.y + c4.y + d4.y;
    v.z = a.z + b4.z + c4.z + d4.z;
    v.w = a.w + b4.w + c4.w + d4.w;
    ((float4*)out)[i] = v;
  }
}

// ---- corr[b][hd] = -1e9 * sum_{s: mask[b][s]==0} V[s][hd]  (from vT bf16)
__global__ __launch_bounds__(256) void masksum_kernel(
    const unsigned short* __restrict__ vT, const int* __restrict__ mask,
    float* __restrict__ corr) {
  const int hg = blockIdx.x, b = blockIdx.y, t = threadIdx.x;
  const int hd = hg * 64 + (t & 63), sg = t >> 6;
  const int* mrow = mask + b * 1024;
  const unsigned short* vrow = vT + (size_t)hd * 4096 + b * 1024 + sg * 256;
  float s = 0.f;
  for (int i = 0; i < 256; ++i)
    if (mrow[sg * 256 + i] == 0) s += bf2f(vrow[i]);
  __shared__ float red[4][64];
  red[sg][t & 63] = s;
  __syncthreads();
  if (sg == 0)
    corr[b * 1024 + hd] = -1e9f * (red[0][t] + red[1][t] + red[2][t] + red[3][t]);
}

// ---- fused attention: ctx[token][hd] = (mask? QK^T/8 : 0)@V + corr
// XCD swizzle: all 8 q-blocks of one (b,h) share a residue -> its 256KB
// K/V stream fetched into one XCD L2 instead of 8.
__global__ __launch_bounds__(256, 2) void attn_kernel(
    const unsigned short* __restrict__ qkb, const unsigned short* __restrict__ vT,
    const int* __restrict__ mask, const float* __restrict__ corr,
    unsigned short* __restrict__ ctx) {
  __shared__ __align__(16) unsigned short Qs[128 * 64];
  __shared__ __align__(16) unsigned short Ks[32 * 64];
  __shared__ __align__(16) unsigned short Vs[64 * 32];
  __shared__ __align__(16) unsigned short Ps[128 * 32];
  const int tid = threadIdx.x, lane = tid & 63, w = tid >> 6;
  const int quad = lane >> 4, col = lane & 15;
  // grid (8,16,4): remap so same (h,b) -> same XCD residue
  const int L = blockIdx.x + 8 * (blockIdx.y + 16 * blockIdx.z);
  const int s_ = L >> 3;
  const int bh = (L & 7) * 8 + (s_ >> 3);    // [0,64)
  const int q0 = (s_ & 7) * 128;
  const int h = bh & 15, b = bh >> 4;
  const size_t qbase = ((size_t)(b * 1024 + q0)) * 2048 + h * 64;

#pragma unroll
  for (int t = 0; t < 4; ++t) {
    const int s = t * 256 + w * 64 + lane;
    const int m = s >> 3, c = (s & 7) ^ (m & 7);
    g2l16(qkb + qbase + (size_t)m * 2048 + c * 8, (void*)(Qs + s * 8));
  }
  __syncthreads();
  bf16x8 qf[2][2];
#pragma unroll
  for (int qt = 0; qt < 2; ++qt)
#pragma unroll
    for (int kf = 0; kf < 2; ++kf) {
      const int m = (w * 2 + qt) * 16 + col;
      const int c = (kf * 4 + quad) ^ (m & 7);
      qf[qt][kf] = *(const bf16x8*)(Qs + m * 64 + c * 8);
    }

  const f32x4 z4 = {0.f, 0.f, 0.f, 0.f};
  f32x4 oacc[2][4];
#pragma unroll
  for (int qt = 0; qt < 2; ++qt)
#pragma unroll
    for (int nt = 0; nt < 4; ++nt) oacc[qt][nt] = z4;

  const int* mrow = mask + b * 1024;
  for (int kb = 0; kb < 1024; kb += 32) {
    __syncthreads();
    {
      const int s = w * 64 + lane;
      const int key = s >> 3, ck = (s & 7) ^ (key & 7);
      g2l16(qkb + ((size_t)(b * 1024 + kb + key)) * 2048 + 1024 + h * 64 + ck * 8,
            (void*)(Ks + s * 8));
      const int d = s >> 2, cv = s & 3;
      g2l16(vT + ((size_t)(h * 64 + d)) * 4096 + b * 1024 + kb + cv * 8,
            (void*)(Vs + s * 8));
    }
    __syncthreads();

    // S^T = K Q^T : C rows = key, cols = q
    f32x4 st[2][2];
#pragma unroll
    for (int qt = 0; qt < 2; ++qt)
#pragma unroll
      for (int kt = 0; kt < 2; ++kt) st[qt][kt] = z4;
#pragma unroll
    for (int kt = 0; kt < 2; ++kt)
#pragma unroll
      for (int kf = 0; kf < 2; ++kf) {
        const int key = kt * 16 + col;
        const int c = (kf * 4 + quad) ^ (key & 7);
        const bf16x8 kfrag = *(const bf16x8*)(Ks + key * 64 + c * 8);
#pragma unroll
        for (int qt = 0; qt < 2; ++qt)
          st[qt][kt] = __builtin_amdgcn_mfma_f32_16x16x32_bf16(
              kfrag, qf[qt][kf], st[qt][kt], 0, 0, 0);
      }

    // mask + scale + pack 4 keys -> one b64 write per (qt,kt)
    const int4 mv0 = *(const int4*)(mrow + kb + quad * 4);
    const int4 mv1 = *(const int4*)(mrow + kb + 16 + quad * 4);
#pragma unroll
    for (int qt = 0; qt < 2; ++qt) {
      const int qrow = (w * 2 + qt) * 16 + col;
#pragma unroll
      for (int kt = 0; kt < 2; ++kt) {
        const int4 mv = kt ? mv1 : mv0;
        const f32x4 sv = st[qt][kt];
        const unsigned int u0 = mv.x ? f2bf(sv[0] * 0.125f) : 0u;
        const unsigned int u1 = mv.y ? f2bf(sv[1] * 0.125f) : 0u;
        const unsigned int u2 = mv.z ? f2bf(sv[2] * 0.125f) : 0u;
        const unsigned int u3 = mv.w ? f2bf(sv[3] * 0.125f) : 0u;
        uint2 pk;
        pk.x = u0 | (u1 << 16);
        pk.y = u2 | (u3 << 16);
        const int pp = kt * 2 + (quad >> 1);
        *(uint2*)(Ps + qrow * 32 + ((pp ^ (qrow & 3)) * 8 + (quad & 1) * 4)) = pk;
      }
    }
    // no barrier: wave w only touches its own q-rows [w*32, w*32+32)

    // oacc += P @ V
#pragma unroll
    for (int qt = 0; qt < 2; ++qt) {
      const int qrow = (w * 2 + qt) * 16 + col;
      const bf16x8 pf = *(const bf16x8*)(Ps + qrow * 32 + (quad ^ (qrow & 3)) * 8);
#pragma unroll
      for (int nt = 0; nt < 4; ++nt) {
        const bf16x8 vf = *(const bf16x8*)(Vs + (nt * 16 + col) * 32 + quad * 8);
        oacc[qt][nt] = __builtin_amdgcn_mfma_f32_16x16x32_bf16(pf, vf, oacc[qt][nt], 0, 0, 0);
      }
    }
  }

  const float* crow = corr + b * 1024 + h * 64;
#pragma unroll
  for (int qt = 0; qt < 2; ++qt)
#pragma unroll
    for (int nt = 0; nt < 4; ++nt) {
      const int d = nt * 16 + col;
      const float cv = crow[d];
#pragma unroll
      for (int r = 0; r < 4; ++r) {
        const int qq = q0 + (w * 2 + qt) * 16 + quad * 4 + r;
        ctx[((size_t)(b * 1024) + qq) * 1024 + h * 64 + d] = f2bf(oacc[qt][nt][r] + cv);
      }
    }
}

extern "C" void kernel_launch(void* const* d_in, const int* in_sizes, int n_in,
                              void* d_out, int out_size, void* d_ws, size_t ws_size,
                              hipStream_t stream) {
  const float* x    = (const float*)d_in[0];
  const int*   mask = (const int*)d_in[1];
  const float* wq = (const float*)d_in[2];
  const float* bq = (const float*)d_in[3];
  const float* wk = (const float*)d_in[4];
  const float* bk = (const float*)d_in[5];
  const float* wv = (const float*)d_in[6];
  const float* bv = (const float*)d_in[7];
  const float* wo = (const float*)d_in[8];
  const float* bo = (const float*)d_in[9];
  const float* w1 = (const float*)d_in[10];
  const float* b1 = (const float*)d_in[11];
  const float* w2 = (const float*)d_in[12];
  const float* b2 = (const float*)d_in[13];
  const float* ln1a = (const float*)d_in[14];
  const float* ln1b = (const float*)d_in[15];
  const float* ln2a = (const float*)d_in[16];
  const float* ln2b = (const float*)d_in[17];
  float* out = (float*)d_out;
  char* W = (char*)d_ws;
  const size_t MB = 1u << 20;

  unsigned short* wqkT = (unsigned short*)(W + 0 * MB);   // 4 MB [2048][1024]
  unsigned short* wvT  = (unsigned short*)(W + 4 * MB);   // 2 MB
  unsigned short* woT  = (unsigned short*)(W + 6 * MB);   // 2 MB
  unsigned short* w1T  = (unsigned short*)(W + 8 * MB);   // 8 MB
  unsigned short* w2T  = (unsigned short*)(W + 16 * MB);  // 8 MB
  float*          bqk  = (float*)(W + 24 * MB);           // 8 KB
  float*          corr = (float*)(W + 24 * MB + 65536);   // 16 KB
  unsigned short* xn   = (unsigned short*)(W + 25 * MB);  // 8 MB (xn / xn2)
  unsigned short* qkb  = (unsigned short*)(W + 33 * MB);  // 16 MB [4096][2048]
  unsigned short* vT   = (unsigned short*)(W + 49 * MB);  // 8 MB [1024][4096]
  unsigned short* ctx  = (unsigned short*)(W + 57 * MB);  // 8 MB
  float*          x1   = (float*)(W + 66 * MB);           // 16 MB (66-82)
  unsigned short* xn2  = xn;                              // reuse
  float*          p0wo = (float*)(W + 33 * MB);           // 16 MB (qkb dead)
  float*          p0f2 = (float*)(W + 0 * MB);            // 16 MB (weights dead)
  unsigned short* hb   = qkb;                             // 32 MB @33-65

  wconv_kernel<<<3073, 256, 0, stream>>>(wq, wk, wv, wo, w1, w2, bq, bk,
                                         wqkT, wvT, woT, w1T, w2T, bqk);
  ln_kernel<<<4096, 256, 0, stream>>>(x, xn, ln1a, ln1b);
  // fused q|k: [4096][2048] = xn @ [wq|wk]^T, 512 blocks, XCD-swizzled
  mfma_gemm<128, 128, true, false, false, false, false, true><<<dim3(16, 32), 256, 0, stream>>>(
      xn, wqkT, bqk, nullptr, qkb, nullptr, 2048, 1024, 1024, 1024);
  // vT[hd][token] = wvT @ xn^T: gx=32 already co-locates same-B-col (no swz)
  mfma_gemm<64, 128, true, true, false, false, false, false><<<dim3(32, 16), 256, 0, stream>>>(
      wvT, xn, bv, nullptr, vT, nullptr, 4096, 1024, 1024, 1024);
  masksum_kernel<<<dim3(16, 4), 256, 0, stream>>>(vT, mask, corr);
  attn_kernel<<<dim3(8, 16, 4), 256, 0, stream>>>(qkb, vT, mask, corr, ctx);
  // wo-proj split-K: 512 blocks of 128x128, KH=512, XCD-swizzled
  mfma_gemm<128, 128, false, false, false, false, true, true><<<dim3(8, 32, 2), 256, 0, stream>>>(
      ctx, woT, nullptr, nullptr, p0wo, x1, 1024, 1024, 1024, 512);
  combine_ln_kernel<<<4096, 256, 0, stream>>>(p0wo, x1, x, bo, ln2a, ln2b, x1, xn2);
  // FFN1: gx=32 natural co-location (no swz)
  mfma_gemm<128, 128, true, false, true, false, false, false><<<dim3(32, 32), 256, 0, stream>>>(
      xn2, w1T, b1, nullptr, hb, nullptr, 4096, 1024, 1024, 1024);
  // FFN2 split-K: 512 blocks of 128x128, KH=2048, XCD-swizzled
  mfma_gemm<128, 128, false, false, false, false, true, true><<<dim3(8, 32, 2), 256, 0, stream>>>(
      hb, w2T, nullptr, nullptr, p0f2, out, 1024, 4096, 4096, 2048);
  combine_out_kernel<<<4096, 256, 0, stream>>>(p0f2, b2, x1, out);
}

// Round 6
// 380.008 us; speedup vs baseline: 6.9472x; 1.0352x over previous
//
#include <hip/hip_runtime.h>
#include <hip/hip_bf16.h>
#include <math.h>

// ---------------------------------------------------------------------------
// EncoderBlock, bf16-MFMA, round 6:
//  - fused QKV GEMM (N=3072, 768 blocks, full 16-MFMA density); v transposed
//    by a small LDS kernel that also computes the masked-V sums (atomics)
//  - As/Bs chunk XOR-swizzle: fragment ds_read_b128 8-way -> 4-way conflicts
//    (swizzle on the GLOBAL chunk index; LDS slots stay lane-linear = g2l16-safe)
//  - split-K partials + x1 in bf16 (halved combine traffic)
//  - 2D L2-region swizzle: each XCD owns a compact RX x RY tile rectangle
// ---------------------------------------------------------------------------

#define EPS 1e-5f

typedef __attribute__((ext_vector_type(8))) short bf16x8;
typedef __attribute__((ext_vector_type(4))) float f32x4;

typedef const __attribute__((address_space(1))) unsigned char glob_byte;
typedef __attribute__((address_space(3))) unsigned char lds_byte;

__device__ __forceinline__ void g2l16(const void* g, void* l) {
  __builtin_amdgcn_global_load_lds((glob_byte*)g, (lds_byte*)l, 16, 0, 0);
}

__device__ __forceinline__ unsigned short f2bf(float f) {
  union { float f; unsigned int u; } v; v.f = f;
  return (unsigned short)((v.u + 0x7FFFu + ((v.u >> 16) & 1u)) >> 16);
}
__device__ __forceinline__ float bf2f(unsigned short b) {
  union { unsigned int u; float f; } v; v.u = (unsigned int)b << 16;
  return v.f;
}

// ---- weight fp32 [K][N] -> bf16 transposed [N][K]; fused qkv bias; corr=0.
__global__ __launch_bounds__(256) void wconv_kernel(
    const float* __restrict__ wq, const float* __restrict__ wk,
    const float* __restrict__ wv, const float* __restrict__ wo,
    const float* __restrict__ w1, const float* __restrict__ w2,
    const float* __restrict__ bq, const float* __restrict__ bk,
    const float* __restrict__ bv,
    unsigned short* __restrict__ wqkvT, unsigned short* __restrict__ woT,
    unsigned short* __restrict__ w1T, unsigned short* __restrict__ w2T,
    float* __restrict__ bqkv, float* __restrict__ corr) {
  const int bid = blockIdx.x;
  const int t = threadIdx.x;
  if (bid == 3072) {  // bqkv = [bq|bk|bv]; corr = 0
#pragma unroll
    for (int i = 0; i < 12; ++i) {
      const int n = i * 256 + t;
      bqkv[n] = n < 1024 ? bq[n] : (n < 2048 ? bk[n - 1024] : bv[n - 2048]);
    }
#pragma unroll
    for (int i = 0; i < 16; ++i) corr[i * 256 + t] = 0.f;
    return;
  }
  __shared__ float tile[64][65];
  const float* src; unsigned short* dst; int K, N, tk, tn;
  if (bid < 1024) {
    const int m = bid >> 8, loc = bid & 255;
    src = m == 0 ? wq : m == 1 ? wk : m == 2 ? wv : wo;
    dst = m == 3 ? woT : (wqkvT + (size_t)m * 1024 * 1024);
    K = 1024; N = 1024; tk = loc >> 4; tn = loc & 15;
  } else if (bid < 2048) {
    const int loc = bid - 1024; src = w1; dst = w1T;
    K = 1024; N = 4096; tk = loc >> 6; tn = loc & 63;
  } else {
    const int loc = bid - 2048; src = w2; dst = w2T;
    K = 4096; N = 1024; tk = loc >> 4; tn = loc & 15;
  }
  const int lr = t >> 4, lc = (t & 15) * 4;
#pragma unroll
  for (int i = 0; i < 4; ++i) {
    const float4 v = *(const float4*)(src + (size_t)(tk * 64 + lr + 16 * i) * N + tn * 64 + lc);
    tile[lr + 16 * i][lc + 0] = v.x;
    tile[lr + 16 * i][lc + 1] = v.y;
    tile[lr + 16 * i][lc + 2] = v.z;
    tile[lr + 16 * i][lc + 3] = v.w;
  }
  __syncthreads();
  const int on = t >> 2, ok = (t & 3) * 16;
#pragma unroll
  for (int jj = 0; jj < 4; ++jj) {
    ushort4 o4;
    o4.x = f2bf(tile[ok + 4 * jj + 0][on]);
    o4.y = f2bf(tile[ok + 4 * jj + 1][on]);
    o4.z = f2bf(tile[ok + 4 * jj + 2][on]);
    o4.w = f2bf(tile[ok + 4 * jj + 3][on]);
    *(ushort4*)(dst + (size_t)(tn * 64 + on) * K + tk * 64 + ok + 4 * jj) = o4;
  }
}

// ---- LayerNorm (torch: ddof=1, /(std+eps)), fp32 in -> bf16 out.
__global__ __launch_bounds__(256) void ln_kernel(
    const float* __restrict__ x, unsigned short* __restrict__ y,
    const float* __restrict__ alpha, const float* __restrict__ beta) {
  const int row = blockIdx.x;
  const float4 v = ((const float4*)(x + (size_t)row * 1024))[threadIdx.x];
  float s  = v.x + v.y + v.z + v.w;
  float ss = v.x * v.x + v.y * v.y + v.z * v.z + v.w * v.w;
#pragma unroll
  for (int off = 32; off > 0; off >>= 1) {
    s  += __shfl_down(s, off, 64);
    ss += __shfl_down(ss, off, 64);
  }
  __shared__ float red[8];
  const int lane = threadIdx.x & 63, wv_ = threadIdx.x >> 6;
  if (lane == 0) { red[wv_] = s; red[4 + wv_] = ss; }
  __syncthreads();
  const float S  = red[0] + red[1] + red[2] + red[3];
  const float SS = red[4] + red[5] + red[6] + red[7];
  const float mean = S * (1.0f / 1024.0f);
  float var = (SS - 1024.0f * mean * mean) * (1.0f / 1023.0f);
  var = fmaxf(var, 0.0f);
  const float scl = alpha[0] / (sqrtf(var) + EPS);
  const float b = beta[0];
  ushort4 o;
  o.x = f2bf((v.x - mean) * scl + b);
  o.y = f2bf((v.y - mean) * scl + b);
  o.z = f2bf((v.z - mean) * scl + b);
  o.w = f2bf((v.w - mean) * scl + b);
  ((ushort4*)(y + (size_t)row * 1024))[threadIdx.x] = o;
}

// ---- bf16 MFMA GEMM. A:[M][lda], Bt:[N][ldb] bf16 row-major, tile TMxTN.
// SPLITK: gridDim.z slices of KH; slice z writes bf16 partial to Cz.
// RX/RY>0: 2D L2-region swizzle (8 regions of RX x RY tiles, one per XCD).
// As/Bs: chunk c of row r stored at slot r*4 + (c^(r&3)) (4-way max on reads).
template <int TM, int TN, bool OUT_BF16, bool BIAS_M, bool RELU, bool RES,
          bool SPLITK, int RX, int RY>
__global__ __launch_bounds__(256, 2) void mfma_gemm(
    const unsigned short* __restrict__ A, const unsigned short* __restrict__ Bt,
    const float* __restrict__ bias, const float* __restrict__ res,
    void* __restrict__ C0, void* __restrict__ C1,
    int N, int lda, int ldb, int KH) {
  constexpr int WM = (TM == 128) ? ((TN == 128) ? 2 : 4) : 1;
  constexpr int WN = 4 / WM;
  constexpr int MSPAN = TM / WM, NSPAN = TN / WN;
  constexpr int MI = MSPAN / 16, NJ = NSPAN / 16;
  __shared__ __align__(16) unsigned short As[TM * 32];
  __shared__ __align__(16) unsigned short Bs[TN * 32];
  const int tid = threadIdx.x, lane = tid & 63;
  const int w = tid >> 6;
  const int quad = lane >> 4, col = lane & 15;
  const int wm = w % WM, wn = w / WM;

  int bx = blockIdx.x, by = blockIdx.y, bz = blockIdx.z;
  if (RX > 0) {
    const int gx = gridDim.x, gy = gridDim.y;
    const int L = bx + gx * (by + gy * bz);
    const int r = L & 7, s = L >> 3;
    const int nrx = gx / RX, nry = gy / RY;
    const int rx = r % nrx, rem = r / nrx;
    const int ry = rem % nry, rz = rem / nry;
    bx = rx * RX + s % RX;
    by = ry * RY + (s / RX) % RY;
    bz = rz;
  }
  const int m0 = by * TM, n0 = bx * TN;
  const int koff = SPLITK ? bz * KH : 0;

  f32x4 acc[MI][NJ];
  const f32x4 z4 = {0.f, 0.f, 0.f, 0.f};
#pragma unroll
  for (int i = 0; i < MI; ++i)
#pragma unroll
    for (int j = 0; j < NJ; ++j) acc[i][j] = z4;

  for (int k0 = 0; k0 < KH; k0 += 32) {
    __syncthreads();
#pragma unroll
    for (int t = 0; t < TM / 64; ++t) {
      const int s = t * 256 + tid;
      const int r = s >> 2, c = (s & 3) ^ (r & 3);   // swizzled source chunk
      g2l16(A + (size_t)(m0 + r) * lda + koff + k0 + c * 8, (void*)(As + s * 8));
    }
#pragma unroll
    for (int t = 0; t < TN / 64; ++t) {
      const int s = t * 256 + tid;
      const int r = s >> 2, c = (s & 3) ^ (r & 3);
      g2l16(Bt + (size_t)(n0 + r) * ldb + koff + k0 + c * 8, (void*)(Bs + s * 8));
    }
    __syncthreads();
    bf16x8 af[MI], bfr[NJ];
#pragma unroll
    for (int i = 0; i < MI; ++i) {
      const int rr = wm * MSPAN + i * 16 + col;
      af[i] = *(const bf16x8*)(As + rr * 32 + (quad ^ (rr & 3)) * 8);
    }
#pragma unroll
    for (int j = 0; j < NJ; ++j) {
      const int rr = wn * NSPAN + j * 16 + col;
      bfr[j] = *(const bf16x8*)(Bs + rr * 32 + (quad ^ (rr & 3)) * 8);
    }
#pragma unroll
    for (int i = 0; i < MI; ++i)
#pragma unroll
      for (int j = 0; j < NJ; ++j)
        acc[i][j] = __builtin_amdgcn_mfma_f32_16x16x32_bf16(af[i], bfr[j], acc[i][j], 0, 0, 0);
  }
#pragma unroll
  for (int i = 0; i < MI; ++i) {
    const int mrow = m0 + wm * MSPAN + i * 16 + quad * 4;
#pragma unroll
    for (int j = 0; j < NJ; ++j) {
      const int n = n0 + wn * NSPAN + j * 16 + col;
      const float bn = (SPLITK || BIAS_M) ? 0.f : bias[n];
#pragma unroll
      for (int r = 0; r < 4; ++r) {
        const int m = mrow + r;
        if (SPLITK) {
          unsigned short* P = bz ? (unsigned short*)C1 : (unsigned short*)C0;
          P[(size_t)m * N + n] = f2bf(acc[i][j][r]);
        } else {
          float v = acc[i][j][r] + (BIAS_M ? bias[m] : bn);
          if (RES)  v += res[(size_t)m * N + n];
          if (RELU) v = fmaxf(v, 0.f);
          if (OUT_BF16) ((unsigned short*)C0)[(size_t)m * N + n] = f2bf(v);
          else          ((float*)C0)[(size_t)m * N + n] = v;
        }
      }
    }
  }
}

// ---- v-transpose + masked-V sums: qkv[:,2048:3072] -> vT[1024][4096];
// corr[b*1024+hd] += sum_{mask==0} v   (zeroed by wconv; attn applies -1e9)
__global__ __launch_bounds__(256) void vtrans_kernel(
    const unsigned short* __restrict__ qkv, const int* __restrict__ mask,
    unsigned short* __restrict__ vT, float* __restrict__ corr) {
  __shared__ unsigned short tile[64][72];
  const int hx = blockIdx.x, ty = blockIdx.y, t = threadIdx.x;
  const int tok0 = ty * 64, hd0 = hx * 64, b = tok0 >> 10;
  const int tr = t >> 2, seg = (t & 3) * 16;
  const unsigned short* src = qkv + (size_t)(tok0 + tr) * 3072 + 2048 + hd0 + seg;
  const uint4 a = *(const uint4*)src;
  const uint4 bb = *(const uint4*)(src + 8);
  *(uint4*)&tile[tr][seg] = a;
  *(uint4*)&tile[tr][seg + 8] = bb;
  __syncthreads();
  const int ch = t >> 2, seg2 = (t & 3) * 16;
  unsigned short vals[16];
  float msum = 0.f;
  const int* mrow = mask + b * 1024 + ((tok0 + seg2) & 1023);
#pragma unroll
  for (int j = 0; j < 16; ++j) {
    vals[j] = tile[seg2 + j][ch];
    if (mrow[j] == 0) msum += bf2f(vals[j]);
  }
  unsigned short* dst = vT + (size_t)(hd0 + ch) * 4096 + tok0 + seg2;
  *(uint4*)dst = *(uint4*)&vals[0];
  *(uint4*)(dst + 8) = *(uint4*)&vals[8];
  atomicAdd(&corr[b * 1024 + hd0 + ch], msum);
}

// ---- combine wo partials (bf16) + x + bo -> x1 (bf16) ; xn2 = LN2.
__global__ __launch_bounds__(256) void combine_ln_kernel(
    const unsigned short* __restrict__ p0, const unsigned short* __restrict__ p1,
    const float* __restrict__ x, const float* __restrict__ bo,
    const float* __restrict__ alpha, const float* __restrict__ beta,
    unsigned short* __restrict__ x1, unsigned short* __restrict__ xn2) {
  const int row = blockIdx.x, t = threadIdx.x;
  const size_t i = (size_t)row * 256 + t;
  const ushort4 a4 = ((const ushort4*)p0)[i];
  const ushort4 b4 = ((const ushort4*)p1)[i];
  const float4 x4 = ((const float4*)x)[i];
  const float4 o4 = ((const float4*)bo)[t];
  float4 v;
  v.x = bf2f(a4.x) + bf2f(b4.x) + x4.x + o4.x;
  v.y = bf2f(a4.y) + bf2f(b4.y) + x4.y + o4.y;
  v.z = bf2f(a4.z) + bf2f(b4.z) + x4.z + o4.z;
  v.w = bf2f(a4.w) + bf2f(b4.w) + x4.w + o4.w;
  ushort4 xb;
  xb.x = f2bf(v.x); xb.y = f2bf(v.y); xb.z = f2bf(v.z); xb.w = f2bf(v.w);
  ((ushort4*)x1)[i] = xb;
  float s  = v.x + v.y + v.z + v.w;
  float ss = v.x * v.x + v.y * v.y + v.z * v.z + v.w * v.w;
#pragma unroll
  for (int off = 32; off > 0; off >>= 1) {
    s  += __shfl_down(s, off, 64);
    ss += __shfl_down(ss, off, 64);
  }
  __shared__ float red[8];
  const int lane = t & 63, wv_ = t >> 6;
  if (lane == 0) { red[wv_] = s; red[4 + wv_] = ss; }
  __syncthreads();
  const float S  = red[0] + red[1] + red[2] + red[3];
  const float SS = red[4] + red[5] + red[6] + red[7];
  const float mean = S * (1.0f / 1024.0f);
  float var = (SS - 1024.0f * mean * mean) * (1.0f / 1023.0f);
  var = fmaxf(var, 0.0f);
  const float scl = alpha[0] / (sqrtf(var) + EPS);
  const float bb = beta[0];
  ushort4 o;
  o.x = f2bf((v.x - mean) * scl + bb);
  o.y = f2bf((v.y - mean) * scl + bb);
  o.z = f2bf((v.z - mean) * scl + bb);
  o.w = f2bf((v.w - mean) * scl + bb);
  ((ushort4*)xn2)[i] = o;
}

// ---- combine ffn2 partials (bf16) + x1 (bf16) + b2 -> out fp32.
__global__ __launch_bounds__(256) void combine_out_kernel(
    const unsigned short* __restrict__ pf0, const unsigned short* __restrict__ pf1,
    const unsigned short* __restrict__ x1, const float* __restrict__ b2,
    float* __restrict__ out) {
  const int t = threadIdx.x;
  const size_t i = (size_t)blockIdx.x * 256 + t;
  const ushort4 a4 = ((const ushort4*)pf0)[i];
  const ushort4 b4 = ((const ushort4*)pf1)[i];
  const ushort4 c4 = ((const ushort4*)x1)[i];
  const float4 d4 = ((const float4*)b2)[t];
  float4 v;
  v.x = bf2f(a4.x) + bf2f(b4.x) + bf2f(c4.x) + d4.x;
  v.y = bf2f(a4.y) + bf2f(b4.y) + bf2f(c4.y) + d4.y;
  v.z = bf2f(a4.z) + bf2f(b4.z) + bf2f(c4.z) + d4.z;
  v.w = bf2f(a4.w) + bf2f(b4.w) + bf2f(c4.w) + d4.w;
  ((float4*)out)[i] = v;
}

// ---- fused attention: ctx = (mask? QK^T/8 : 0)@V + (-1e9)*corr
// q/k from qkv [4096][3072] (q cols 0-1023, k cols 1024-2047).
__global__ __launch_bounds__(256, 2) void attn_kernel(
    const unsigned short* __restrict__ qkv, const unsigned short* __restrict__ vT,
    const int* __restrict__ mask, const float* __restrict__ corr,
    unsigned short* __restrict__ ctx) {
  __shared__ __align__(16) unsigned short Qs[128 * 64];
  __shared__ __align__(16) unsigned short Ks[32 * 64];
  __shared__ __align__(16) unsigned short Vs[64 * 32];
  __shared__ __align__(16) unsigned short Ps[128 * 32];
  const int tid = threadIdx.x, lane = tid & 63, w = tid >> 6;
  const int quad = lane >> 4, col = lane & 15;
  // XCD swizzle: same (b,h) -> same residue
  const int L = blockIdx.x + 8 * (blockIdx.y + 16 * blockIdx.z);
  const int s_ = L >> 3;
  const int bh = (L & 7) * 8 + (s_ >> 3);
  const int q0 = (s_ & 7) * 128;
  const int h = bh & 15, b = bh >> 4;
  const size_t qbase = ((size_t)(b * 1024 + q0)) * 3072 + h * 64;

#pragma unroll
  for (int t = 0; t < 4; ++t) {
    const int s = t * 256 + w * 64 + lane;
    const int m = s >> 3, c = (s & 7) ^ (m & 7);
    g2l16(qkv + qbase + (size_t)m * 3072 + c * 8, (void*)(Qs + s * 8));
  }
  __syncthreads();
  bf16x8 qf[2][2];
#pragma unroll
  for (int qt = 0; qt < 2; ++qt)
#pragma unroll
    for (int kf = 0; kf < 2; ++kf) {
      const int m = (w * 2 + qt) * 16 + col;
      const int c = (kf * 4 + quad) ^ (m & 7);
      qf[qt][kf] = *(const bf16x8*)(Qs + m * 64 + c * 8);
    }

  const f32x4 z4 = {0.f, 0.f, 0.f, 0.f};
  f32x4 oacc[2][4];
#pragma unroll
  for (int qt = 0; qt < 2; ++qt)
#pragma unroll
    for (int nt = 0; nt < 4; ++nt) oacc[qt][nt] = z4;

  const int* mrow = mask + b * 1024;
  for (int kb = 0; kb < 1024; kb += 32) {
    __syncthreads();
    {
      const int s = w * 64 + lane;
      const int key = s >> 3, ck = (s & 7) ^ (key & 7);
      g2l16(qkv + ((size_t)(b * 1024 + kb + key)) * 3072 + 1024 + h * 64 + ck * 8,
            (void*)(Ks + s * 8));
      const int d = s >> 2, cv = (s & 3) ^ (d & 3);   // swizzled Vs chunk
      g2l16(vT + ((size_t)(h * 64 + d)) * 4096 + b * 1024 + kb + cv * 8,
            (void*)(Vs + s * 8));
    }
    __syncthreads();

    // S^T = K Q^T : C rows = key, cols = q
    f32x4 st[2][2];
#pragma unroll
    for (int qt = 0; qt < 2; ++qt)
#pragma unroll
      for (int kt = 0; kt < 2; ++kt) st[qt][kt] = z4;
#pragma unroll
    for (int kt = 0; kt < 2; ++kt)
#pragma unroll
      for (int kf = 0; kf < 2; ++kf) {
        const int key = kt * 16 + col;
        const int c = (kf * 4 + quad) ^ (key & 7);
        const bf16x8 kfrag = *(const bf16x8*)(Ks + key * 64 + c * 8);
#pragma unroll
        for (int qt = 0; qt < 2; ++qt)
          st[qt][kt] = __builtin_amdgcn_mfma_f32_16x16x32_bf16(
              kfrag, qf[qt][kf], st[qt][kt], 0, 0, 0);
      }

    // mask + scale + pack 4 keys -> one b64 write per (qt,kt)
    const int4 mv0 = *(const int4*)(mrow + kb + quad * 4);
    const int4 mv1 = *(const int4*)(mrow + kb + 16 + quad * 4);
#pragma unroll
    for (int qt = 0; qt < 2; ++qt) {
      const int qrow = (w * 2 + qt) * 16 + col;
#pragma unroll
      for (int kt = 0; kt < 2; ++kt) {
        const int4 mv = kt ? mv1 : mv0;
        const f32x4 sv = st[qt][kt];
        const unsigned int u0 = mv.x ? f2bf(sv[0] * 0.125f) : 0u;
        const unsigned int u1 = mv.y ? f2bf(sv[1] * 0.125f) : 0u;
        const unsigned int u2 = mv.z ? f2bf(sv[2] * 0.125f) : 0u;
        const unsigned int u3 = mv.w ? f2bf(sv[3] * 0.125f) : 0u;
        uint2 pk;
        pk.x = u0 | (u1 << 16);
        pk.y = u2 | (u3 << 16);
        const int pp = kt * 2 + (quad >> 1);
        *(uint2*)(Ps + qrow * 32 + ((pp ^ (qrow & 3)) * 8 + (quad & 1) * 4)) = pk;
      }
    }
    // no barrier: wave w only touches its own q-rows

    // oacc += P @ V
#pragma unroll
    for (int qt = 0; qt < 2; ++qt) {
      const int qrow = (w * 2 + qt) * 16 + col;
      const bf16x8 pf = *(const bf16x8*)(Ps + qrow * 32 + (quad ^ (qrow & 3)) * 8);
#pragma unroll
      for (int nt = 0; nt < 4; ++nt) {
        const int vr = nt * 16 + col;
        const bf16x8 vf = *(const bf16x8*)(Vs + vr * 32 + (quad ^ (vr & 3)) * 8);
        oacc[qt][nt] = __builtin_amdgcn_mfma_f32_16x16x32_bf16(pf, vf, oacc[qt][nt], 0, 0, 0);
      }
    }
  }

  const float* crow = corr + b * 1024 + h * 64;
#pragma unroll
  for (int qt = 0; qt < 2; ++qt)
#pragma unroll
    for (int nt = 0; nt < 4; ++nt) {
      const int d = nt * 16 + col;
      const float cv = -1e9f * crow[d];
#pragma unroll
      for (int r = 0; r < 4; ++r) {
        const int qq = q0 + (w * 2 + qt) * 16 + quad * 4 + r;
        ctx[((size_t)(b * 1024) + qq) * 1024 + h * 64 + d] = f2bf(oacc[qt][nt][r] + cv);
      }
    }
}

extern "C" void kernel_launch(void* const* d_in, const int* in_sizes, int n_in,
                              void* d_out, int out_size, void* d_ws, size_t ws_size,
                              hipStream_t stream) {
  const float* x    = (const float*)d_in[0];
  const int*   mask = (const int*)d_in[1];
  const float* wq = (const float*)d_in[2];
  const float* bq = (const float*)d_in[3];
  const float* wk = (const float*)d_in[4];
  const float* bk = (const float*)d_in[5];
  const float* wv = (const float*)d_in[6];
  const float* bv = (const float*)d_in[7];
  const float* wo = (const float*)d_in[8];
  const float* bo = (const float*)d_in[9];
  const float* w1 = (const float*)d_in[10];
  const float* b1 = (const float*)d_in[11];
  const float* w2 = (const float*)d_in[12];
  const float* b2 = (const float*)d_in[13];
  const float* ln1a = (const float*)d_in[14];
  const float* ln1b = (const float*)d_in[15];
  const float* ln2a = (const float*)d_in[16];
  const float* ln2b = (const float*)d_in[17];
  float* out = (float*)d_out;
  char* W = (char*)d_ws;
  const size_t MB = 1u << 20;

  // workspace (81 MB max):
  unsigned short* wqkvT = (unsigned short*)(W + 0 * MB);   // 6 MB [3072][1024]
  unsigned short* woT   = (unsigned short*)(W + 6 * MB);   // 2 MB
  unsigned short* w1T   = (unsigned short*)(W + 8 * MB);   // 8 MB
  unsigned short* w2T   = (unsigned short*)(W + 16 * MB);  // 8 MB
  float*          bqkv  = (float*)(W + 24 * MB);           // 12 KB
  float*          corr  = (float*)(W + 24 * MB + 16384);   // 16 KB
  unsigned short* xn    = (unsigned short*)(W + 25 * MB);  // 8 MB (xn / xn2)
  unsigned short* qkv   = (unsigned short*)(W + 33 * MB);  // 24 MB [4096][3072]
  unsigned short* vT    = (unsigned short*)(W + 57 * MB);  // 8 MB [1024][4096]
  unsigned short* ctx   = (unsigned short*)(W + 65 * MB);  // 8 MB
  unsigned short* x1    = (unsigned short*)(W + 73 * MB);  // 8 MB bf16
  unsigned short* xn2   = xn;                              // reuse (xn dead)
  unsigned short* p0wo  = (unsigned short*)(W + 33 * MB);  // 8 MB (qkv dead)
  unsigned short* p1wo  = (unsigned short*)(W + 41 * MB);  // 8 MB
  unsigned short* hb    = (unsigned short*)(W + 33 * MB);  // 32 MB (partials/vT dead)
  unsigned short* pf0   = (unsigned short*)(W + 0 * MB);   // 8 MB (wqkvT/woT dead)
  unsigned short* pf1   = (unsigned short*)(W + 8 * MB);   // 8 MB (w1T dead)

  wconv_kernel<<<3073, 256, 0, stream>>>(wq, wk, wv, wo, w1, w2, bq, bk, bv,
                                         wqkvT, woT, w1T, w2T, bqkv, corr);
  ln_kernel<<<4096, 256, 0, stream>>>(x, xn, ln1a, ln1b);
  // fused q|k|v: [4096][3072] = xn @ wqkvT^T + bqkv, 768 blocks (3/CU)
  mfma_gemm<128, 128, true, false, false, false, false, 12, 8>
      <<<dim3(24, 32), 256, 0, stream>>>(
      xn, wqkvT, bqkv, nullptr, qkv, nullptr, 3072, 1024, 1024, 1024);
  // v transpose + masked-V sums
  vtrans_kernel<<<dim3(16, 64), 256, 0, stream>>>(qkv, mask, vT, corr);
  attn_kernel<<<dim3(8, 16, 4), 256, 0, stream>>>(qkv, vT, mask, corr, ctx);
  // wo-proj split-K z=2, bf16 partials
  mfma_gemm<128, 128, false, false, false, false, true, 8, 8>
      <<<dim3(8, 32, 2), 256, 0, stream>>>(
      ctx, woT, nullptr, nullptr, p0wo, p1wo, 1024, 1024, 1024, 512);
  combine_ln_kernel<<<4096, 256, 0, stream>>>(p0wo, p1wo, x, bo, ln2a, ln2b, x1, xn2);
  // FFN1: 1024 blocks (4/CU), 2D-swizzled
  mfma_gemm<128, 128, true, false, true, false, false, 16, 8>
      <<<dim3(32, 32), 256, 0, stream>>>(
      xn2, w1T, b1, nullptr, hb, nullptr, 4096, 1024, 1024, 1024);
  // FFN2 split-K z=2, bf16 partials
  mfma_gemm<128, 128, false, false, false, false, true, 8, 8>
      <<<dim3(8, 32, 2), 256, 0, stream>>>(
      hb, w2T, nullptr, nullptr, pf0, pf1, 1024, 4096, 4096, 2048);
  combine_out_kernel<<<4096, 256, 0, stream>>>(pf0, pf1, x1, b2, out);
}

// Round 7
// 331.269 us; speedup vs baseline: 7.9694x; 1.1471x over previous
//
#include <hip/hip_runtime.h>
#include <hip/hip_bf16.h>
#include <math.h>

// ---------------------------------------------------------------------------
// EncoderBlock, bf16-MFMA, round 7:
//  - vtrans: atomicAdd(float) removed (HIP compiles it to a CAS retry loop ->
//    60us of pure atomic latency). Per-block partial sums via 4-lane shfl ->
//    corrp[64][1024]; corr_reduce sums 16 tiles per (b,hd). No contention.
//  - everything else as round 6 (fused QKV, XOR-swizzled LDS, bf16 split-K,
//    2D L2-region swizzle).
// ---------------------------------------------------------------------------

#define EPS 1e-5f

typedef __attribute__((ext_vector_type(8))) short bf16x8;
typedef __attribute__((ext_vector_type(4))) float f32x4;

typedef const __attribute__((address_space(1))) unsigned char glob_byte;
typedef __attribute__((address_space(3))) unsigned char lds_byte;

__device__ __forceinline__ void g2l16(const void* g, void* l) {
  __builtin_amdgcn_global_load_lds((glob_byte*)g, (lds_byte*)l, 16, 0, 0);
}

__device__ __forceinline__ unsigned short f2bf(float f) {
  union { float f; unsigned int u; } v; v.f = f;
  return (unsigned short)((v.u + 0x7FFFu + ((v.u >> 16) & 1u)) >> 16);
}
__device__ __forceinline__ float bf2f(unsigned short b) {
  union { unsigned int u; float f; } v; v.u = (unsigned int)b << 16;
  return v.f;
}

// ---- weight fp32 [K][N] -> bf16 transposed [N][K]; fused qkv bias.
__global__ __launch_bounds__(256) void wconv_kernel(
    const float* __restrict__ wq, const float* __restrict__ wk,
    const float* __restrict__ wv, const float* __restrict__ wo,
    const float* __restrict__ w1, const float* __restrict__ w2,
    const float* __restrict__ bq, const float* __restrict__ bk,
    const float* __restrict__ bv,
    unsigned short* __restrict__ wqkvT, unsigned short* __restrict__ woT,
    unsigned short* __restrict__ w1T, unsigned short* __restrict__ w2T,
    float* __restrict__ bqkv) {
  const int bid = blockIdx.x;
  const int t = threadIdx.x;
  if (bid == 3072) {  // bqkv = [bq|bk|bv]
#pragma unroll
    for (int i = 0; i < 12; ++i) {
      const int n = i * 256 + t;
      bqkv[n] = n < 1024 ? bq[n] : (n < 2048 ? bk[n - 1024] : bv[n - 2048]);
    }
    return;
  }
  __shared__ float tile[64][65];
  const float* src; unsigned short* dst; int K, N, tk, tn;
  if (bid < 1024) {
    const int m = bid >> 8, loc = bid & 255;
    src = m == 0 ? wq : m == 1 ? wk : m == 2 ? wv : wo;
    dst = m == 3 ? woT : (wqkvT + (size_t)m * 1024 * 1024);
    K = 1024; N = 1024; tk = loc >> 4; tn = loc & 15;
  } else if (bid < 2048) {
    const int loc = bid - 1024; src = w1; dst = w1T;
    K = 1024; N = 4096; tk = loc >> 6; tn = loc & 63;
  } else {
    const int loc = bid - 2048; src = w2; dst = w2T;
    K = 4096; N = 1024; tk = loc >> 4; tn = loc & 15;
  }
  const int lr = t >> 4, lc = (t & 15) * 4;
#pragma unroll
  for (int i = 0; i < 4; ++i) {
    const float4 v = *(const float4*)(src + (size_t)(tk * 64 + lr + 16 * i) * N + tn * 64 + lc);
    tile[lr + 16 * i][lc + 0] = v.x;
    tile[lr + 16 * i][lc + 1] = v.y;
    tile[lr + 16 * i][lc + 2] = v.z;
    tile[lr + 16 * i][lc + 3] = v.w;
  }
  __syncthreads();
  const int on = t >> 2, ok = (t & 3) * 16;
#pragma unroll
  for (int jj = 0; jj < 4; ++jj) {
    ushort4 o4;
    o4.x = f2bf(tile[ok + 4 * jj + 0][on]);
    o4.y = f2bf(tile[ok + 4 * jj + 1][on]);
    o4.z = f2bf(tile[ok + 4 * jj + 2][on]);
    o4.w = f2bf(tile[ok + 4 * jj + 3][on]);
    *(ushort4*)(dst + (size_t)(tn * 64 + on) * K + tk * 64 + ok + 4 * jj) = o4;
  }
}

// ---- LayerNorm (torch: ddof=1, /(std+eps)), fp32 in -> bf16 out.
__global__ __launch_bounds__(256) void ln_kernel(
    const float* __restrict__ x, unsigned short* __restrict__ y,
    const float* __restrict__ alpha, const float* __restrict__ beta) {
  const int row = blockIdx.x;
  const float4 v = ((const float4*)(x + (size_t)row * 1024))[threadIdx.x];
  float s  = v.x + v.y + v.z + v.w;
  float ss = v.x * v.x + v.y * v.y + v.z * v.z + v.w * v.w;
#pragma unroll
  for (int off = 32; off > 0; off >>= 1) {
    s  += __shfl_down(s, off, 64);
    ss += __shfl_down(ss, off, 64);
  }
  __shared__ float red[8];
  const int lane = threadIdx.x & 63, wv_ = threadIdx.x >> 6;
  if (lane == 0) { red[wv_] = s; red[4 + wv_] = ss; }
  __syncthreads();
  const float S  = red[0] + red[1] + red[2] + red[3];
  const float SS = red[4] + red[5] + red[6] + red[7];
  const float mean = S * (1.0f / 1024.0f);
  float var = (SS - 1024.0f * mean * mean) * (1.0f / 1023.0f);
  var = fmaxf(var, 0.0f);
  const float scl = alpha[0] / (sqrtf(var) + EPS);
  const float b = beta[0];
  ushort4 o;
  o.x = f2bf((v.x - mean) * scl + b);
  o.y = f2bf((v.y - mean) * scl + b);
  o.z = f2bf((v.z - mean) * scl + b);
  o.w = f2bf((v.w - mean) * scl + b);
  ((ushort4*)(y + (size_t)row * 1024))[threadIdx.x] = o;
}

// ---- bf16 MFMA GEMM (as round 6). A:[M][lda], Bt:[N][ldb], tile TMxTN.
template <int TM, int TN, bool OUT_BF16, bool BIAS_M, bool RELU, bool RES,
          bool SPLITK, int RX, int RY>
__global__ __launch_bounds__(256, 2) void mfma_gemm(
    const unsigned short* __restrict__ A, const unsigned short* __restrict__ Bt,
    const float* __restrict__ bias, const float* __restrict__ res,
    void* __restrict__ C0, void* __restrict__ C1,
    int N, int lda, int ldb, int KH) {
  constexpr int WM = (TM == 128) ? ((TN == 128) ? 2 : 4) : 1;
  constexpr int WN = 4 / WM;
  constexpr int MSPAN = TM / WM, NSPAN = TN / WN;
  constexpr int MI = MSPAN / 16, NJ = NSPAN / 16;
  __shared__ __align__(16) unsigned short As[TM * 32];
  __shared__ __align__(16) unsigned short Bs[TN * 32];
  const int tid = threadIdx.x, lane = tid & 63;
  const int w = tid >> 6;
  const int quad = lane >> 4, col = lane & 15;
  const int wm = w % WM, wn = w / WM;

  int bx = blockIdx.x, by = blockIdx.y, bz = blockIdx.z;
  if (RX > 0) {
    const int gx = gridDim.x, gy = gridDim.y;
    const int L = bx + gx * (by + gy * bz);
    const int r = L & 7, s = L >> 3;
    const int nrx = gx / RX, nry = gy / RY;
    const int rx = r % nrx, rem = r / nrx;
    const int ry = rem % nry, rz = rem / nry;
    bx = rx * RX + s % RX;
    by = ry * RY + (s / RX) % RY;
    bz = rz;
  }
  const int m0 = by * TM, n0 = bx * TN;
  const int koff = SPLITK ? bz * KH : 0;

  f32x4 acc[MI][NJ];
  const f32x4 z4 = {0.f, 0.f, 0.f, 0.f};
#pragma unroll
  for (int i = 0; i < MI; ++i)
#pragma unroll
    for (int j = 0; j < NJ; ++j) acc[i][j] = z4;

  for (int k0 = 0; k0 < KH; k0 += 32) {
    __syncthreads();
#pragma unroll
    for (int t = 0; t < TM / 64; ++t) {
      const int s = t * 256 + tid;
      const int r = s >> 2, c = (s & 3) ^ (r & 3);
      g2l16(A + (size_t)(m0 + r) * lda + koff + k0 + c * 8, (void*)(As + s * 8));
    }
#pragma unroll
    for (int t = 0; t < TN / 64; ++t) {
      const int s = t * 256 + tid;
      const int r = s >> 2, c = (s & 3) ^ (r & 3);
      g2l16(Bt + (size_t)(n0 + r) * ldb + koff + k0 + c * 8, (void*)(Bs + s * 8));
    }
    __syncthreads();
    bf16x8 af[MI], bfr[NJ];
#pragma unroll
    for (int i = 0; i < MI; ++i) {
      const int rr = wm * MSPAN + i * 16 + col;
      af[i] = *(const bf16x8*)(As + rr * 32 + (quad ^ (rr & 3)) * 8);
    }
#pragma unroll
    for (int j = 0; j < NJ; ++j) {
      const int rr = wn * NSPAN + j * 16 + col;
      bfr[j] = *(const bf16x8*)(Bs + rr * 32 + (quad ^ (rr & 3)) * 8);
    }
#pragma unroll
    for (int i = 0; i < MI; ++i)
#pragma unroll
      for (int j = 0; j < NJ; ++j)
        acc[i][j] = __builtin_amdgcn_mfma_f32_16x16x32_bf16(af[i], bfr[j], acc[i][j], 0, 0, 0);
  }
#pragma unroll
  for (int i = 0; i < MI; ++i) {
    const int mrow = m0 + wm * MSPAN + i * 16 + quad * 4;
#pragma unroll
    for (int j = 0; j < NJ; ++j) {
      const int n = n0 + wn * NSPAN + j * 16 + col;
      const float bn = (SPLITK || BIAS_M) ? 0.f : bias[n];
#pragma unroll
      for (int r = 0; r < 4; ++r) {
        const int m = mrow + r;
        if (SPLITK) {
          unsigned short* P = bz ? (unsigned short*)C1 : (unsigned short*)C0;
          P[(size_t)m * N + n] = f2bf(acc[i][j][r]);
        } else {
          float v = acc[i][j][r] + (BIAS_M ? bias[m] : bn);
          if (RES)  v += res[(size_t)m * N + n];
          if (RELU) v = fmaxf(v, 0.f);
          if (OUT_BF16) ((unsigned short*)C0)[(size_t)m * N + n] = f2bf(v);
          else          ((float*)C0)[(size_t)m * N + n] = v;
        }
      }
    }
  }
}

// ---- v-transpose + masked-V partial sums (NO atomics):
// qkv[:,2048:3072] -> vT[1024][4096]; corrp[ty][hd] = sum over this tile's
// 64 tokens of V[token][hd] where mask==0.
__global__ __launch_bounds__(256) void vtrans_kernel(
    const unsigned short* __restrict__ qkv, const int* __restrict__ mask,
    unsigned short* __restrict__ vT, float* __restrict__ corrp) {
  __shared__ unsigned short tile[64][72];
  const int hx = blockIdx.x, ty = blockIdx.y, t = threadIdx.x;
  const int tok0 = ty * 64, hd0 = hx * 64, b = tok0 >> 10;
  const int tr = t >> 2, seg = (t & 3) * 16;
  const unsigned short* src = qkv + (size_t)(tok0 + tr) * 3072 + 2048 + hd0 + seg;
  const uint4 a = *(const uint4*)src;
  const uint4 bb = *(const uint4*)(src + 8);
  *(uint4*)&tile[tr][seg] = a;
  *(uint4*)&tile[tr][seg + 8] = bb;
  __syncthreads();
  const int ch = t >> 2, seg2 = (t & 3) * 16;
  unsigned short vals[16];
  float msum = 0.f;
  const int* mrow = mask + b * 1024 + ((tok0 + seg2) & 1023);
#pragma unroll
  for (int j = 0; j < 16; ++j) {
    vals[j] = tile[seg2 + j][ch];
    if (mrow[j] == 0) msum += bf2f(vals[j]);
  }
  unsigned short* dst = vT + (size_t)(hd0 + ch) * 4096 + tok0 + seg2;
  *(uint4*)dst = *(uint4*)&vals[0];
  *(uint4*)(dst + 8) = *(uint4*)&vals[8];
  // reduce across the 4 lanes (seg2 groups) sharing this ch, then one plain
  // store per (tile, hd) -- no contention, no atomics.
  msum += __shfl_down(msum, 2, 4);
  msum += __shfl_down(msum, 1, 4);
  if ((t & 3) == 0) corrp[(size_t)ty * 1024 + hd0 + ch] = msum;
}

// ---- corr[b*1024+hd] = sum of the 16 token-tile partials of batch b.
__global__ __launch_bounds__(256) void corr_reduce_kernel(
    const float* __restrict__ corrp, float* __restrict__ corr) {
  const int idx = blockIdx.x * 256 + threadIdx.x;  // 16 blocks -> 4096
  const int b = idx >> 10, hd = idx & 1023;
  float s = 0.f;
#pragma unroll
  for (int i = 0; i < 16; ++i)
    s += corrp[(size_t)(b * 16 + i) * 1024 + hd];
  corr[idx] = s;
}

// ---- combine wo partials (bf16) + x + bo -> x1 (bf16) ; xn2 = LN2.
__global__ __launch_bounds__(256) void combine_ln_kernel(
    const unsigned short* __restrict__ p0, const unsigned short* __restrict__ p1,
    const float* __restrict__ x, const float* __restrict__ bo,
    const float* __restrict__ alpha, const float* __restrict__ beta,
    unsigned short* __restrict__ x1, unsigned short* __restrict__ xn2) {
  const int row = blockIdx.x, t = threadIdx.x;
  const size_t i = (size_t)row * 256 + t;
  const ushort4 a4 = ((const ushort4*)p0)[i];
  const ushort4 b4 = ((const ushort4*)p1)[i];
  const float4 x4 = ((const float4*)x)[i];
  const float4 o4 = ((const float4*)bo)[t];
  float4 v;
  v.x = bf2f(a4.x) + bf2f(b4.x) + x4.x + o4.x;
  v.y = bf2f(a4.y) + bf2f(b4.y) + x4.y + o4.y;
  v.z = bf2f(a4.z) + bf2f(b4.z) + x4.z + o4.z;
  v.w = bf2f(a4.w) + bf2f(b4.w) + x4.w + o4.w;
  ushort4 xb;
  xb.x = f2bf(v.x); xb.y = f2bf(v.y); xb.z = f2bf(v.z); xb.w = f2bf(v.w);
  ((ushort4*)x1)[i] = xb;
  float s  = v.x + v.y + v.z + v.w;
  float ss = v.x * v.x + v.y * v.y + v.z * v.z + v.w * v.w;
#pragma unroll
  for (int off = 32; off > 0; off >>= 1) {
    s  += __shfl_down(s, off, 64);
    ss += __shfl_down(ss, off, 64);
  }
  __shared__ float red[8];
  const int lane = t & 63, wv_ = t >> 6;
  if (lane == 0) { red[wv_] = s; red[4 + wv_] = ss; }
  __syncthreads();
  const float S  = red[0] + red[1] + red[2] + red[3];
  const float SS = red[4] + red[5] + red[6] + red[7];
  const float mean = S * (1.0f / 1024.0f);
  float var = (SS - 1024.0f * mean * mean) * (1.0f / 1023.0f);
  var = fmaxf(var, 0.0f);
  const float scl = alpha[0] / (sqrtf(var) + EPS);
  const float bb = beta[0];
  ushort4 o;
  o.x = f2bf((v.x - mean) * scl + bb);
  o.y = f2bf((v.y - mean) * scl + bb);
  o.z = f2bf((v.z - mean) * scl + bb);
  o.w = f2bf((v.w - mean) * scl + bb);
  ((ushort4*)xn2)[i] = o;
}

// ---- combine ffn2 partials (bf16) + x1 (bf16) + b2 -> out fp32.
__global__ __launch_bounds__(256) void combine_out_kernel(
    const unsigned short* __restrict__ pf0, const unsigned short* __restrict__ pf1,
    const unsigned short* __restrict__ x1, const float* __restrict__ b2,
    float* __restrict__ out) {
  const int t = threadIdx.x;
  const size_t i = (size_t)blockIdx.x * 256 + t;
  const ushort4 a4 = ((const ushort4*)pf0)[i];
  const ushort4 b4 = ((const ushort4*)pf1)[i];
  const ushort4 c4 = ((const ushort4*)x1)[i];
  const float4 d4 = ((const float4*)b2)[t];
  float4 v;
  v.x = bf2f(a4.x) + bf2f(b4.x) + bf2f(c4.x) + d4.x;
  v.y = bf2f(a4.y) + bf2f(b4.y) + bf2f(c4.y) + d4.y;
  v.z = bf2f(a4.z) + bf2f(b4.z) + bf2f(c4.z) + d4.z;
  v.w = bf2f(a4.w) + bf2f(b4.w) + bf2f(c4.w) + d4.w;
  ((float4*)out)[i] = v;
}

// ---- fused attention: ctx = (mask? QK^T/8 : 0)@V + (-1e9)*corr
__global__ __launch_bounds__(256, 2) void attn_kernel(
    const unsigned short* __restrict__ qkv, const unsigned short* __restrict__ vT,
    const int* __restrict__ mask, const float* __restrict__ corr,
    unsigned short* __restrict__ ctx) {
  __shared__ __align__(16) unsigned short Qs[128 * 64];
  __shared__ __align__(16) unsigned short Ks[32 * 64];
  __shared__ __align__(16) unsigned short Vs[64 * 32];
  __shared__ __align__(16) unsigned short Ps[128 * 32];
  const int tid = threadIdx.x, lane = tid & 63, w = tid >> 6;
  const int quad = lane >> 4, col = lane & 15;
  const int L = blockIdx.x + 8 * (blockIdx.y + 16 * blockIdx.z);
  const int s_ = L >> 3;
  const int bh = (L & 7) * 8 + (s_ >> 3);
  const int q0 = (s_ & 7) * 128;
  const int h = bh & 15, b = bh >> 4;
  const size_t qbase = ((size_t)(b * 1024 + q0)) * 3072 + h * 64;

#pragma unroll
  for (int t = 0; t < 4; ++t) {
    const int s = t * 256 + w * 64 + lane;
    const int m = s >> 3, c = (s & 7) ^ (m & 7);
    g2l16(qkv + qbase + (size_t)m * 3072 + c * 8, (void*)(Qs + s * 8));
  }
  __syncthreads();
  bf16x8 qf[2][2];
#pragma unroll
  for (int qt = 0; qt < 2; ++qt)
#pragma unroll
    for (int kf = 0; kf < 2; ++kf) {
      const int m = (w * 2 + qt) * 16 + col;
      const int c = (kf * 4 + quad) ^ (m & 7);
      qf[qt][kf] = *(const bf16x8*)(Qs + m * 64 + c * 8);
    }

  const f32x4 z4 = {0.f, 0.f, 0.f, 0.f};
  f32x4 oacc[2][4];
#pragma unroll
  for (int qt = 0; qt < 2; ++qt)
#pragma unroll
    for (int nt = 0; nt < 4; ++nt) oacc[qt][nt] = z4;

  const int* mrow = mask + b * 1024;
  for (int kb = 0; kb < 1024; kb += 32) {
    __syncthreads();
    {
      const int s = w * 64 + lane;
      const int key = s >> 3, ck = (s & 7) ^ (key & 7);
      g2l16(qkv + ((size_t)(b * 1024 + kb + key)) * 3072 + 1024 + h * 64 + ck * 8,
            (void*)(Ks + s * 8));
      const int d = s >> 2, cv = (s & 3) ^ (d & 3);
      g2l16(vT + ((size_t)(h * 64 + d)) * 4096 + b * 1024 + kb + cv * 8,
            (void*)(Vs + s * 8));
    }
    __syncthreads();

    f32x4 st[2][2];
#pragma unroll
    for (int qt = 0; qt < 2; ++qt)
#pragma unroll
      for (int kt = 0; kt < 2; ++kt) st[qt][kt] = z4;
#pragma unroll
    for (int kt = 0; kt < 2; ++kt)
#pragma unroll
      for (int kf = 0; kf < 2; ++kf) {
        const int key = kt * 16 + col;
        const int c = (kf * 4 + quad) ^ (key & 7);
        const bf16x8 kfrag = *(const bf16x8*)(Ks + key * 64 + c * 8);
#pragma unroll
        for (int qt = 0; qt < 2; ++qt)
          st[qt][kt] = __builtin_amdgcn_mfma_f32_16x16x32_bf16(
              kfrag, qf[qt][kf], st[qt][kt], 0, 0, 0);
      }

    const int4 mv0 = *(const int4*)(mrow + kb + quad * 4);
    const int4 mv1 = *(const int4*)(mrow + kb + 16 + quad * 4);
#pragma unroll
    for (int qt = 0; qt < 2; ++qt) {
      const int qrow = (w * 2 + qt) * 16 + col;
#pragma unroll
      for (int kt = 0; kt < 2; ++kt) {
        const int4 mv = kt ? mv1 : mv0;
        const f32x4 sv = st[qt][kt];
        const unsigned int u0 = mv.x ? f2bf(sv[0] * 0.125f) : 0u;
        const unsigned int u1 = mv.y ? f2bf(sv[1] * 0.125f) : 0u;
        const unsigned int u2 = mv.z ? f2bf(sv[2] * 0.125f) : 0u;
        const unsigned int u3 = mv.w ? f2bf(sv[3] * 0.125f) : 0u;
        uint2 pk;
        pk.x = u0 | (u1 << 16);
        pk.y = u2 | (u3 << 16);
        const int pp = kt * 2 + (quad >> 1);
        *(uint2*)(Ps + qrow * 32 + ((pp ^ (qrow & 3)) * 8 + (quad & 1) * 4)) = pk;
      }
    }
    // no barrier: wave w only touches its own q-rows

#pragma unroll
    for (int qt = 0; qt < 2; ++qt) {
      const int qrow = (w * 2 + qt) * 16 + col;
      const bf16x8 pf = *(const bf16x8*)(Ps + qrow * 32 + (quad ^ (qrow & 3)) * 8);
#pragma unroll
      for (int nt = 0; nt < 4; ++nt) {
        const int vr = nt * 16 + col;
        const bf16x8 vf = *(const bf16x8*)(Vs + vr * 32 + (quad ^ (vr & 3)) * 8);
        oacc[qt][nt] = __builtin_amdgcn_mfma_f32_16x16x32_bf16(pf, vf, oacc[qt][nt], 0, 0, 0);
      }
    }
  }

  const float* crow = corr + b * 1024 + h * 64;
#pragma unroll
  for (int qt = 0; qt < 2; ++qt)
#pragma unroll
    for (int nt = 0; nt < 4; ++nt) {
      const int d = nt * 16 + col;
      const float cv = -1e9f * crow[d];
#pragma unroll
      for (int r = 0; r < 4; ++r) {
        const int qq = q0 + (w * 2 + qt) * 16 + quad * 4 + r;
        ctx[((size_t)(b * 1024) + qq) * 1024 + h * 64 + d] = f2bf(oacc[qt][nt][r] + cv);
      }
    }
}

extern "C" void kernel_launch(void* const* d_in, const int* in_sizes, int n_in,
                              void* d_out, int out_size, void* d_ws, size_t ws_size,
                              hipStream_t stream) {
  const float* x    = (const float*)d_in[0];
  const int*   mask = (const int*)d_in[1];
  const float* wq = (const float*)d_in[2];
  const float* bq = (const float*)d_in[3];
  const float* wk = (const float*)d_in[4];
  const float* bk = (const float*)d_in[5];
  const float* wv = (const float*)d_in[6];
  const float* bv = (const float*)d_in[7];
  const float* wo = (const float*)d_in[8];
  const float* bo = (const float*)d_in[9];
  const float* w1 = (const float*)d_in[10];
  const float* b1 = (const float*)d_in[11];
  const float* w2 = (const float*)d_in[12];
  const float* b2 = (const float*)d_in[13];
  const float* ln1a = (const float*)d_in[14];
  const float* ln1b = (const float*)d_in[15];
  const float* ln2a = (const float*)d_in[16];
  const float* ln2b = (const float*)d_in[17];
  float* out = (float*)d_out;
  char* W = (char*)d_ws;
  const size_t MB = 1u << 20;

  unsigned short* wqkvT = (unsigned short*)(W + 0 * MB);   // 6 MB [3072][1024]
  unsigned short* woT   = (unsigned short*)(W + 6 * MB);   // 2 MB
  unsigned short* w1T   = (unsigned short*)(W + 8 * MB);   // 8 MB
  unsigned short* w2T   = (unsigned short*)(W + 16 * MB);  // 8 MB
  float*          bqkv  = (float*)(W + 24 * MB);           // 12 KB
  float*          corr  = (float*)(W + 24 * MB + 65536);   // 16 KB
  float*          corrp = (float*)(W + 24 * MB + 131072);  // 256 KB
  unsigned short* xn    = (unsigned short*)(W + 25 * MB);  // 8 MB (xn / xn2)
  unsigned short* qkv   = (unsigned short*)(W + 33 * MB);  // 24 MB [4096][3072]
  unsigned short* vT    = (unsigned short*)(W + 57 * MB);  // 8 MB [1024][4096]
  unsigned short* ctx   = (unsigned short*)(W + 65 * MB);  // 8 MB
  unsigned short* x1    = (unsigned short*)(W + 73 * MB);  // 8 MB bf16
  unsigned short* xn2   = xn;                              // reuse
  unsigned short* p0wo  = (unsigned short*)(W + 33 * MB);  // 8 MB (qkv dead)
  unsigned short* p1wo  = (unsigned short*)(W + 41 * MB);  // 8 MB
  unsigned short* hb    = (unsigned short*)(W + 33 * MB);  // 32 MB
  unsigned short* pf0   = (unsigned short*)(W + 0 * MB);   // 8 MB (weights dead)
  unsigned short* pf1   = (unsigned short*)(W + 8 * MB);   // 8 MB

  wconv_kernel<<<3073, 256, 0, stream>>>(wq, wk, wv, wo, w1, w2, bq, bk, bv,
                                         wqkvT, woT, w1T, w2T, bqkv);
  ln_kernel<<<4096, 256, 0, stream>>>(x, xn, ln1a, ln1b);
  // fused q|k|v: [4096][3072] = xn @ wqkvT^T + bqkv, 768 blocks (3/CU)
  mfma_gemm<128, 128, true, false, false, false, false, 12, 8>
      <<<dim3(24, 32), 256, 0, stream>>>(
      xn, wqkvT, bqkv, nullptr, qkv, nullptr, 3072, 1024, 1024, 1024);
  vtrans_kernel<<<dim3(16, 64), 256, 0, stream>>>(qkv, mask, vT, corrp);
  corr_reduce_kernel<<<16, 256, 0, stream>>>(corrp, corr);
  attn_kernel<<<dim3(8, 16, 4), 256, 0, stream>>>(qkv, vT, mask, corr, ctx);
  // wo-proj split-K z=2, bf16 partials
  mfma_gemm<128, 128, false, false, false, false, true, 8, 8>
      <<<dim3(8, 32, 2), 256, 0, stream>>>(
      ctx, woT, nullptr, nullptr, p0wo, p1wo, 1024, 1024, 1024, 512);
  combine_ln_kernel<<<4096, 256, 0, stream>>>(p0wo, p1wo, x, bo, ln2a, ln2b, x1, xn2);
  // FFN1: 1024 blocks (4/CU), 2D-swizzled
  mfma_gemm<128, 128, true, false, true, false, false, 16, 8>
      <<<dim3(32, 32), 256, 0, stream>>>(
      xn2, w1T, b1, nullptr, hb, nullptr, 4096, 1024, 1024, 1024);
  // FFN2 split-K z=2, bf16 partials
  mfma_gemm<128, 128, false, false, false, false, true, 8, 8>
      <<<dim3(8, 32, 2), 256, 0, stream>>>(
      hb, w2T, nullptr, nullptr, pf0, pf1, 1024, 4096, 4096, 2048);
  combine_out_kernel<<<4096, 256, 0, stream>>>(pf0, pf1, x1, b2, out);
}

// Round 8
// 312.017 us; speedup vs baseline: 8.4611x; 1.0617x over previous
//
#include <hip/hip_runtime.h>
#include <hip/hip_bf16.h>
#include <math.h>

// ---------------------------------------------------------------------------
// EncoderBlock, bf16-MFMA, round 8:
//  - BK=64 GEMM K-loop (32 KB LDS/buffer, 32 MFMA per barrier pair: halves
//    the barrier-drain tax seen at 2 blocks/CU with BK=32)
//  - __launch_bounds__(256,4): allow 4 blocks/CU on 1024-block grids
//  - ffn2 split-K z=4 (KH=1024, 1024 blocks, 4 bf16 partials)
//  - rest as round 7 (fused QKV, vtrans+corr partials, 2D L2-region swizzle)
// ---------------------------------------------------------------------------

#define EPS 1e-5f

typedef __attribute__((ext_vector_type(8))) short bf16x8;
typedef __attribute__((ext_vector_type(4))) float f32x4;

typedef const __attribute__((address_space(1))) unsigned char glob_byte;
typedef __attribute__((address_space(3))) unsigned char lds_byte;

__device__ __forceinline__ void g2l16(const void* g, void* l) {
  __builtin_amdgcn_global_load_lds((glob_byte*)g, (lds_byte*)l, 16, 0, 0);
}

__device__ __forceinline__ unsigned short f2bf(float f) {
  union { float f; unsigned int u; } v; v.f = f;
  return (unsigned short)((v.u + 0x7FFFu + ((v.u >> 16) & 1u)) >> 16);
}
__device__ __forceinline__ float bf2f(unsigned short b) {
  union { unsigned int u; float f; } v; v.u = (unsigned int)b << 16;
  return v.f;
}

// ---- weight fp32 [K][N] -> bf16 transposed [N][K]; fused qkv bias.
__global__ __launch_bounds__(256) void wconv_kernel(
    const float* __restrict__ wq, const float* __restrict__ wk,
    const float* __restrict__ wv, const float* __restrict__ wo,
    const float* __restrict__ w1, const float* __restrict__ w2,
    const float* __restrict__ bq, const float* __restrict__ bk,
    const float* __restrict__ bv,
    unsigned short* __restrict__ wqkvT, unsigned short* __restrict__ woT,
    unsigned short* __restrict__ w1T, unsigned short* __restrict__ w2T,
    float* __restrict__ bqkv) {
  const int bid = blockIdx.x;
  const int t = threadIdx.x;
  if (bid == 3072) {
#pragma unroll
    for (int i = 0; i < 12; ++i) {
      const int n = i * 256 + t;
      bqkv[n] = n < 1024 ? bq[n] : (n < 2048 ? bk[n - 1024] : bv[n - 2048]);
    }
    return;
  }
  __shared__ float tile[64][65];
  const float* src; unsigned short* dst; int K, N, tk, tn;
  if (bid < 1024) {
    const int m = bid >> 8, loc = bid & 255;
    src = m == 0 ? wq : m == 1 ? wk : m == 2 ? wv : wo;
    dst = m == 3 ? woT : (wqkvT + (size_t)m * 1024 * 1024);
    K = 1024; N = 1024; tk = loc >> 4; tn = loc & 15;
  } else if (bid < 2048) {
    const int loc = bid - 1024; src = w1; dst = w1T;
    K = 1024; N = 4096; tk = loc >> 6; tn = loc & 63;
  } else {
    const int loc = bid - 2048; src = w2; dst = w2T;
    K = 4096; N = 1024; tk = loc >> 4; tn = loc & 15;
  }
  const int lr = t >> 4, lc = (t & 15) * 4;
#pragma unroll
  for (int i = 0; i < 4; ++i) {
    const float4 v = *(const float4*)(src + (size_t)(tk * 64 + lr + 16 * i) * N + tn * 64 + lc);
    tile[lr + 16 * i][lc + 0] = v.x;
    tile[lr + 16 * i][lc + 1] = v.y;
    tile[lr + 16 * i][lc + 2] = v.z;
    tile[lr + 16 * i][lc + 3] = v.w;
  }
  __syncthreads();
  const int on = t >> 2, ok = (t & 3) * 16;
#pragma unroll
  for (int jj = 0; jj < 4; ++jj) {
    ushort4 o4;
    o4.x = f2bf(tile[ok + 4 * jj + 0][on]);
    o4.y = f2bf(tile[ok + 4 * jj + 1][on]);
    o4.z = f2bf(tile[ok + 4 * jj + 2][on]);
    o4.w = f2bf(tile[ok + 4 * jj + 3][on]);
    *(ushort4*)(dst + (size_t)(tn * 64 + on) * K + tk * 64 + ok + 4 * jj) = o4;
  }
}

// ---- LayerNorm (torch: ddof=1, /(std+eps)), fp32 in -> bf16 out.
__global__ __launch_bounds__(256) void ln_kernel(
    const float* __restrict__ x, unsigned short* __restrict__ y,
    const float* __restrict__ alpha, const float* __restrict__ beta) {
  const int row = blockIdx.x;
  const float4 v = ((const float4*)(x + (size_t)row * 1024))[threadIdx.x];
  float s  = v.x + v.y + v.z + v.w;
  float ss = v.x * v.x + v.y * v.y + v.z * v.z + v.w * v.w;
#pragma unroll
  for (int off = 32; off > 0; off >>= 1) {
    s  += __shfl_down(s, off, 64);
    ss += __shfl_down(ss, off, 64);
  }
  __shared__ float red[8];
  const int lane = threadIdx.x & 63, wv_ = threadIdx.x >> 6;
  if (lane == 0) { red[wv_] = s; red[4 + wv_] = ss; }
  __syncthreads();
  const float S  = red[0] + red[1] + red[2] + red[3];
  const float SS = red[4] + red[5] + red[6] + red[7];
  const float mean = S * (1.0f / 1024.0f);
  float var = (SS - 1024.0f * mean * mean) * (1.0f / 1023.0f);
  var = fmaxf(var, 0.0f);
  const float scl = alpha[0] / (sqrtf(var) + EPS);
  const float b = beta[0];
  ushort4 o;
  o.x = f2bf((v.x - mean) * scl + b);
  o.y = f2bf((v.y - mean) * scl + b);
  o.z = f2bf((v.z - mean) * scl + b);
  o.w = f2bf((v.w - mean) * scl + b);
  ((ushort4*)(y + (size_t)row * 1024))[threadIdx.x] = o;
}

// ---- bf16 MFMA GEMM, BK=64. A:[M][lda], Bt:[N][ldb] bf16 row-major,
// 128x128 tile. Rows are 64 bf16 (128 B); chunk c of row r stored at slot
// r*8 + (c^(r&7)). Fragment reads land 2-way max (free).
// SPLITK: gridDim.z slices of KH; slice z writes bf16 partial to Cz.
// RX/RY: 2D L2-region swizzle (requires nrx*nry*gz == 8).
template <int TM, int TN, bool OUT_BF16, bool RELU, bool SPLITK, int RX, int RY>
__global__ __launch_bounds__(256, 4) void mfma_gemm(
    const unsigned short* __restrict__ A, const unsigned short* __restrict__ Bt,
    const float* __restrict__ bias,
    void* __restrict__ C0, void* __restrict__ C1,
    void* __restrict__ C2, void* __restrict__ C3,
    int N, int lda, int ldb, int KH) {
  constexpr int WM = 2, WN = 2;
  constexpr int MSPAN = TM / WM, NSPAN = TN / WN;
  constexpr int MI = MSPAN / 16, NJ = NSPAN / 16;
  __shared__ __align__(16) unsigned short As[TM * 64];
  __shared__ __align__(16) unsigned short Bs[TN * 64];
  const int tid = threadIdx.x, lane = tid & 63;
  const int w = tid >> 6;
  const int quad = lane >> 4, col = lane & 15;
  const int wm = w % WM, wn = w / WM;

  int bx = blockIdx.x, by = blockIdx.y, bz = blockIdx.z;
  {
    const int gx = gridDim.x, gy = gridDim.y;
    const int L = bx + gx * (by + gy * bz);
    const int r = L & 7, s = L >> 3;
    const int nrx = gx / RX, nry = gy / RY;
    const int rx = r % nrx, rem = r / nrx;
    const int ry = rem % nry, rz = rem / nry;
    bx = rx * RX + s % RX;
    by = ry * RY + (s / RX) % RY;
    bz = rz;
  }
  const int m0 = by * TM, n0 = bx * TN;
  const int koff = SPLITK ? bz * KH : 0;

  f32x4 acc[MI][NJ];
  const f32x4 z4 = {0.f, 0.f, 0.f, 0.f};
#pragma unroll
  for (int i = 0; i < MI; ++i)
#pragma unroll
    for (int j = 0; j < NJ; ++j) acc[i][j] = z4;

  for (int k0 = 0; k0 < KH; k0 += 64) {
    __syncthreads();
#pragma unroll
    for (int t = 0; t < TM / 32; ++t) {
      const int s = t * 256 + tid;
      const int r = s >> 3, c = (s & 7) ^ (r & 7);
      g2l16(A + (size_t)(m0 + r) * lda + koff + k0 + c * 8, (void*)(As + s * 8));
    }
#pragma unroll
    for (int t = 0; t < TN / 32; ++t) {
      const int s = t * 256 + tid;
      const int r = s >> 3, c = (s & 7) ^ (r & 7);
      g2l16(Bt + (size_t)(n0 + r) * ldb + koff + k0 + c * 8, (void*)(Bs + s * 8));
    }
    __syncthreads();
#pragma unroll
    for (int h = 0; h < 2; ++h) {
      bf16x8 af[MI], bfr[NJ];
#pragma unroll
      for (int i = 0; i < MI; ++i) {
        const int rr = wm * MSPAN + i * 16 + col;
        af[i] = *(const bf16x8*)(As + rr * 64 + (((h << 2) | quad) ^ (rr & 7)) * 8);
      }
#pragma unroll
      for (int j = 0; j < NJ; ++j) {
        const int rr = wn * NSPAN + j * 16 + col;
        bfr[j] = *(const bf16x8*)(Bs + rr * 64 + (((h << 2) | quad) ^ (rr & 7)) * 8);
      }
#pragma unroll
      for (int i = 0; i < MI; ++i)
#pragma unroll
        for (int j = 0; j < NJ; ++j)
          acc[i][j] = __builtin_amdgcn_mfma_f32_16x16x32_bf16(af[i], bfr[j], acc[i][j], 0, 0, 0);
    }
  }
#pragma unroll
  for (int i = 0; i < MI; ++i) {
    const int mrow = m0 + wm * MSPAN + i * 16 + quad * 4;
#pragma unroll
    for (int j = 0; j < NJ; ++j) {
      const int n = n0 + wn * NSPAN + j * 16 + col;
      const float bn = SPLITK ? 0.f : bias[n];
#pragma unroll
      for (int r = 0; r < 4; ++r) {
        const int m = mrow + r;
        if (SPLITK) {
          unsigned short* P = bz == 0 ? (unsigned short*)C0
                            : bz == 1 ? (unsigned short*)C1
                            : bz == 2 ? (unsigned short*)C2
                                      : (unsigned short*)C3;
          P[(size_t)m * N + n] = f2bf(acc[i][j][r]);
        } else {
          float v = acc[i][j][r] + bn;
          if (RELU) v = fmaxf(v, 0.f);
          if (OUT_BF16) ((unsigned short*)C0)[(size_t)m * N + n] = f2bf(v);
          else          ((float*)C0)[(size_t)m * N + n] = v;
        }
      }
    }
  }
}

// ---- v-transpose + masked-V partial sums (no atomics).
__global__ __launch_bounds__(256) void vtrans_kernel(
    const unsigned short* __restrict__ qkv, const int* __restrict__ mask,
    unsigned short* __restrict__ vT, float* __restrict__ corrp) {
  __shared__ unsigned short tile[64][72];
  const int hx = blockIdx.x, ty = blockIdx.y, t = threadIdx.x;
  const int tok0 = ty * 64, hd0 = hx * 64, b = tok0 >> 10;
  const int tr = t >> 2, seg = (t & 3) * 16;
  const unsigned short* src = qkv + (size_t)(tok0 + tr) * 3072 + 2048 + hd0 + seg;
  const uint4 a = *(const uint4*)src;
  const uint4 bb = *(const uint4*)(src + 8);
  *(uint4*)&tile[tr][seg] = a;
  *(uint4*)&tile[tr][seg + 8] = bb;
  __syncthreads();
  const int ch = t >> 2, seg2 = (t & 3) * 16;
  unsigned short vals[16];
  float msum = 0.f;
  const int* mrow = mask + b * 1024 + ((tok0 + seg2) & 1023);
#pragma unroll
  for (int j = 0; j < 16; ++j) {
    vals[j] = tile[seg2 + j][ch];
    if (mrow[j] == 0) msum += bf2f(vals[j]);
  }
  unsigned short* dst = vT + (size_t)(hd0 + ch) * 4096 + tok0 + seg2;
  *(uint4*)dst = *(uint4*)&vals[0];
  *(uint4*)(dst + 8) = *(uint4*)&vals[8];
  msum += __shfl_down(msum, 2, 4);
  msum += __shfl_down(msum, 1, 4);
  if ((t & 3) == 0) corrp[(size_t)ty * 1024 + hd0 + ch] = msum;
}

// ---- corr[b*1024+hd] = sum of the 16 token-tile partials of batch b.
__global__ __launch_bounds__(256) void corr_reduce_kernel(
    const float* __restrict__ corrp, float* __restrict__ corr) {
  const int idx = blockIdx.x * 256 + threadIdx.x;
  const int b = idx >> 10, hd = idx & 1023;
  float s = 0.f;
#pragma unroll
  for (int i = 0; i < 16; ++i)
    s += corrp[(size_t)(b * 16 + i) * 1024 + hd];
  corr[idx] = s;
}

// ---- combine wo partials (bf16) + x + bo -> x1 (bf16) ; xn2 = LN2.
__global__ __launch_bounds__(256) void combine_ln_kernel(
    const unsigned short* __restrict__ p0, const unsigned short* __restrict__ p1,
    const float* __restrict__ x, const float* __restrict__ bo,
    const float* __restrict__ alpha, const float* __restrict__ beta,
    unsigned short* __restrict__ x1, unsigned short* __restrict__ xn2) {
  const int row = blockIdx.x, t = threadIdx.x;
  const size_t i = (size_t)row * 256 + t;
  const ushort4 a4 = ((const ushort4*)p0)[i];
  const ushort4 b4 = ((const ushort4*)p1)[i];
  const float4 x4 = ((const float4*)x)[i];
  const float4 o4 = ((const float4*)bo)[t];
  float4 v;
  v.x = bf2f(a4.x) + bf2f(b4.x) + x4.x + o4.x;
  v.y = bf2f(a4.y) + bf2f(b4.y) + x4.y + o4.y;
  v.z = bf2f(a4.z) + bf2f(b4.z) + x4.z + o4.z;
  v.w = bf2f(a4.w) + bf2f(b4.w) + x4.w + o4.w;
  ushort4 xb;
  xb.x = f2bf(v.x); xb.y = f2bf(v.y); xb.z = f2bf(v.z); xb.w = f2bf(v.w);
  ((ushort4*)x1)[i] = xb;
  float s  = v.x + v.y + v.z + v.w;
  float ss = v.x * v.x + v.y * v.y + v.z * v.z + v.w * v.w;
#pragma unroll
  for (int off = 32; off > 0; off >>= 1) {
    s  += __shfl_down(s, off, 64);
    ss += __shfl_down(ss, off, 64);
  }
  __shared__ float red[8];
  const int lane = t & 63, wv_ = t >> 6;
  if (lane == 0) { red[wv_] = s; red[4 + wv_] = ss; }
  __syncthreads();
  const float S  = red[0] + red[1] + red[2] + red[3];
  const float SS = red[4] + red[5] + red[6] + red[7];
  const float mean = S * (1.0f / 1024.0f);
  float var = (SS - 1024.0f * mean * mean) * (1.0f / 1023.0f);
  var = fmaxf(var, 0.0f);
  const float scl = alpha[0] / (sqrtf(var) + EPS);
  const float bb = beta[0];
  ushort4 o;
  o.x = f2bf((v.x - mean) * scl + bb);
  o.y = f2bf((v.y - mean) * scl + bb);
  o.z = f2bf((v.z - mean) * scl + bb);
  o.w = f2bf((v.w - mean) * scl + bb);
  ((ushort4*)xn2)[i] = o;
}

// ---- combine ffn2 partials (4x bf16) + x1 (bf16) + b2 -> out fp32.
__global__ __launch_bounds__(256) void combine_out_kernel(
    const unsigned short* __restrict__ pf0, const unsigned short* __restrict__ pf1,
    const unsigned short* __restrict__ pf2, const unsigned short* __restrict__ pf3,
    const unsigned short* __restrict__ x1, const float* __restrict__ b2,
    float* __restrict__ out) {
  const int t = threadIdx.x;
  const size_t i = (size_t)blockIdx.x * 256 + t;
  const ushort4 a4 = ((const ushort4*)pf0)[i];
  const ushort4 b4 = ((const ushort4*)pf1)[i];
  const ushort4 c4 = ((const ushort4*)pf2)[i];
  const ushort4 d4 = ((const ushort4*)pf3)[i];
  const ushort4 e4 = ((const ushort4*)x1)[i];
  const float4 f4 = ((const float4*)b2)[t];
  float4 v;
  v.x = bf2f(a4.x) + bf2f(b4.x) + bf2f(c4.x) + bf2f(d4.x) + bf2f(e4.x) + f4.x;
  v.y = bf2f(a4.y) + bf2f(b4.y) + bf2f(c4.y) + bf2f(d4.y) + bf2f(e4.y) + f4.y;
  v.z = bf2f(a4.z) + bf2f(b4.z) + bf2f(c4.z) + bf2f(d4.z) + bf2f(e4.z) + f4.z;
  v.w = bf2f(a4.w) + bf2f(b4.w) + bf2f(c4.w) + bf2f(d4.w) + bf2f(e4.w) + f4.w;
  ((float4*)out)[i] = v;
}

// ---- fused attention: ctx = (mask? QK^T/8 : 0)@V + (-1e9)*corr
__global__ __launch_bounds__(256, 2) void attn_kernel(
    const unsigned short* __restrict__ qkv, const unsigned short* __restrict__ vT,
    const int* __restrict__ mask, const float* __restrict__ corr,
    unsigned short* __restrict__ ctx) {
  __shared__ __align__(16) unsigned short Qs[128 * 64];
  __shared__ __align__(16) unsigned short Ks[32 * 64];
  __shared__ __align__(16) unsigned short Vs[64 * 32];
  __shared__ __align__(16) unsigned short Ps[128 * 32];
  const int tid = threadIdx.x, lane = tid & 63, w = tid >> 6;
  const int quad = lane >> 4, col = lane & 15;
  const int L = blockIdx.x + 8 * (blockIdx.y + 16 * blockIdx.z);
  const int s_ = L >> 3;
  const int bh = (L & 7) * 8 + (s_ >> 3);
  const int q0 = (s_ & 7) * 128;
  const int h = bh & 15, b = bh >> 4;
  const size_t qbase = ((size_t)(b * 1024 + q0)) * 3072 + h * 64;

#pragma unroll
  for (int t = 0; t < 4; ++t) {
    const int s = t * 256 + w * 64 + lane;
    const int m = s >> 3, c = (s & 7) ^ (m & 7);
    g2l16(qkv + qbase + (size_t)m * 3072 + c * 8, (void*)(Qs + s * 8));
  }
  __syncthreads();
  bf16x8 qf[2][2];
#pragma unroll
  for (int qt = 0; qt < 2; ++qt)
#pragma unroll
    for (int kf = 0; kf < 2; ++kf) {
      const int m = (w * 2 + qt) * 16 + col;
      const int c = (kf * 4 + quad) ^ (m & 7);
      qf[qt][kf] = *(const bf16x8*)(Qs + m * 64 + c * 8);
    }

  const f32x4 z4 = {0.f, 0.f, 0.f, 0.f};
  f32x4 oacc[2][4];
#pragma unroll
  for (int qt = 0; qt < 2; ++qt)
#pragma unroll
    for (int nt = 0; nt < 4; ++nt) oacc[qt][nt] = z4;

  const int* mrow = mask + b * 1024;
  for (int kb = 0; kb < 1024; kb += 32) {
    __syncthreads();
    {
      const int s = w * 64 + lane;
      const int key = s >> 3, ck = (s & 7) ^ (key & 7);
      g2l16(qkv + ((size_t)(b * 1024 + kb + key)) * 3072 + 1024 + h * 64 + ck * 8,
            (void*)(Ks + s * 8));
      const int d = s >> 2, cv = (s & 3) ^ (d & 3);
      g2l16(vT + ((size_t)(h * 64 + d)) * 4096 + b * 1024 + kb + cv * 8,
            (void*)(Vs + s * 8));
    }
    __syncthreads();

    f32x4 st[2][2];
#pragma unroll
    for (int qt = 0; qt < 2; ++qt)
#pragma unroll
      for (int kt = 0; kt < 2; ++kt) st[qt][kt] = z4;
#pragma unroll
    for (int kt = 0; kt < 2; ++kt)
#pragma unroll
      for (int kf = 0; kf < 2; ++kf) {
        const int key = kt * 16 + col;
        const int c = (kf * 4 + quad) ^ (key & 7);
        const bf16x8 kfrag = *(const bf16x8*)(Ks + key * 64 + c * 8);
#pragma unroll
        for (int qt = 0; qt < 2; ++qt)
          st[qt][kt] = __builtin_amdgcn_mfma_f32_16x16x32_bf16(
              kfrag, qf[qt][kf], st[qt][kt], 0, 0, 0);
      }

    const int4 mv0 = *(const int4*)(mrow + kb + quad * 4);
    const int4 mv1 = *(const int4*)(mrow + kb + 16 + quad * 4);
#pragma unroll
    for (int qt = 0; qt < 2; ++qt) {
      const int qrow = (w * 2 + qt) * 16 + col;
#pragma unroll
      for (int kt = 0; kt < 2; ++kt) {
        const int4 mv = kt ? mv1 : mv0;
        const f32x4 sv = st[qt][kt];
        const unsigned int u0 = mv.x ? f2bf(sv[0] * 0.125f) : 0u;
        const unsigned int u1 = mv.y ? f2bf(sv[1] * 0.125f) : 0u;
        const unsigned int u2 = mv.z ? f2bf(sv[2] * 0.125f) : 0u;
        const unsigned int u3 = mv.w ? f2bf(sv[3] * 0.125f) : 0u;
        uint2 pk;
        pk.x = u0 | (u1 << 16);
        pk.y = u2 | (u3 << 16);
        const int pp = kt * 2 + (quad >> 1);
        *(uint2*)(Ps + qrow * 32 + ((pp ^ (qrow & 3)) * 8 + (quad & 1) * 4)) = pk;
      }
    }
    // no barrier: wave w only touches its own q-rows

#pragma unroll
    for (int qt = 0; qt < 2; ++qt) {
      const int qrow = (w * 2 + qt) * 16 + col;
      const bf16x8 pf = *(const bf16x8*)(Ps + qrow * 32 + (quad ^ (qrow & 3)) * 8);
#pragma unroll
      for (int nt = 0; nt < 4; ++nt) {
        const int vr = nt * 16 + col;
        const bf16x8 vf = *(const bf16x8*)(Vs + vr * 32 + (quad ^ (vr & 3)) * 8);
        oacc[qt][nt] = __builtin_amdgcn_mfma_f32_16x16x32_bf16(pf, vf, oacc[qt][nt], 0, 0, 0);
      }
    }
  }

  const float* crow = corr + b * 1024 + h * 64;
#pragma unroll
  for (int qt = 0; qt < 2; ++qt)
#pragma unroll
    for (int nt = 0; nt < 4; ++nt) {
      const int d = nt * 16 + col;
      const float cv = -1e9f * crow[d];
#pragma unroll
      for (int r = 0; r < 4; ++r) {
        const int qq = q0 + (w * 2 + qt) * 16 + quad * 4 + r;
        ctx[((size_t)(b * 1024) + qq) * 1024 + h * 64 + d] = f2bf(oacc[qt][nt][r] + cv);
      }
    }
}

extern "C" void kernel_launch(void* const* d_in, const int* in_sizes, int n_in,
                              void* d_out, int out_size, void* d_ws, size_t ws_size,
                              hipStream_t stream) {
  const float* x    = (const float*)d_in[0];
  const int*   mask = (const int*)d_in[1];
  const float* wq = (const float*)d_in[2];
  const float* bq = (const float*)d_in[3];
  const float* wk = (const float*)d_in[4];
  const float* bk = (const float*)d_in[5];
  const float* wv = (const float*)d_in[6];
  const float* bv = (const float*)d_in[7];
  const float* wo = (const float*)d_in[8];
  const float* bo = (const float*)d_in[9];
  const float* w1 = (const float*)d_in[10];
  const float* b1 = (const float*)d_in[11];
  const float* w2 = (const float*)d_in[12];
  const float* b2 = (const float*)d_in[13];
  const float* ln1a = (const float*)d_in[14];
  const float* ln1b = (const float*)d_in[15];
  const float* ln2a = (const float*)d_in[16];
  const float* ln2b = (const float*)d_in[17];
  float* out = (float*)d_out;
  char* W = (char*)d_ws;
  const size_t MB = 1u << 20;

  unsigned short* wqkvT = (unsigned short*)(W + 0 * MB);   // 6 MB [3072][1024]
  unsigned short* woT   = (unsigned short*)(W + 6 * MB);   // 2 MB
  unsigned short* w1T   = (unsigned short*)(W + 8 * MB);   // 8 MB
  unsigned short* w2T   = (unsigned short*)(W + 16 * MB);  // 8 MB
  float*          bqkv  = (float*)(W + 24 * MB);           // 12 KB
  float*          corr  = (float*)(W + 24 * MB + 65536);   // 16 KB
  float*          corrp = (float*)(W + 24 * MB + 131072);  // 256 KB
  unsigned short* xn    = (unsigned short*)(W + 25 * MB);  // 8 MB (xn / xn2)
  unsigned short* qkv   = (unsigned short*)(W + 33 * MB);  // 24 MB [4096][3072]
  unsigned short* vT    = (unsigned short*)(W + 57 * MB);  // 8 MB [1024][4096]
  unsigned short* ctx   = (unsigned short*)(W + 65 * MB);  // 8 MB
  unsigned short* x1    = (unsigned short*)(W + 73 * MB);  // 8 MB bf16
  unsigned short* xn2   = xn;                              // reuse
  unsigned short* p0wo  = (unsigned short*)(W + 33 * MB);  // 8 MB (qkv dead)
  unsigned short* p1wo  = (unsigned short*)(W + 41 * MB);  // 8 MB
  unsigned short* hb    = (unsigned short*)(W + 33 * MB);  // 32 MB
  // ffn2 partials (w2T 16-24 and hb 33-65 and x1 73-81 stay live):
  unsigned short* pf0   = (unsigned short*)(W + 0 * MB);   // 8 MB (weights dead)
  unsigned short* pf1   = (unsigned short*)(W + 8 * MB);   // 8 MB (w1T dead)
  unsigned short* pf2   = (unsigned short*)(W + 24 * MB);  // 8 MB (xn/bqkv dead)
  unsigned short* pf3   = (unsigned short*)(W + 65 * MB);  // 8 MB (ctx dead)

  wconv_kernel<<<3073, 256, 0, stream>>>(wq, wk, wv, wo, w1, w2, bq, bk, bv,
                                         wqkvT, woT, w1T, w2T, bqkv);
  ln_kernel<<<4096, 256, 0, stream>>>(x, xn, ln1a, ln1b);
  // fused q|k|v: [4096][3072], 768 blocks (3/CU), BK=64
  mfma_gemm<128, 128, true, false, false, 12, 8>
      <<<dim3(24, 32), 256, 0, stream>>>(
      xn, wqkvT, bqkv, qkv, nullptr, nullptr, nullptr, 3072, 1024, 1024, 1024);
  vtrans_kernel<<<dim3(16, 64), 256, 0, stream>>>(qkv, mask, vT, corrp);
  corr_reduce_kernel<<<16, 256, 0, stream>>>(corrp, corr);
  attn_kernel<<<dim3(8, 16, 4), 256, 0, stream>>>(qkv, vT, mask, corr, ctx);
  // wo-proj split-K z=2 (KH=512), bf16 partials
  mfma_gemm<128, 128, false, false, true, 8, 8>
      <<<dim3(8, 32, 2), 256, 0, stream>>>(
      ctx, woT, nullptr, p0wo, p1wo, nullptr, nullptr, 1024, 1024, 1024, 512);
  combine_ln_kernel<<<4096, 256, 0, stream>>>(p0wo, p1wo, x, bo, ln2a, ln2b, x1, xn2);
  // FFN1: 1024 blocks (4/CU), BK=64
  mfma_gemm<128, 128, true, true, false, 16, 8>
      <<<dim3(32, 32), 256, 0, stream>>>(
      xn2, w1T, b1, hb, nullptr, nullptr, nullptr, 4096, 1024, 1024, 1024);
  // FFN2 split-K z=4 (KH=1024), 1024 blocks (4/CU), bf16 partials
  mfma_gemm<128, 128, false, false, true, 8, 16>
      <<<dim3(8, 32, 4), 256, 0, stream>>>(
      hb, w2T, nullptr, pf0, pf1, pf2, pf3, 1024, 4096, 4096, 1024);
  combine_out_kernel<<<4096, 256, 0, stream>>>(pf0, pf1, pf2, pf3, x1, b2, out);
}

// Round 9
// 310.624 us; speedup vs baseline: 8.4991x; 1.0045x over previous
//
#include <hip/hip_runtime.h>
#include <hip/hip_bf16.h>
#include <math.h>

// ---------------------------------------------------------------------------
// EncoderBlock, bf16-MFMA, round 9: attention fixes.
//  - Ps padded to 40-ushort rows (plain ds_write -> padding legal): kills the
//    8-way row-stride-64B conflicts seen as 4.7M SQ_LDS_BANK_CONFLICT
//  - Vs swizzle ((d>>2)^d)&3: 4-way -> 2-way fragment reads
//  - cheaper mask+scale+pack (mul by 0/0.125, round-half-up pack)
//  - key-split kz=2 -> 1024 blocks (4/CU); bf16 partial ctx + combine(+corr)
//  - GEMM side unchanged from round 8 (BK=64, split-K, region swizzle)
// ---------------------------------------------------------------------------

#define EPS 1e-5f

typedef __attribute__((ext_vector_type(8))) short bf16x8;
typedef __attribute__((ext_vector_type(4))) float f32x4;

typedef const __attribute__((address_space(1))) unsigned char glob_byte;
typedef __attribute__((address_space(3))) unsigned char lds_byte;

__device__ __forceinline__ void g2l16(const void* g, void* l) {
  __builtin_amdgcn_global_load_lds((glob_byte*)g, (lds_byte*)l, 16, 0, 0);
}

__device__ __forceinline__ unsigned short f2bf(float f) {
  union { float f; unsigned int u; } v; v.f = f;
  return (unsigned short)((v.u + 0x7FFFu + ((v.u >> 16) & 1u)) >> 16);
}
__device__ __forceinline__ float bf2f(unsigned short b) {
  union { unsigned int u; float f; } v; v.u = (unsigned int)b << 16;
  return v.f;
}
__device__ __forceinline__ unsigned int fbits(float f) {
  union { float f; unsigned int u; } v; v.f = f;
  return v.u;
}

// ---- weight fp32 [K][N] -> bf16 transposed [N][K]; fused qkv bias.
__global__ __launch_bounds__(256) void wconv_kernel(
    const float* __restrict__ wq, const float* __restrict__ wk,
    const float* __restrict__ wv, const float* __restrict__ wo,
    const float* __restrict__ w1, const float* __restrict__ w2,
    const float* __restrict__ bq, const float* __restrict__ bk,
    const float* __restrict__ bv,
    unsigned short* __restrict__ wqkvT, unsigned short* __restrict__ woT,
    unsigned short* __restrict__ w1T, unsigned short* __restrict__ w2T,
    float* __restrict__ bqkv) {
  const int bid = blockIdx.x;
  const int t = threadIdx.x;
  if (bid == 3072) {
#pragma unroll
    for (int i = 0; i < 12; ++i) {
      const int n = i * 256 + t;
      bqkv[n] = n < 1024 ? bq[n] : (n < 2048 ? bk[n - 1024] : bv[n - 2048]);
    }
    return;
  }
  __shared__ float tile[64][65];
  const float* src; unsigned short* dst; int K, N, tk, tn;
  if (bid < 1024) {
    const int m = bid >> 8, loc = bid & 255;
    src = m == 0 ? wq : m == 1 ? wk : m == 2 ? wv : wo;
    dst = m == 3 ? woT : (wqkvT + (size_t)m * 1024 * 1024);
    K = 1024; N = 1024; tk = loc >> 4; tn = loc & 15;
  } else if (bid < 2048) {
    const int loc = bid - 1024; src = w1; dst = w1T;
    K = 1024; N = 4096; tk = loc >> 6; tn = loc & 63;
  } else {
    const int loc = bid - 2048; src = w2; dst = w2T;
    K = 4096; N = 1024; tk = loc >> 4; tn = loc & 15;
  }
  const int lr = t >> 4, lc = (t & 15) * 4;
#pragma unroll
  for (int i = 0; i < 4; ++i) {
    const float4 v = *(const float4*)(src + (size_t)(tk * 64 + lr + 16 * i) * N + tn * 64 + lc);
    tile[lr + 16 * i][lc + 0] = v.x;
    tile[lr + 16 * i][lc + 1] = v.y;
    tile[lr + 16 * i][lc + 2] = v.z;
    tile[lr + 16 * i][lc + 3] = v.w;
  }
  __syncthreads();
  const int on = t >> 2, ok = (t & 3) * 16;
#pragma unroll
  for (int jj = 0; jj < 4; ++jj) {
    ushort4 o4;
    o4.x = f2bf(tile[ok + 4 * jj + 0][on]);
    o4.y = f2bf(tile[ok + 4 * jj + 1][on]);
    o4.z = f2bf(tile[ok + 4 * jj + 2][on]);
    o4.w = f2bf(tile[ok + 4 * jj + 3][on]);
    *(ushort4*)(dst + (size_t)(tn * 64 + on) * K + tk * 64 + ok + 4 * jj) = o4;
  }
}

// ---- LayerNorm (torch: ddof=1, /(std+eps)), fp32 in -> bf16 out.
__global__ __launch_bounds__(256) void ln_kernel(
    const float* __restrict__ x, unsigned short* __restrict__ y,
    const float* __restrict__ alpha, const float* __restrict__ beta) {
  const int row = blockIdx.x;
  const float4 v = ((const float4*)(x + (size_t)row * 1024))[threadIdx.x];
  float s  = v.x + v.y + v.z + v.w;
  float ss = v.x * v.x + v.y * v.y + v.z * v.z + v.w * v.w;
#pragma unroll
  for (int off = 32; off > 0; off >>= 1) {
    s  += __shfl_down(s, off, 64);
    ss += __shfl_down(ss, off, 64);
  }
  __shared__ float red[8];
  const int lane = threadIdx.x & 63, wv_ = threadIdx.x >> 6;
  if (lane == 0) { red[wv_] = s; red[4 + wv_] = ss; }
  __syncthreads();
  const float S  = red[0] + red[1] + red[2] + red[3];
  const float SS = red[4] + red[5] + red[6] + red[7];
  const float mean = S * (1.0f / 1024.0f);
  float var = (SS - 1024.0f * mean * mean) * (1.0f / 1023.0f);
  var = fmaxf(var, 0.0f);
  const float scl = alpha[0] / (sqrtf(var) + EPS);
  const float b = beta[0];
  ushort4 o;
  o.x = f2bf((v.x - mean) * scl + b);
  o.y = f2bf((v.y - mean) * scl + b);
  o.z = f2bf((v.z - mean) * scl + b);
  o.w = f2bf((v.w - mean) * scl + b);
  ((ushort4*)(y + (size_t)row * 1024))[threadIdx.x] = o;
}

// ---- bf16 MFMA GEMM, BK=64 (unchanged from round 8).
template <int TM, int TN, bool OUT_BF16, bool RELU, bool SPLITK, int RX, int RY>
__global__ __launch_bounds__(256, 4) void mfma_gemm(
    const unsigned short* __restrict__ A, const unsigned short* __restrict__ Bt,
    const float* __restrict__ bias,
    void* __restrict__ C0, void* __restrict__ C1,
    void* __restrict__ C2, void* __restrict__ C3,
    int N, int lda, int ldb, int KH) {
  constexpr int WM = 2, WN = 2;
  constexpr int MSPAN = TM / WM, NSPAN = TN / WN;
  constexpr int MI = MSPAN / 16, NJ = NSPAN / 16;
  __shared__ __align__(16) unsigned short As[TM * 64];
  __shared__ __align__(16) unsigned short Bs[TN * 64];
  const int tid = threadIdx.x, lane = tid & 63;
  const int w = tid >> 6;
  const int quad = lane >> 4, col = lane & 15;
  const int wm = w % WM, wn = w / WM;

  int bx = blockIdx.x, by = blockIdx.y, bz = blockIdx.z;
  {
    const int gx = gridDim.x, gy = gridDim.y;
    const int L = bx + gx * (by + gy * bz);
    const int r = L & 7, s = L >> 3;
    const int nrx = gx / RX, nry = gy / RY;
    const int rx = r % nrx, rem = r / nrx;
    const int ry = rem % nry, rz = rem / nry;
    bx = rx * RX + s % RX;
    by = ry * RY + (s / RX) % RY;
    bz = rz;
  }
  const int m0 = by * TM, n0 = bx * TN;
  const int koff = SPLITK ? bz * KH : 0;

  f32x4 acc[MI][NJ];
  const f32x4 z4 = {0.f, 0.f, 0.f, 0.f};
#pragma unroll
  for (int i = 0; i < MI; ++i)
#pragma unroll
    for (int j = 0; j < NJ; ++j) acc[i][j] = z4;

  for (int k0 = 0; k0 < KH; k0 += 64) {
    __syncthreads();
#pragma unroll
    for (int t = 0; t < TM / 32; ++t) {
      const int s = t * 256 + tid;
      const int r = s >> 3, c = (s & 7) ^ (r & 7);
      g2l16(A + (size_t)(m0 + r) * lda + koff + k0 + c * 8, (void*)(As + s * 8));
    }
#pragma unroll
    for (int t = 0; t < TN / 32; ++t) {
      const int s = t * 256 + tid;
      const int r = s >> 3, c = (s & 7) ^ (r & 7);
      g2l16(Bt + (size_t)(n0 + r) * ldb + koff + k0 + c * 8, (void*)(Bs + s * 8));
    }
    __syncthreads();
#pragma unroll
    for (int h = 0; h < 2; ++h) {
      bf16x8 af[MI], bfr[NJ];
#pragma unroll
      for (int i = 0; i < MI; ++i) {
        const int rr = wm * MSPAN + i * 16 + col;
        af[i] = *(const bf16x8*)(As + rr * 64 + (((h << 2) | quad) ^ (rr & 7)) * 8);
      }
#pragma unroll
      for (int j = 0; j < NJ; ++j) {
        const int rr = wn * NSPAN + j * 16 + col;
        bfr[j] = *(const bf16x8*)(Bs + rr * 64 + (((h << 2) | quad) ^ (rr & 7)) * 8);
      }
#pragma unroll
      for (int i = 0; i < MI; ++i)
#pragma unroll
        for (int j = 0; j < NJ; ++j)
          acc[i][j] = __builtin_amdgcn_mfma_f32_16x16x32_bf16(af[i], bfr[j], acc[i][j], 0, 0, 0);
    }
  }
#pragma unroll
  for (int i = 0; i < MI; ++i) {
    const int mrow = m0 + wm * MSPAN + i * 16 + quad * 4;
#pragma unroll
    for (int j = 0; j < NJ; ++j) {
      const int n = n0 + wn * NSPAN + j * 16 + col;
      const float bn = SPLITK ? 0.f : bias[n];
#pragma unroll
      for (int r = 0; r < 4; ++r) {
        const int m = mrow + r;
        if (SPLITK) {
          unsigned short* P = bz == 0 ? (unsigned short*)C0
                            : bz == 1 ? (unsigned short*)C1
                            : bz == 2 ? (unsigned short*)C2
                                      : (unsigned short*)C3;
          P[(size_t)m * N + n] = f2bf(acc[i][j][r]);
        } else {
          float v = acc[i][j][r] + bn;
          if (RELU) v = fmaxf(v, 0.f);
          if (OUT_BF16) ((unsigned short*)C0)[(size_t)m * N + n] = f2bf(v);
          else          ((float*)C0)[(size_t)m * N + n] = v;
        }
      }
    }
  }
}

// ---- v-transpose + masked-V partial sums (no atomics).
__global__ __launch_bounds__(256) void vtrans_kernel(
    const unsigned short* __restrict__ qkv, const int* __restrict__ mask,
    unsigned short* __restrict__ vT, float* __restrict__ corrp) {
  __shared__ unsigned short tile[64][72];
  const int hx = blockIdx.x, ty = blockIdx.y, t = threadIdx.x;
  const int tok0 = ty * 64, hd0 = hx * 64, b = tok0 >> 10;
  const int tr = t >> 2, seg = (t & 3) * 16;
  const unsigned short* src = qkv + (size_t)(tok0 + tr) * 3072 + 2048 + hd0 + seg;
  const uint4 a = *(const uint4*)src;
  const uint4 bb = *(const uint4*)(src + 8);
  *(uint4*)&tile[tr][seg] = a;
  *(uint4*)&tile[tr][seg + 8] = bb;
  __syncthreads();
  const int ch = t >> 2, seg2 = (t & 3) * 16;
  unsigned short vals[16];
  float msum = 0.f;
  const int* mrow = mask + b * 1024 + ((tok0 + seg2) & 1023);
#pragma unroll
  for (int j = 0; j < 16; ++j) {
    vals[j] = tile[seg2 + j][ch];
    if (mrow[j] == 0) msum += bf2f(vals[j]);
  }
  unsigned short* dst = vT + (size_t)(hd0 + ch) * 4096 + tok0 + seg2;
  *(uint4*)dst = *(uint4*)&vals[0];
  *(uint4*)(dst + 8) = *(uint4*)&vals[8];
  msum += __shfl_down(msum, 2, 4);
  msum += __shfl_down(msum, 1, 4);
  if ((t & 3) == 0) corrp[(size_t)ty * 1024 + hd0 + ch] = msum;
}

// ---- corr[b*1024+hd] = sum of the 16 token-tile partials of batch b.
__global__ __launch_bounds__(256) void corr_reduce_kernel(
    const float* __restrict__ corrp, float* __restrict__ corr) {
  const int idx = blockIdx.x * 256 + threadIdx.x;
  const int b = idx >> 10, hd = idx & 1023;
  float s = 0.f;
#pragma unroll
  for (int i = 0; i < 16; ++i)
    s += corrp[(size_t)(b * 16 + i) * 1024 + hd];
  corr[idx] = s;
}

// ---- combine wo partials (bf16) + x + bo -> x1 (bf16) ; xn2 = LN2.
__global__ __launch_bounds__(256) void combine_ln_kernel(
    const unsigned short* __restrict__ p0, const unsigned short* __restrict__ p1,
    const float* __restrict__ x, const float* __restrict__ bo,
    const float* __restrict__ alpha, const float* __restrict__ beta,
    unsigned short* __restrict__ x1, unsigned short* __restrict__ xn2) {
  const int row = blockIdx.x, t = threadIdx.x;
  const size_t i = (size_t)row * 256 + t;
  const ushort4 a4 = ((const ushort4*)p0)[i];
  const ushort4 b4 = ((const ushort4*)p1)[i];
  const float4 x4 = ((const float4*)x)[i];
  const float4 o4 = ((const float4*)bo)[t];
  float4 v;
  v.x = bf2f(a4.x) + bf2f(b4.x) + x4.x + o4.x;
  v.y = bf2f(a4.y) + bf2f(b4.y) + x4.y + o4.y;
  v.z = bf2f(a4.z) + bf2f(b4.z) + x4.z + o4.z;
  v.w = bf2f(a4.w) + bf2f(b4.w) + x4.w + o4.w;
  ushort4 xb;
  xb.x = f2bf(v.x); xb.y = f2bf(v.y); xb.z = f2bf(v.z); xb.w = f2bf(v.w);
  ((ushort4*)x1)[i] = xb;
  float s  = v.x + v.y + v.z + v.w;
  float ss = v.x * v.x + v.y * v.y + v.z * v.z + v.w * v.w;
#pragma unroll
  for (int off = 32; off > 0; off >>= 1) {
    s  += __shfl_down(s, off, 64);
    ss += __shfl_down(ss, off, 64);
  }
  __shared__ float red[8];
  const int lane = t & 63, wv_ = t >> 6;
  if (lane == 0) { red[wv_] = s; red[4 + wv_] = ss; }
  __syncthreads();
  const float S  = red[0] + red[1] + red[2] + red[3];
  const float SS = red[4] + red[5] + red[6] + red[7];
  const float mean = S * (1.0f / 1024.0f);
  float var = (SS - 1024.0f * mean * mean) * (1.0f / 1023.0f);
  var = fmaxf(var, 0.0f);
  const float scl = alpha[0] / (sqrtf(var) + EPS);
  const float bb = beta[0];
  ushort4 o;
  o.x = f2bf((v.x - mean) * scl + bb);
  o.y = f2bf((v.y - mean) * scl + bb);
  o.z = f2bf((v.z - mean) * scl + bb);
  o.w = f2bf((v.w - mean) * scl + bb);
  ((ushort4*)xn2)[i] = o;
}

// ---- combine ffn2 partials (4x bf16) + x1 (bf16) + b2 -> out fp32.
__global__ __launch_bounds__(256) void combine_out_kernel(
    const unsigned short* __restrict__ pf0, const unsigned short* __restrict__ pf1,
    const unsigned short* __restrict__ pf2, const unsigned short* __restrict__ pf3,
    const unsigned short* __restrict__ x1, const float* __restrict__ b2,
    float* __restrict__ out) {
  const int t = threadIdx.x;
  const size_t i = (size_t)blockIdx.x * 256 + t;
  const ushort4 a4 = ((const ushort4*)pf0)[i];
  const ushort4 b4 = ((const ushort4*)pf1)[i];
  const ushort4 c4 = ((const ushort4*)pf2)[i];
  const ushort4 d4 = ((const ushort4*)pf3)[i];
  const ushort4 e4 = ((const ushort4*)x1)[i];
  const float4 f4 = ((const float4*)b2)[t];
  float4 v;
  v.x = bf2f(a4.x) + bf2f(b4.x) + bf2f(c4.x) + bf2f(d4.x) + bf2f(e4.x) + f4.x;
  v.y = bf2f(a4.y) + bf2f(b4.y) + bf2f(c4.y) + bf2f(d4.y) + bf2f(e4.y) + f4.y;
  v.z = bf2f(a4.z) + bf2f(b4.z) + bf2f(c4.z) + bf2f(d4.z) + bf2f(e4.z) + f4.z;
  v.w = bf2f(a4.w) + bf2f(b4.w) + bf2f(c4.w) + bf2f(d4.w) + bf2f(e4.w) + f4.w;
  ((float4*)out)[i] = v;
}

// ---- combine attention key-halves + corr -> ctx (bf16)
__global__ __launch_bounds__(256) void attn_combine_kernel(
    const unsigned short* __restrict__ p0, const unsigned short* __restrict__ p1,
    const float* __restrict__ corr, unsigned short* __restrict__ ctx) {
  const int row = blockIdx.x, t = threadIdx.x;
  const size_t i = (size_t)row * 256 + t;
  const ushort4 a4 = ((const ushort4*)p0)[i];
  const ushort4 b4 = ((const ushort4*)p1)[i];
  const float4 c4 = ((const float4*)(corr + (row >> 10) * 1024))[t];
  ushort4 o;
  o.x = f2bf(bf2f(a4.x) + bf2f(b4.x) - 1e9f * c4.x);
  o.y = f2bf(bf2f(a4.y) + bf2f(b4.y) - 1e9f * c4.y);
  o.z = f2bf(bf2f(a4.z) + bf2f(b4.z) - 1e9f * c4.z);
  o.w = f2bf(bf2f(a4.w) + bf2f(b4.w) - 1e9f * c4.w);
  ((ushort4*)ctx)[i] = o;
}

// ---- fused attention, key-split kz=2: ctxp[kz] = (mask? QK^T/8 : 0)@V
// over keys [kz*512, kz*512+512). 1024 blocks, 4/CU.
__global__ __launch_bounds__(256, 4) void attn_kernel(
    const unsigned short* __restrict__ qkv, const unsigned short* __restrict__ vT,
    const int* __restrict__ mask,
    unsigned short* __restrict__ ctxp0, unsigned short* __restrict__ ctxp1) {
  __shared__ __align__(16) unsigned short Qs[128 * 64];
  __shared__ __align__(16) unsigned short Ks[32 * 64];
  __shared__ __align__(16) unsigned short Vs[64 * 32];
  __shared__ __align__(16) unsigned short Ps[128 * 40];  // padded rows (80 B)
  const int tid = threadIdx.x, lane = tid & 63, w = tid >> 6;
  const int quad = lane >> 4, col = lane & 15;
  // XCD swizzle: same (b,h,kz) -> same residue (its 8 q-blocks share K/V)
  const int L = blockIdx.x + 8 * (blockIdx.y + 16 * blockIdx.z);  // 0..1023
  const int s_ = L >> 3;
  const int g = (L & 7) * 16 + (s_ >> 3);   // 0..127
  const int q0 = (s_ & 7) * 128;
  const int h = g & 15, bkz = g >> 4;
  const int b = bkz >> 1, kz = bkz & 1;
  const size_t qbase = ((size_t)(b * 1024 + q0)) * 3072 + h * 64;

#pragma unroll
  for (int t = 0; t < 4; ++t) {
    const int s = t * 256 + w * 64 + lane;
    const int m = s >> 3, c = (s & 7) ^ (m & 7);
    g2l16(qkv + qbase + (size_t)m * 3072 + c * 8, (void*)(Qs + s * 8));
  }
  __syncthreads();
  bf16x8 qf[2][2];
#pragma unroll
  for (int qt = 0; qt < 2; ++qt)
#pragma unroll
    for (int kf = 0; kf < 2; ++kf) {
      const int m = (w * 2 + qt) * 16 + col;
      const int c = (kf * 4 + quad) ^ (m & 7);
      qf[qt][kf] = *(const bf16x8*)(Qs + m * 64 + c * 8);
    }

  const f32x4 z4 = {0.f, 0.f, 0.f, 0.f};
  f32x4 oacc[2][4];
#pragma unroll
  for (int qt = 0; qt < 2; ++qt)
#pragma unroll
    for (int nt = 0; nt < 4; ++nt) oacc[qt][nt] = z4;

  const int* mrow = mask + b * 1024;
  const int kb0 = kz * 512;
  for (int kb = kb0; kb < kb0 + 512; kb += 32) {
    __syncthreads();
    {
      const int s = w * 64 + lane;
      const int key = s >> 3, ck = (s & 7) ^ (key & 7);
      g2l16(qkv + ((size_t)(b * 1024 + kb + key)) * 3072 + 1024 + h * 64 + ck * 8,
            (void*)(Ks + s * 8));
      const int d = s >> 2, cv = (s & 3) ^ (((d >> 2) ^ d) & 3);
      g2l16(vT + ((size_t)(h * 64 + d)) * 4096 + b * 1024 + kb + cv * 8,
            (void*)(Vs + s * 8));
    }
    __syncthreads();

    // S^T = K Q^T : C rows = key, cols = q
    f32x4 st[2][2];
#pragma unroll
    for (int qt = 0; qt < 2; ++qt)
#pragma unroll
      for (int kt = 0; kt < 2; ++kt) st[qt][kt] = z4;
#pragma unroll
    for (int kt = 0; kt < 2; ++kt)
#pragma unroll
      for (int kf = 0; kf < 2; ++kf) {
        const int key = kt * 16 + col;
        const int c = (kf * 4 + quad) ^ (key & 7);
        const bf16x8 kfrag = *(const bf16x8*)(Ks + key * 64 + c * 8);
#pragma unroll
        for (int qt = 0; qt < 2; ++qt)
          st[qt][kt] = __builtin_amdgcn_mfma_f32_16x16x32_bf16(
              kfrag, qf[qt][kf], st[qt][kt], 0, 0, 0);
      }

    // mask*scale then round-half-up pack; one b64 write per (qt,kt)
    const int4 mv0 = *(const int4*)(mrow + kb + quad * 4);
    const int4 mv1 = *(const int4*)(mrow + kb + 16 + quad * 4);
#pragma unroll
    for (int qt = 0; qt < 2; ++qt) {
      const int qrow = (w * 2 + qt) * 16 + col;
#pragma unroll
      for (int kt = 0; kt < 2; ++kt) {
        const int4 mv = kt ? mv1 : mv0;
        const f32x4 sv = st[qt][kt];
        const unsigned int u0 = fbits((mv.x ? 0.125f : 0.f) * sv[0]) + 0x8000u;
        const unsigned int u1 = fbits((mv.y ? 0.125f : 0.f) * sv[1]) + 0x8000u;
        const unsigned int u2 = fbits((mv.z ? 0.125f : 0.f) * sv[2]) + 0x8000u;
        const unsigned int u3 = fbits((mv.w ? 0.125f : 0.f) * sv[3]) + 0x8000u;
        uint2 pk;
        pk.x = (u0 >> 16) | (u1 & 0xFFFF0000u);
        pk.y = (u2 >> 16) | (u3 & 0xFFFF0000u);
        const int pp = kt * 2 + (quad >> 1);
        *(uint2*)(Ps + qrow * 40 + ((pp ^ (qrow & 3)) * 8 + (quad & 1) * 4)) = pk;
      }
    }
    // no barrier: wave w only touches its own q-rows

    // oacc += P @ V
#pragma unroll
    for (int qt = 0; qt < 2; ++qt) {
      const int qrow = (w * 2 + qt) * 16 + col;
      const bf16x8 pf = *(const bf16x8*)(Ps + qrow * 40 + (quad ^ (qrow & 3)) * 8);
#pragma unroll
      for (int nt = 0; nt < 4; ++nt) {
        const int vr = nt * 16 + col;
        const bf16x8 vf = *(const bf16x8*)(Vs + vr * 32 + ((quad ^ (((vr >> 2) ^ vr) & 3))) * 8);
        oacc[qt][nt] = __builtin_amdgcn_mfma_f32_16x16x32_bf16(pf, vf, oacc[qt][nt], 0, 0, 0);
      }
    }
  }

  unsigned short* P = kz ? ctxp1 : ctxp0;
#pragma unroll
  for (int qt = 0; qt < 2; ++qt)
#pragma unroll
    for (int nt = 0; nt < 4; ++nt) {
      const int d = nt * 16 + col;
#pragma unroll
      for (int r = 0; r < 4; ++r) {
        const int qq = q0 + (w * 2 + qt) * 16 + quad * 4 + r;
        P[((size_t)(b * 1024) + qq) * 1024 + h * 64 + d] = f2bf(oacc[qt][nt][r]);
      }
    }
}

extern "C" void kernel_launch(void* const* d_in, const int* in_sizes, int n_in,
                              void* d_out, int out_size, void* d_ws, size_t ws_size,
                              hipStream_t stream) {
  const float* x    = (const float*)d_in[0];
  const int*   mask = (const int*)d_in[1];
  const float* wq = (const float*)d_in[2];
  const float* bq = (const float*)d_in[3];
  const float* wk = (const float*)d_in[4];
  const float* bk = (const float*)d_in[5];
  const float* wv = (const float*)d_in[6];
  const float* bv = (const float*)d_in[7];
  const float* wo = (const float*)d_in[8];
  const float* bo = (const float*)d_in[9];
  const float* w1 = (const float*)d_in[10];
  const float* b1 = (const float*)d_in[11];
  const float* w2 = (const float*)d_in[12];
  const float* b2 = (const float*)d_in[13];
  const float* ln1a = (const float*)d_in[14];
  const float* ln1b = (const float*)d_in[15];
  const float* ln2a = (const float*)d_in[16];
  const float* ln2b = (const float*)d_in[17];
  float* out = (float*)d_out;
  char* W = (char*)d_ws;
  const size_t MB = 1u << 20;

  unsigned short* wqkvT = (unsigned short*)(W + 0 * MB);   // 6 MB [3072][1024]
  unsigned short* woT   = (unsigned short*)(W + 6 * MB);   // 2 MB
  unsigned short* w1T   = (unsigned short*)(W + 8 * MB);   // 8 MB
  unsigned short* w2T   = (unsigned short*)(W + 16 * MB);  // 8 MB
  float*          bqkv  = (float*)(W + 24 * MB);           // 12 KB
  float*          corr  = (float*)(W + 24 * MB + 65536);   // 16 KB
  float*          corrp = (float*)(W + 24 * MB + 131072);  // 256 KB
  unsigned short* xn    = (unsigned short*)(W + 25 * MB);  // 8 MB (xn / xn2)
  unsigned short* qkv   = (unsigned short*)(W + 33 * MB);  // 24 MB [4096][3072]
  unsigned short* vT    = (unsigned short*)(W + 57 * MB);  // 8 MB [1024][4096]
  unsigned short* ctxp0 = (unsigned short*)(W + 65 * MB);  // 8 MB
  unsigned short* ctxp1 = (unsigned short*)(W + 73 * MB);  // 8 MB
  unsigned short* ctx   = (unsigned short*)(W + 33 * MB);  // 8 MB (qkv dead)
  unsigned short* p0wo  = (unsigned short*)(W + 41 * MB);  // 8 MB (qkv dead)
  unsigned short* p1wo  = (unsigned short*)(W + 49 * MB);  // 8 MB (qkv dead)
  unsigned short* x1    = (unsigned short*)(W + 65 * MB);  // 8 MB (ctxp0 dead)
  unsigned short* xn2   = xn;                              // reuse
  unsigned short* hb    = (unsigned short*)(W + 33 * MB);  // 32 MB (ctx/p0wo/p1wo/vT dead)
  unsigned short* pf0   = (unsigned short*)(W + 0 * MB);   // 8 MB (wqkvT/woT dead)
  unsigned short* pf1   = (unsigned short*)(W + 8 * MB);   // 8 MB (w1T dead)
  unsigned short* pf2   = (unsigned short*)(W + 73 * MB);  // 8 MB (ctxp1 dead)
  unsigned short* pf3   = (unsigned short*)(W + 24 * MB);  // 8 MB (bqkv/corr/xn2 dead)

  wconv_kernel<<<3073, 256, 0, stream>>>(wq, wk, wv, wo, w1, w2, bq, bk, bv,
                                         wqkvT, woT, w1T, w2T, bqkv);
  ln_kernel<<<4096, 256, 0, stream>>>(x, xn, ln1a, ln1b);
  // fused q|k|v: [4096][3072], 768 blocks (3/CU), BK=64
  mfma_gemm<128, 128, true, false, false, 12, 8>
      <<<dim3(24, 32), 256, 0, stream>>>(
      xn, wqkvT, bqkv, qkv, nullptr, nullptr, nullptr, 3072, 1024, 1024, 1024);
  vtrans_kernel<<<dim3(16, 64), 256, 0, stream>>>(qkv, mask, vT, corrp);
  corr_reduce_kernel<<<16, 256, 0, stream>>>(corrp, corr);
  // attention, key-split kz=2: 1024 blocks (4/CU)
  attn_kernel<<<dim3(8, 16, 8), 256, 0, stream>>>(qkv, vT, mask, ctxp0, ctxp1);
  attn_combine_kernel<<<4096, 256, 0, stream>>>(ctxp0, ctxp1, corr, ctx);
  // wo-proj split-K z=2 (KH=512), bf16 partials
  mfma_gemm<128, 128, false, false, true, 8, 8>
      <<<dim3(8, 32, 2), 256, 0, stream>>>(
      ctx, woT, nullptr, p0wo, p1wo, nullptr, nullptr, 1024, 1024, 1024, 512);
  combine_ln_kernel<<<4096, 256, 0, stream>>>(p0wo, p1wo, x, bo, ln2a, ln2b, x1, xn2);
  // FFN1: 1024 blocks (4/CU), BK=64
  mfma_gemm<128, 128, true, true, false, 16, 8>
      <<<dim3(32, 32), 256, 0, stream>>>(
      xn2, w1T, b1, hb, nullptr, nullptr, nullptr, 4096, 1024, 1024, 1024);
  // FFN2 split-K z=4 (KH=1024), 1024 blocks (4/CU), bf16 partials
  mfma_gemm<128, 128, false, false, true, 8, 16>
      <<<dim3(8, 32, 4), 256, 0, stream>>>(
      hb, w2T, nullptr, pf0, pf1, pf2, pf3, 1024, 4096, 4096, 1024);
  combine_out_kernel<<<4096, 256, 0, stream>>>(pf0, pf1, pf2, pf3, x1, b2, out);
}